// Round 1
// baseline (1085.956 us; speedup 1.0000x reference)
//
#include <hip/hip_runtime.h>
#include <math.h>

#define Bn 2
#define Nn 20000
#define Cn 512
#define Sn 128
#define Hn 8
#define Dn 64
#define En 320000
#define EPSf 1e-6f
#define NBLK 313  // ceil(20000/64)

// ---------------- K1: weights = softmax(x @ Ws + bs), accumulate wsum ----------
__global__ __launch_bounds__(256) void k_assign(
    const float* __restrict__ x, const float* __restrict__ Ws,
    const float* __restrict__ bs, float* __restrict__ weights,
    float* __restrict__ wsum)
{
    __shared__ float xt[32][68];
    __shared__ float wst[32][128];
    __shared__ float wsum_loc[128];

    int t = threadIdx.x;
    int tc = t & 31, tr = t >> 5;
    int b = blockIdx.x / NBLK;
    int rb = blockIdx.x % NBLK;
    int n0 = rb * 64;

    if (t < 128) wsum_loc[t] = 0.f;

    float acc[8][4];
    #pragma unroll
    for (int i = 0; i < 8; i++)
        #pragma unroll
        for (int j = 0; j < 4; j++) acc[i][j] = 0.f;

    const float* xb = x + (size_t)b * Nn * Cn;

    for (int k0 = 0; k0 < Cn; k0 += 32) {
        #pragma unroll
        for (int l = 0; l < 8; l++) {
            int idx = t + l * 256;
            int r = idx >> 5, kk = idx & 31;
            int n = n0 + r;
            xt[kk][r] = (n < Nn) ? xb[(size_t)n * Cn + k0 + kk] : 0.f;
        }
        #pragma unroll
        for (int l = 0; l < 16; l++) {
            int idx = t + l * 256;
            int kk = idx >> 7, s = idx & 127;
            wst[kk][s] = Ws[(size_t)(k0 + kk) * Sn + s];
        }
        __syncthreads();
        #pragma unroll
        for (int kk = 0; kk < 32; kk++) {
            float4 wv = *(const float4*)&wst[kk][tc * 4];
            float4 xa = *(const float4*)&xt[kk][tr * 8];
            float4 xc = *(const float4*)&xt[kk][tr * 8 + 4];
            float xs[8] = {xa.x, xa.y, xa.z, xa.w, xc.x, xc.y, xc.z, xc.w};
            float wf[4] = {wv.x, wv.y, wv.z, wv.w};
            #pragma unroll
            for (int i = 0; i < 8; i++)
                #pragma unroll
                for (int j = 0; j < 4; j++) acc[i][j] += xs[i] * wf[j];
        }
        __syncthreads();
    }

    float bsv[4];
    #pragma unroll
    for (int j = 0; j < 4; j++) bsv[j] = bs[tc * 4 + j];

    float wacc[4] = {0.f, 0.f, 0.f, 0.f};
    float* wb = weights + (size_t)b * Nn * Sn;
    #pragma unroll
    for (int i = 0; i < 8; i++) {
        int n = n0 + tr * 8 + i;
        float l0 = acc[i][0] + bsv[0];
        float l1 = acc[i][1] + bsv[1];
        float l2 = acc[i][2] + bsv[2];
        float l3 = acc[i][3] + bsv[3];
        float m = fmaxf(fmaxf(l0, l1), fmaxf(l2, l3));
        #pragma unroll
        for (int d = 1; d < 32; d <<= 1) m = fmaxf(m, __shfl_xor(m, d));
        float e0 = __expf(l0 - m), e1 = __expf(l1 - m);
        float e2 = __expf(l2 - m), e3 = __expf(l3 - m);
        float sm = e0 + e1 + e2 + e3;
        #pragma unroll
        for (int d = 1; d < 32; d <<= 1) sm += __shfl_xor(sm, d);
        float inv = 1.f / sm;
        if (n < Nn) {
            float4 wv4 = make_float4(e0 * inv, e1 * inv, e2 * inv, e3 * inv);
            *(float4*)&wb[(size_t)n * Sn + tc * 4] = wv4;
            wacc[0] += wv4.x; wacc[1] += wv4.y; wacc[2] += wv4.z; wacc[3] += wv4.w;
        }
    }
    __syncthreads();
    #pragma unroll
    for (int j = 0; j < 4; j++) atomicAdd(&wsum_loc[tc * 4 + j], wacc[j]);
    __syncthreads();
    if (t < 128) atomicAdd(&wsum[b * Sn + t], wsum_loc[t]);
}

// ---------------- K2: slices_raw[b,s,c] += sum_n w[b,n,s]*x[b,n,c] (split-K) ----
__global__ __launch_bounds__(256) void k_slices(
    const float* __restrict__ weights, const float* __restrict__ x,
    float* __restrict__ slices_raw)
{
    __shared__ float wt[8][128];
    __shared__ float xt[8][68];
    int t = threadIdx.x;
    int tc = t & 15, ts = t >> 4;
    int blk = blockIdx.x;
    int b = blk / 1000;
    int cb = (blk % 1000) / 125;
    int kb = blk % 125;
    int c0 = cb * 64;
    int k0 = kb * 160;
    const float* wb = weights + (size_t)b * Nn * Sn;
    const float* xb = x + (size_t)b * Nn * Cn;

    float acc[8][4];
    #pragma unroll
    for (int i = 0; i < 8; i++)
        #pragma unroll
        for (int j = 0; j < 4; j++) acc[i][j] = 0.f;

    for (int kt = 0; kt < 160; kt += 8) {
        #pragma unroll
        for (int l = 0; l < 4; l++) {
            int idx = t + l * 256;
            int r = idx >> 7, s = idx & 127;
            wt[r][s] = wb[(size_t)(k0 + kt + r) * Sn + s];
        }
        #pragma unroll
        for (int l = 0; l < 2; l++) {
            int idx = t + l * 256;
            int r = idx >> 6, c = idx & 63;
            xt[r][c] = xb[(size_t)(k0 + kt + r) * Cn + c0 + c];
        }
        __syncthreads();
        #pragma unroll
        for (int kk = 0; kk < 8; kk++) {
            float4 xv = *(const float4*)&xt[kk][tc * 4];
            float4 wa = *(const float4*)&wt[kk][ts * 8];
            float4 wc = *(const float4*)&wt[kk][ts * 8 + 4];
            float wf[8] = {wa.x, wa.y, wa.z, wa.w, wc.x, wc.y, wc.z, wc.w};
            float xf[4] = {xv.x, xv.y, xv.z, xv.w};
            #pragma unroll
            for (int i = 0; i < 8; i++)
                #pragma unroll
                for (int j = 0; j < 4; j++) acc[i][j] += wf[i] * xf[j];
        }
        __syncthreads();
    }
    float* sr = slices_raw + (size_t)b * Sn * Cn;
    #pragma unroll
    for (int i = 0; i < 8; i++)
        #pragma unroll
        for (int j = 0; j < 4; j++)
            atomicAdd(&sr[(size_t)(ts * 8 + i) * Cn + c0 + tc * 4 + j], acc[i][j]);
}

// ---------------- K2b ----------------------------------------------------------
__global__ __launch_bounds__(256) void k_slices_div(
    float* __restrict__ slices, const float* __restrict__ wsum)
{
    int i = blockIdx.x * 256 + threadIdx.x;
    if (i < Bn * Sn * Cn) {
        int bsi = i / Cn;
        slices[i] = slices[i] / fmaxf(wsum[bsi], EPSf);
    }
}

// ---------------- K3 -----------------------------------------------------------
__global__ __launch_bounds__(256) void k_scatter(
    const float* __restrict__ weights, const int* __restrict__ adj,
    const float* __restrict__ vals, float* __restrict__ gw)
{
    int t = threadIdx.x;
    int s = t & 127;
    int half = t >> 7;
    int e0 = blockIdx.x * 32;
    for (int it = 0; it < 16; it++) {
        int e = e0 + it * 2 + half;
        int r = adj[e];
        int c = adj[En + e];
        float vv = vals[e];
        #pragma unroll
        for (int b = 0; b < Bn; b++) {
            float w = weights[(size_t)b * Nn * Sn + (size_t)c * Sn + s];
            atomicAdd(&gw[(size_t)b * Nn * Sn + (size_t)r * Sn + s], vv * w);
        }
    }
}

// ---------------- K4 -----------------------------------------------------------
__global__ __launch_bounds__(256) void k_gb(
    const float* __restrict__ weights, const float* __restrict__ gw,
    float* __restrict__ gb_raw)
{
    __shared__ float wt[8][128];
    __shared__ float gt[8][128];
    int t = threadIdx.x;
    int tt = t & 15, ts = t >> 4;
    int b = blockIdx.x / 125;
    int k0 = (blockIdx.x % 125) * 160;
    const float* wb = weights + (size_t)b * Nn * Sn;
    const float* gwb = gw + (size_t)b * Nn * Sn;

    float acc[8][8];
    #pragma unroll
    for (int i = 0; i < 8; i++)
        #pragma unroll
        for (int j = 0; j < 8; j++) acc[i][j] = 0.f;

    for (int kt = 0; kt < 160; kt += 8) {
        #pragma unroll
        for (int l = 0; l < 4; l++) {
            int idx = t + l * 256;
            int r = idx >> 7, s = idx & 127;
            wt[r][s] = wb[(size_t)(k0 + kt + r) * Sn + s];
            gt[r][s] = gwb[(size_t)(k0 + kt + r) * Sn + s];
        }
        __syncthreads();
        #pragma unroll
        for (int kk = 0; kk < 8; kk++) {
            float4 wa = *(const float4*)&wt[kk][ts * 8];
            float4 wc = *(const float4*)&wt[kk][ts * 8 + 4];
            float4 ga = *(const float4*)&gt[kk][tt * 8];
            float4 gc = *(const float4*)&gt[kk][tt * 8 + 4];
            float wf[8] = {wa.x, wa.y, wa.z, wa.w, wc.x, wc.y, wc.z, wc.w};
            float gf[8] = {ga.x, ga.y, ga.z, ga.w, gc.x, gc.y, gc.z, gc.w};
            #pragma unroll
            for (int i = 0; i < 8; i++)
                #pragma unroll
                for (int j = 0; j < 8; j++) acc[i][j] += wf[i] * gf[j];
        }
        __syncthreads();
    }
    float* gr = gb_raw + (size_t)b * Sn * Sn;
    #pragma unroll
    for (int i = 0; i < 8; i++)
        #pragma unroll
        for (int j = 0; j < 8; j++)
            atomicAdd(&gr[(size_t)(ts * 8 + i) * Sn + tt * 8 + j], acc[i][j]);
}

// ---------------- K4b ----------------------------------------------------------
__global__ __launch_bounds__(128) void k_gb_fin(
    const float* __restrict__ gb_raw, float* __restrict__ gb)
{
    int bid = blockIdx.x;
    int b = bid >> 7, i = bid & 127;
    int j = threadIdx.x;
    const float* gr = gb_raw + (size_t)b * Sn * Sn;
    float sym = 0.5f * (gr[i * Sn + j] + gr[j * Sn + i]);
    float sum = sym;
    #pragma unroll
    for (int d = 1; d < 64; d <<= 1) sum += __shfl_xor(sum, d);
    __shared__ float wred[2];
    if ((j & 63) == 0) wred[j >> 6] = sum;
    __syncthreads();
    sum = wred[0] + wred[1];
    float r = fmaxf(sum, EPSf);
    gb[(size_t)b * Sn * Sn + (size_t)i * Sn + j] = logf(fmaxf(sym / r, EPSf));
}

// ---------------- K5/K7 --------------------------------------------------------
__global__ __launch_bounds__(256) void k_lin(
    const float* __restrict__ in, const float* __restrict__ W,
    const float* __restrict__ bias, float* __restrict__ out)
{
    __shared__ float it[8][512];
    int t = threadIdx.x;
    int m0 = blockIdx.x * 8;
    int c = blockIdx.y * 256 + t;
    #pragma unroll
    for (int l = 0; l < 16; l++) {
        int idx = t + l * 256;
        int r = idx >> 9, kk = idx & 511;
        it[r][kk] = in[(size_t)(m0 + r) * Cn + kk];
    }
    __syncthreads();
    float acc[8] = {0.f,0.f,0.f,0.f,0.f,0.f,0.f,0.f};
    #pragma unroll 4
    for (int kk = 0; kk < Cn; kk++) {
        float wv = W[(size_t)kk * Cn + c];
        #pragma unroll
        for (int r = 0; r < 8; r++) acc[r] += it[r][kk] * wv;
    }
    float bv = bias[c];
    #pragma unroll
    for (int r = 0; r < 8; r++) out[(size_t)(m0 + r) * Cn + c] = acc[r] + bv;
}

// ---------------- K6 -----------------------------------------------------------
__global__ __launch_bounds__(128) void k_attn(
    const float* __restrict__ q, const float* __restrict__ k,
    const float* __restrict__ v, const float* __restrict__ gb,
    const float* __restrict__ beta_raw, float* __restrict__ attn_out)
{
    __shared__ float kv[128][65];
    __shared__ float qv[64];
    __shared__ float p[128];
    __shared__ float wred[2][2];

    int t = threadIdx.x;
    int bid = blockIdx.x;
    int b = bid / (Hn * Sn);
    int h = (bid / Sn) % Hn;
    int i = bid % Sn;
    size_t base = (size_t)b * Sn * Cn + (size_t)h * Dn;

    if (t < 64) qv[t] = q[base + (size_t)i * Cn + t];
    for (int l = 0; l < 64; l++) {
        int idx = t + l * 128;
        int j = idx >> 6, d = idx & 63;
        kv[j][d] = k[base + (size_t)j * Cn + d];
    }
    __syncthreads();

    float dot = 0.f;
    #pragma unroll
    for (int d = 0; d < 64; d++) dot += qv[d] * kv[t][d];

    float beta = log1pf(__expf(beta_raw[0]));
    float logit = dot * 0.125f + beta * gb[(size_t)b * Sn * Sn + (size_t)i * Sn + t];

    float m = logit;
    #pragma unroll
    for (int d = 1; d < 64; d <<= 1) m = fmaxf(m, __shfl_xor(m, d));
    if ((t & 63) == 0) wred[0][t >> 6] = m;
    __syncthreads();
    m = fmaxf(wred[0][0], wred[0][1]);
    float e = __expf(logit - m);
    float sm = e;
    #pragma unroll
    for (int d = 1; d < 64; d <<= 1) sm += __shfl_xor(sm, d);
    if ((t & 63) == 0) wred[1][t >> 6] = sm;
    __syncthreads();
    sm = wred[1][0] + wred[1][1];
    p[t] = e / sm;
    __syncthreads();

    for (int l = 0; l < 64; l++) {
        int idx = t + l * 128;
        int j = idx >> 6, d = idx & 63;
        kv[j][d] = v[base + (size_t)j * Cn + d];
    }
    __syncthreads();

    if (t < 64) {
        float o = 0.f;
        #pragma unroll 8
        for (int j = 0; j < 128; j++) o += p[j] * kv[j][t];
        attn_out[base + (size_t)i * Cn + t] = o;
    }
}

// ---------------- K8 -----------------------------------------------------------
__global__ __launch_bounds__(256) void k_out(
    const float* __restrict__ weights, const float* __restrict__ so,
    float* __restrict__ out)
{
    __shared__ float wt[16][68];
    __shared__ float st[16][68];
    int t = threadIdx.x;
    int tc = t & 15, tr = t >> 4;
    int blk = blockIdx.x;
    int b = blk / (NBLK * 8);
    int rb = (blk / 8) % NBLK;
    int cb = blk & 7;
    int n0 = rb * 64, c0 = cb * 64;
    const float* wb = weights + (size_t)b * Nn * Sn;
    const float* sb = so + (size_t)b * Sn * Cn;

    float acc[4][4];
    #pragma unroll
    for (int i = 0; i < 4; i++)
        #pragma unroll
        for (int j = 0; j < 4; j++) acc[i][j] = 0.f;

    for (int k0 = 0; k0 < Sn; k0 += 16) {
        #pragma unroll
        for (int l = 0; l < 4; l++) {
            int idx = t + l * 256;
            int r = idx >> 4, kk = idx & 15;
            int n = n0 + r;
            wt[kk][r] = (n < Nn) ? wb[(size_t)n * Sn + k0 + kk] : 0.f;
        }
        #pragma unroll
        for (int l = 0; l < 4; l++) {
            int idx = t + l * 256;
            int kk = idx >> 6, c = idx & 63;
            st[kk][c] = sb[(size_t)(k0 + kk) * Cn + c0 + c];
        }
        __syncthreads();
        #pragma unroll
        for (int kk = 0; kk < 16; kk++) {
            float4 sv = *(const float4*)&st[kk][tc * 4];
            float4 wv = *(const float4*)&wt[kk][tr * 4];
            float wf[4] = {wv.x, wv.y, wv.z, wv.w};
            float sf[4] = {sv.x, sv.y, sv.z, sv.w};
            #pragma unroll
            for (int i = 0; i < 4; i++)
                #pragma unroll
                for (int j = 0; j < 4; j++) acc[i][j] += wf[i] * sf[j];
        }
        __syncthreads();
    }
    #pragma unroll
    for (int i = 0; i < 4; i++) {
        int n = n0 + tr * 4 + i;
        if (n < Nn) {
            float4 o = make_float4(acc[i][0], acc[i][1], acc[i][2], acc[i][3]);
            *(float4*)&out[((size_t)b * Nn + n) * Cn + c0 + tc * 4] = o;
        }
    }
}

extern "C" void kernel_launch(void* const* d_in, const int* in_sizes, int n_in,
                              void* d_out, int out_size, void* d_ws, size_t ws_size,
                              hipStream_t stream)
{
    const float* x  = (const float*)d_in[0];
    const int* adj  = (const int*)d_in[1];
    const float* av = (const float*)d_in[2];
    const float* Ws = (const float*)d_in[3];
    const float* bs = (const float*)d_in[4];
    const float* Wq = (const float*)d_in[5];
    const float* bq = (const float*)d_in[6];
    const float* Wk = (const float*)d_in[7];
    const float* bk = (const float*)d_in[8];
    const float* Wv = (const float*)d_in[9];
    const float* bv = (const float*)d_in[10];
    const float* Wo = (const float*)d_in[11];
    const float* bo = (const float*)d_in[12];
    const float* br = (const float*)d_in[13];
    float* out = (float*)d_out;
    (void)in_sizes; (void)n_in; (void)out_size; (void)ws_size;

    char* ws = (char*)d_ws;
    size_t off = 0;
    float* weights    = (float*)(ws + off); off += (size_t)Bn * Nn * Sn * 4;
    size_t zstart = off;
    float* gw         = (float*)(ws + off); off += (size_t)Bn * Nn * Sn * 4;
    float* slices     = (float*)(ws + off); off += (size_t)Bn * Sn * Cn * 4;
    float* wsum       = (float*)(ws + off); off += 1024;
    float* gb_raw     = (float*)(ws + off); off += (size_t)Bn * Sn * Sn * 4;
    size_t zlen = off - zstart;
    float* gb         = (float*)(ws + off); off += (size_t)Bn * Sn * Sn * 4;
    float* q          = (float*)(ws + off); off += (size_t)Bn * Sn * Cn * 4;
    float* kbuf       = (float*)(ws + off); off += (size_t)Bn * Sn * Cn * 4;
    float* vbuf       = (float*)(ws + off); off += (size_t)Bn * Sn * Cn * 4;
    float* attn_out   = (float*)(ws + off); off += (size_t)Bn * Sn * Cn * 4;
    float* slices_out = (float*)(ws + off); off += (size_t)Bn * Sn * Cn * 4;

    hipMemsetAsync(ws + zstart, 0, zlen, stream);

    k_assign<<<Bn * NBLK, 256, 0, stream>>>(x, Ws, bs, weights, wsum);
    k_slices<<<2000, 256, 0, stream>>>(weights, x, slices);
    k_slices_div<<<(Bn * Sn * Cn) / 256, 256, 0, stream>>>(slices, wsum);
    k_scatter<<<En / 32, 256, 0, stream>>>(weights, adj, av, gw);
    k_gb<<<Bn * 125, 256, 0, stream>>>(weights, gw, gb_raw);
    k_gb_fin<<<Bn * Sn, 128, 0, stream>>>(gb_raw, gb);
    k_lin<<<dim3(32, 2), 256, 0, stream>>>(slices, Wq, bq, q);
    k_lin<<<dim3(32, 2), 256, 0, stream>>>(slices, Wk, bk, kbuf);
    k_lin<<<dim3(32, 2), 256, 0, stream>>>(slices, Wv, bv, vbuf);
    k_attn<<<Bn * Hn * Sn, 128, 0, stream>>>(q, kbuf, vbuf, gb, br, attn_out);
    k_lin<<<dim3(32, 2), 256, 0, stream>>>(attn_out, Wo, bo, slices_out);
    k_out<<<Bn * NBLK * 8, 256, 0, stream>>>(weights, slices_out, out);
}

// Round 2
// 801.187 us; speedup vs baseline: 1.3554x; 1.3554x over previous
//
#include <hip/hip_runtime.h>
#include <math.h>

#define Bn 2
#define Nn 20000
#define Cn 512
#define Sn 128
#define Hn 8
#define Dn 64
#define En 320000
#define EPSf 1e-6f
#define NBLK 313  // ceil(20000/64)

// K-split geometry for the two big transposed GEMMs
#define S_KB 40     // k_slices2: 40 chunks of 512 rows (covers 20480, guarded)
#define S_CHUNK 512
#define G_KB 80     // k_gb2: 80 chunks of 256 rows
#define G_CHUNK 256

// ---------------- K1: weights = softmax(x @ Ws + bs), accumulate wsum ----------
__global__ __launch_bounds__(256) void k_assign(
    const float* __restrict__ x, const float* __restrict__ Ws,
    const float* __restrict__ bs, float* __restrict__ weights,
    float* __restrict__ wsum)
{
    __shared__ float xt[32][68];
    __shared__ float wst[32][128];
    __shared__ float wsum_loc[128];

    int t = threadIdx.x;
    int tc = t & 31, tr = t >> 5;
    int b = blockIdx.x / NBLK;
    int rb = blockIdx.x % NBLK;
    int n0 = rb * 64;

    if (t < 128) wsum_loc[t] = 0.f;

    float acc[8][4];
    #pragma unroll
    for (int i = 0; i < 8; i++)
        #pragma unroll
        for (int j = 0; j < 4; j++) acc[i][j] = 0.f;

    const float* xb = x + (size_t)b * Nn * Cn;

    for (int k0 = 0; k0 < Cn; k0 += 32) {
        #pragma unroll
        for (int l = 0; l < 8; l++) {
            int idx = t + l * 256;
            int r = idx >> 5, kk = idx & 31;
            int n = n0 + r;
            xt[kk][r] = (n < Nn) ? xb[(size_t)n * Cn + k0 + kk] : 0.f;
        }
        #pragma unroll
        for (int l = 0; l < 16; l++) {
            int idx = t + l * 256;
            int kk = idx >> 7, s = idx & 127;
            wst[kk][s] = Ws[(size_t)(k0 + kk) * Sn + s];
        }
        __syncthreads();
        #pragma unroll
        for (int kk = 0; kk < 32; kk++) {
            float4 wv = *(const float4*)&wst[kk][tc * 4];
            float4 xa = *(const float4*)&xt[kk][tr * 8];
            float4 xc = *(const float4*)&xt[kk][tr * 8 + 4];
            float xs[8] = {xa.x, xa.y, xa.z, xa.w, xc.x, xc.y, xc.z, xc.w};
            float wf[4] = {wv.x, wv.y, wv.z, wv.w};
            #pragma unroll
            for (int i = 0; i < 8; i++)
                #pragma unroll
                for (int j = 0; j < 4; j++) acc[i][j] += xs[i] * wf[j];
        }
        __syncthreads();
    }

    float bsv[4];
    #pragma unroll
    for (int j = 0; j < 4; j++) bsv[j] = bs[tc * 4 + j];

    float wacc[4] = {0.f, 0.f, 0.f, 0.f};
    float* wb = weights + (size_t)b * Nn * Sn;
    #pragma unroll
    for (int i = 0; i < 8; i++) {
        int n = n0 + tr * 8 + i;
        float l0 = acc[i][0] + bsv[0];
        float l1 = acc[i][1] + bsv[1];
        float l2 = acc[i][2] + bsv[2];
        float l3 = acc[i][3] + bsv[3];
        float m = fmaxf(fmaxf(l0, l1), fmaxf(l2, l3));
        #pragma unroll
        for (int d = 1; d < 32; d <<= 1) m = fmaxf(m, __shfl_xor(m, d));
        float e0 = __expf(l0 - m), e1 = __expf(l1 - m);
        float e2 = __expf(l2 - m), e3 = __expf(l3 - m);
        float sm = e0 + e1 + e2 + e3;
        #pragma unroll
        for (int d = 1; d < 32; d <<= 1) sm += __shfl_xor(sm, d);
        float inv = 1.f / sm;
        if (n < Nn) {
            float4 wv4 = make_float4(e0 * inv, e1 * inv, e2 * inv, e3 * inv);
            *(float4*)&wb[(size_t)n * Sn + tc * 4] = wv4;
            wacc[0] += wv4.x; wacc[1] += wv4.y; wacc[2] += wv4.z; wacc[3] += wv4.w;
        }
    }
    __syncthreads();
    #pragma unroll
    for (int j = 0; j < 4; j++) atomicAdd(&wsum_loc[tc * 4 + j], wacc[j]);
    __syncthreads();
    if (t < 128) atomicAdd(&wsum[b * Sn + t], wsum_loc[t]);
}

// ---------------- CSR build: degree histogram ----------------------------------
__global__ __launch_bounds__(256) void k_deg(
    const int* __restrict__ adj, int* __restrict__ deg)
{
    int e = blockIdx.x * 256 + threadIdx.x;
    if (e < En) atomicAdd(&deg[adj[e]], 1);
}

// ---------------- CSR build: single-block prefix scan over N -------------------
__global__ __launch_bounds__(256) void k_scan(
    const int* __restrict__ deg, int* __restrict__ offs)
{
    __shared__ int buf[256];
    __shared__ int runs;
    int t = threadIdx.x;
    if (t == 0) { offs[0] = 0; runs = 0; }
    __syncthreads();
    for (int base = 0; base < Nn; base += 256) {
        int v = (base + t < Nn) ? deg[base + t] : 0;
        buf[t] = v;
        __syncthreads();
        #pragma unroll
        for (int d = 1; d < 256; d <<= 1) {
            int add = (t >= d) ? buf[t - d] : 0;
            __syncthreads();
            buf[t] += add;
            __syncthreads();
        }
        if (base + t < Nn) offs[base + t + 1] = runs + buf[t];
        __syncthreads();
        if (t == 255) runs += buf[255];
        __syncthreads();
    }
}

// ---------------- CSR build: fill edge ids -------------------------------------
__global__ __launch_bounds__(256) void k_fill(
    const int* __restrict__ adj, const int* __restrict__ offs,
    int* __restrict__ cursor, int* __restrict__ eid)
{
    int e = blockIdx.x * 256 + threadIdx.x;
    if (e < En) {
        int r = adj[e];
        int p = atomicAdd(&cursor[r], 1);
        eid[offs[r] + p] = e;
    }
}

// ---------------- K3': gw[b,r,:] = sum_{e in row r} v_e * w[b,col_e,:] ---------
__global__ __launch_bounds__(128) void k_gather(
    const float* __restrict__ weights, const int* __restrict__ adj,
    const float* __restrict__ vals, const int* __restrict__ offs,
    const int* __restrict__ eid, float* __restrict__ gw)
{
    int r = blockIdx.x;
    int s = threadIdx.x;
    int o0 = offs[r], o1 = offs[r + 1];
    const float* w0 = weights;
    const float* w1 = weights + (size_t)Nn * Sn;
    float a0 = 0.f, a1 = 0.f;
    for (int j = o0; j < o1; j++) {
        int e = eid[j];
        int c = adj[En + e];
        float v = vals[e];
        a0 += v * w0[(size_t)c * Sn + s];
        a1 += v * w1[(size_t)c * Sn + s];
    }
    gw[(size_t)r * Sn + s] = a0;
    gw[(size_t)Nn * Sn + (size_t)r * Sn + s] = a1;
}

// ---------------- K2': slices partials: wT @ x, K-split, no atomics ------------
__global__ __launch_bounds__(256) void k_slices2(
    const float* __restrict__ weights, const float* __restrict__ x,
    float* __restrict__ partial)
{
    __shared__ float wt[8][128];
    __shared__ float xt[8][128];
    int t = threadIdx.x;
    int tc = t & 15, tr = t >> 4;
    int blk = blockIdx.x;                 // ((b*4+cb)*S_KB + kb)
    int b = blk / (4 * S_KB);
    int rem = blk % (4 * S_KB);
    int cb = rem / S_KB;
    int kb = rem % S_KB;
    int k0 = kb * S_CHUNK;
    int c0 = cb * 128;
    const float* wb = weights + (size_t)b * Nn * Sn;
    const float* xb = x + (size_t)b * Nn * Cn;

    float acc[8][8];
    #pragma unroll
    for (int i = 0; i < 8; i++)
        #pragma unroll
        for (int j = 0; j < 8; j++) acc[i][j] = 0.f;

    for (int kt = 0; kt < S_CHUNK; kt += 8) {
        #pragma unroll
        for (int l = 0; l < 4; l++) {
            int idx = t + l * 256;
            int r = idx >> 7, s = idx & 127;
            int n = k0 + kt + r;
            bool ok = (n < Nn);
            wt[r][s] = ok ? wb[(size_t)n * Sn + s] : 0.f;
            xt[r][s] = ok ? xb[(size_t)n * Cn + c0 + s] : 0.f;
        }
        __syncthreads();
        #pragma unroll
        for (int kk = 0; kk < 8; kk++) {
            float4 w0 = *(const float4*)&wt[kk][tr * 8];
            float4 w1 = *(const float4*)&wt[kk][tr * 8 + 4];
            float4 x0 = *(const float4*)&xt[kk][tc * 8];
            float4 x1 = *(const float4*)&xt[kk][tc * 8 + 4];
            float wf[8] = {w0.x, w0.y, w0.z, w0.w, w1.x, w1.y, w1.z, w1.w};
            float xf[8] = {x0.x, x0.y, x0.z, x0.w, x1.x, x1.y, x1.z, x1.w};
            #pragma unroll
            for (int i = 0; i < 8; i++)
                #pragma unroll
                for (int j = 0; j < 8; j++) acc[i][j] += wf[i] * xf[j];
        }
        __syncthreads();
    }
    float* pp = partial + (size_t)blk * 16384;
    #pragma unroll
    for (int i = 0; i < 8; i++) {
        #pragma unroll
        for (int j4 = 0; j4 < 2; j4++) {
            float4 o = make_float4(acc[i][j4 * 4], acc[i][j4 * 4 + 1],
                                   acc[i][j4 * 4 + 2], acc[i][j4 * 4 + 3]);
            *(float4*)&pp[(size_t)(tr * 8 + i) * 128 + tc * 8 + j4 * 4] = o;
        }
    }
}

// ---------------- reduce partials -> slices (with /wsum) -----------------------
__global__ __launch_bounds__(256) void k_reduceS(
    const float* __restrict__ partial, const float* __restrict__ wsum,
    float* __restrict__ slices)
{
    int g = blockIdx.x * 256 + threadIdx.x;   // 0..131071
    int c = g & 127;
    int s = (g >> 7) & 127;
    int cb = (g >> 14) & 3;
    int b = g >> 16;
    const float* pp = partial + (size_t)(b * 4 + cb) * S_KB * 16384 + (size_t)s * 128 + c;
    float sum = 0.f;
    #pragma unroll 8
    for (int kb = 0; kb < S_KB; kb++) sum += pp[(size_t)kb * 16384];
    slices[((size_t)b * Sn + s) * Cn + cb * 128 + c] = sum / fmaxf(wsum[b * Sn + s], EPSf);
}

// ---------------- K4': gb partials: wT @ gw, K-split, no atomics ---------------
__global__ __launch_bounds__(256) void k_gb2(
    const float* __restrict__ weights, const float* __restrict__ gw,
    float* __restrict__ partial)
{
    __shared__ float wt[8][128];
    __shared__ float gt[8][128];
    int t = threadIdx.x;
    int tc = t & 15, tr = t >> 4;
    int blk = blockIdx.x;                 // b*G_KB + kb
    int b = blk / G_KB;
    int kb = blk % G_KB;
    int k0 = kb * G_CHUNK;
    const float* wb = weights + (size_t)b * Nn * Sn;
    const float* gwb = gw + (size_t)b * Nn * Sn;

    float acc[8][8];
    #pragma unroll
    for (int i = 0; i < 8; i++)
        #pragma unroll
        for (int j = 0; j < 8; j++) acc[i][j] = 0.f;

    for (int kt = 0; kt < G_CHUNK; kt += 8) {
        #pragma unroll
        for (int l = 0; l < 4; l++) {
            int idx = t + l * 256;
            int r = idx >> 7, s = idx & 127;
            int n = k0 + kt + r;
            bool ok = (n < Nn);
            wt[r][s] = ok ? wb[(size_t)n * Sn + s] : 0.f;
            gt[r][s] = ok ? gwb[(size_t)n * Sn + s] : 0.f;
        }
        __syncthreads();
        #pragma unroll
        for (int kk = 0; kk < 8; kk++) {
            float4 w0 = *(const float4*)&wt[kk][tr * 8];
            float4 w1 = *(const float4*)&wt[kk][tr * 8 + 4];
            float4 g0 = *(const float4*)&gt[kk][tc * 8];
            float4 g1 = *(const float4*)&gt[kk][tc * 8 + 4];
            float wf[8] = {w0.x, w0.y, w0.z, w0.w, w1.x, w1.y, w1.z, w1.w};
            float gf[8] = {g0.x, g0.y, g0.z, g0.w, g1.x, g1.y, g1.z, g1.w};
            #pragma unroll
            for (int i = 0; i < 8; i++)
                #pragma unroll
                for (int j = 0; j < 8; j++) acc[i][j] += wf[i] * gf[j];
        }
        __syncthreads();
    }
    float* pp = partial + (size_t)blk * 16384;
    #pragma unroll
    for (int i = 0; i < 8; i++) {
        #pragma unroll
        for (int j4 = 0; j4 < 2; j4++) {
            float4 o = make_float4(acc[i][j4 * 4], acc[i][j4 * 4 + 1],
                                   acc[i][j4 * 4 + 2], acc[i][j4 * 4 + 3]);
            *(float4*)&pp[(size_t)(tr * 8 + i) * 128 + tc * 8 + j4 * 4] = o;
        }
    }
}

// ---------------- reduce partials -> gb_raw ------------------------------------
__global__ __launch_bounds__(256) void k_reduceG(
    const float* __restrict__ partial, float* __restrict__ gb_raw)
{
    int g = blockIdx.x * 256 + threadIdx.x;   // 0..32767
    int t2 = g & 127;
    int s = (g >> 7) & 127;
    int b = g >> 14;
    const float* pp = partial + (size_t)b * G_KB * 16384 + (size_t)s * 128 + t2;
    float sum = 0.f;
    #pragma unroll 8
    for (int kb = 0; kb < G_KB; kb++) sum += pp[(size_t)kb * 16384];
    gb_raw[(size_t)b * 16384 + (size_t)s * 128 + t2] = sum;
}

// ---------------- K4b: symmetrize, row-normalize, log --------------------------
__global__ __launch_bounds__(128) void k_gb_fin(
    const float* __restrict__ gb_raw, float* __restrict__ gb)
{
    int bid = blockIdx.x;
    int b = bid >> 7, i = bid & 127;
    int j = threadIdx.x;
    const float* gr = gb_raw + (size_t)b * Sn * Sn;
    float sym = 0.5f * (gr[i * Sn + j] + gr[j * Sn + i]);
    float sum = sym;
    #pragma unroll
    for (int d = 1; d < 64; d <<= 1) sum += __shfl_xor(sum, d);
    __shared__ float wred[2];
    if ((j & 63) == 0) wred[j >> 6] = sum;
    __syncthreads();
    sum = wred[0] + wred[1];
    float r = fmaxf(sum, EPSf);
    gb[(size_t)b * Sn * Sn + (size_t)i * Sn + j] = logf(fmaxf(sym / r, EPSf));
}

// ---------------- K5/K7: out[m,c] = in[m,:] @ W[:,c] + bias[c], M=256 ----------
__global__ __launch_bounds__(256) void k_lin(
    const float* __restrict__ in, const float* __restrict__ W,
    const float* __restrict__ bias, float* __restrict__ out)
{
    __shared__ float it[8][512];
    int t = threadIdx.x;
    int m0 = blockIdx.x * 8;
    int c = blockIdx.y * 256 + t;
    #pragma unroll
    for (int l = 0; l < 16; l++) {
        int idx = t + l * 256;
        int r = idx >> 9, kk = idx & 511;
        it[r][kk] = in[(size_t)(m0 + r) * Cn + kk];
    }
    __syncthreads();
    float acc[8] = {0.f,0.f,0.f,0.f,0.f,0.f,0.f,0.f};
    #pragma unroll 4
    for (int kk = 0; kk < Cn; kk++) {
        float wv = W[(size_t)kk * Cn + c];
        #pragma unroll
        for (int r = 0; r < 8; r++) acc[r] += it[r][kk] * wv;
    }
    float bv = bias[c];
    #pragma unroll
    for (int r = 0; r < 8; r++) out[(size_t)(m0 + r) * Cn + c] = acc[r] + bv;
}

// ---------------- K6: attention per (b,h,i) ------------------------------------
__global__ __launch_bounds__(128) void k_attn(
    const float* __restrict__ q, const float* __restrict__ k,
    const float* __restrict__ v, const float* __restrict__ gb,
    const float* __restrict__ beta_raw, float* __restrict__ attn_out)
{
    __shared__ float kv[128][65];
    __shared__ float qv[64];
    __shared__ float p[128];
    __shared__ float wred[2][2];

    int t = threadIdx.x;
    int bid = blockIdx.x;
    int b = bid / (Hn * Sn);
    int h = (bid / Sn) % Hn;
    int i = bid % Sn;
    size_t base = (size_t)b * Sn * Cn + (size_t)h * Dn;

    if (t < 64) qv[t] = q[base + (size_t)i * Cn + t];
    for (int l = 0; l < 64; l++) {
        int idx = t + l * 128;
        int j = idx >> 6, d = idx & 63;
        kv[j][d] = k[base + (size_t)j * Cn + d];
    }
    __syncthreads();

    float dot = 0.f;
    #pragma unroll
    for (int d = 0; d < 64; d++) dot += qv[d] * kv[t][d];

    float beta = log1pf(__expf(beta_raw[0]));
    float logit = dot * 0.125f + beta * gb[(size_t)b * Sn * Sn + (size_t)i * Sn + t];

    float m = logit;
    #pragma unroll
    for (int d = 1; d < 64; d <<= 1) m = fmaxf(m, __shfl_xor(m, d));
    if ((t & 63) == 0) wred[0][t >> 6] = m;
    __syncthreads();
    m = fmaxf(wred[0][0], wred[0][1]);
    float e = __expf(logit - m);
    float sm = e;
    #pragma unroll
    for (int d = 1; d < 64; d <<= 1) sm += __shfl_xor(sm, d);
    if ((t & 63) == 0) wred[1][t >> 6] = sm;
    __syncthreads();
    sm = wred[1][0] + wred[1][1];
    p[t] = e / sm;
    __syncthreads();

    for (int l = 0; l < 64; l++) {
        int idx = t + l * 128;
        int j = idx >> 6, d = idx & 63;
        kv[j][d] = v[base + (size_t)j * Cn + d];
    }
    __syncthreads();

    if (t < 64) {
        float o = 0.f;
        #pragma unroll 8
        for (int j = 0; j < 128; j++) o += p[j] * kv[j][t];
        attn_out[base + (size_t)i * Cn + t] = o;
    }
}

// ---------------- K8: out[b,n,c] = sum_s w[b,n,s] * so[b,s,c] ------------------
__global__ __launch_bounds__(256) void k_out(
    const float* __restrict__ weights, const float* __restrict__ so,
    float* __restrict__ out)
{
    __shared__ float wt[16][68];
    __shared__ float st[16][68];
    int t = threadIdx.x;
    int tc = t & 15, tr = t >> 4;
    int blk = blockIdx.x;
    int b = blk / (NBLK * 8);
    int rb = (blk / 8) % NBLK;
    int cb = blk & 7;
    int n0 = rb * 64, c0 = cb * 64;
    const float* wb = weights + (size_t)b * Nn * Sn;
    const float* sb = so + (size_t)b * Sn * Cn;

    float acc[4][4];
    #pragma unroll
    for (int i = 0; i < 4; i++)
        #pragma unroll
        for (int j = 0; j < 4; j++) acc[i][j] = 0.f;

    for (int k0 = 0; k0 < Sn; k0 += 16) {
        #pragma unroll
        for (int l = 0; l < 4; l++) {
            int idx = t + l * 256;
            int r = idx >> 4, kk = idx & 15;
            int n = n0 + r;
            wt[kk][r] = (n < Nn) ? wb[(size_t)n * Sn + k0 + kk] : 0.f;
        }
        #pragma unroll
        for (int l = 0; l < 4; l++) {
            int idx = t + l * 256;
            int kk = idx >> 6, c = idx & 63;
            st[kk][c] = sb[(size_t)(k0 + kk) * Cn + c0 + c];
        }
        __syncthreads();
        #pragma unroll
        for (int kk = 0; kk < 16; kk++) {
            float4 sv = *(const float4*)&st[kk][tc * 4];
            float4 wv = *(const float4*)&wt[kk][tr * 4];
            float wf[4] = {wv.x, wv.y, wv.z, wv.w};
            float sf[4] = {sv.x, sv.y, sv.z, sv.w};
            #pragma unroll
            for (int i = 0; i < 4; i++)
                #pragma unroll
                for (int j = 0; j < 4; j++) acc[i][j] += wf[i] * sf[j];
        }
        __syncthreads();
    }
    #pragma unroll
    for (int i = 0; i < 4; i++) {
        int n = n0 + tr * 4 + i;
        if (n < Nn) {
            float4 o = make_float4(acc[i][0], acc[i][1], acc[i][2], acc[i][3]);
            *(float4*)&out[((size_t)b * Nn + n) * Cn + c0 + tc * 4] = o;
        }
    }
}

extern "C" void kernel_launch(void* const* d_in, const int* in_sizes, int n_in,
                              void* d_out, int out_size, void* d_ws, size_t ws_size,
                              hipStream_t stream)
{
    const float* x  = (const float*)d_in[0];
    const int* adj  = (const int*)d_in[1];
    const float* av = (const float*)d_in[2];
    const float* Ws = (const float*)d_in[3];
    const float* bs = (const float*)d_in[4];
    const float* Wq = (const float*)d_in[5];
    const float* bq = (const float*)d_in[6];
    const float* Wk = (const float*)d_in[7];
    const float* bk = (const float*)d_in[8];
    const float* Wv = (const float*)d_in[9];
    const float* bv = (const float*)d_in[10];
    const float* Wo = (const float*)d_in[11];
    const float* bo = (const float*)d_in[12];
    const float* br = (const float*)d_in[13];
    float* out = (float*)d_out;
    (void)in_sizes; (void)n_in; (void)out_size; (void)ws_size;

    char* ws = (char*)d_ws;
    size_t off = 0;
    float* weights    = (float*)(ws + off); off += (size_t)Bn * Nn * Sn * 4;   // 20.48 MB
    float* gw         = (float*)(ws + off); off += (size_t)Bn * Nn * Sn * 4;   // 20.48 MB
    float* slices     = (float*)(ws + off); off += (size_t)Bn * Sn * Cn * 4;
    float* wsum       = (float*)(ws + off); off += 1024;
    float* gb_raw     = (float*)(ws + off); off += (size_t)Bn * Sn * Sn * 4;
    float* gb         = (float*)(ws + off); off += (size_t)Bn * Sn * Sn * 4;
    float* q          = (float*)(ws + off); off += (size_t)Bn * Sn * Cn * 4;
    float* kbuf       = (float*)(ws + off); off += (size_t)Bn * Sn * Cn * 4;
    float* vbuf       = (float*)(ws + off); off += (size_t)Bn * Sn * Cn * 4;
    float* attn_out   = (float*)(ws + off); off += (size_t)Bn * Sn * Cn * 4;
    float* slices_out = (float*)(ws + off); off += (size_t)Bn * Sn * Cn * 4;
    // Union region U (21 MB): CSR buffers live [k_deg .. k_gather], then
    // partialS lives [k_slices2 .. k_reduceS], then partialG [k_gb2 .. k_reduceG].
    char* U = ws + off;
    int* deg    = (int*)(U);                // 80,128 B (pad)
    int* cursor = (int*)(U + 80128);        // 80,128 B
    int* offs   = (int*)(U + 160256);       // 80,384 B (N+1 ints, pad)
    int* eid    = (int*)(U + 240640);       // 1,280,000 B
    float* partialS = (float*)U;            // 320 * 64 KB = 20.97 MB
    float* partialG = (float*)U;            // 160 * 64 KB = 10.49 MB

    // zero: wsum + CSR deg/cursor (contiguous)
    hipMemsetAsync(wsum, 0, 1024, stream);
    hipMemsetAsync(U, 0, 160256, stream);

    k_assign<<<Bn * NBLK, 256, 0, stream>>>(x, Ws, bs, weights, wsum);

    // CSR build + gather (replaces 82M-atomic scatter)
    k_deg<<<(En + 255) / 256, 256, 0, stream>>>(adj, deg);
    k_scan<<<1, 256, 0, stream>>>(deg, offs);
    k_fill<<<(En + 255) / 256, 256, 0, stream>>>(adj, offs, cursor, eid);
    k_gather<<<Nn, 128, 0, stream>>>(weights, adj, av, offs, eid, gw);

    // slices = wT @ x / wsum  (partials + reduce; clobbers CSR region, which is dead)
    k_slices2<<<Bn * 4 * S_KB, 256, 0, stream>>>(weights, x, partialS);
    k_reduceS<<<(Bn * Sn * Cn) / 256, 256, 0, stream>>>(partialS, wsum, slices);

    // gb_raw = wT @ gw (partials + reduce)
    k_gb2<<<Bn * G_KB, 256, 0, stream>>>(weights, gw, partialG);
    k_reduceG<<<(Bn * Sn * Sn) / 256, 256, 0, stream>>>(partialG, gb_raw);
    k_gb_fin<<<Bn * Sn, 128, 0, stream>>>(gb_raw, gb);

    k_lin<<<dim3(32, 2), 256, 0, stream>>>(slices, Wq, bq, q);
    k_lin<<<dim3(32, 2), 256, 0, stream>>>(slices, Wk, bk, kbuf);
    k_lin<<<dim3(32, 2), 256, 0, stream>>>(slices, Wv, bv, vbuf);
    k_attn<<<Bn * Hn * Sn, 128, 0, stream>>>(q, kbuf, vbuf, gb, br, attn_out);
    k_lin<<<dim3(32, 2), 256, 0, stream>>>(attn_out, Wo, bo, slices_out);
    k_out<<<Bn * NBLK * 8, 256, 0, stream>>>(weights, slices_out, out);
}

// Round 3
// 552.300 us; speedup vs baseline: 1.9662x; 1.4506x over previous
//
#include <hip/hip_runtime.h>
#include <math.h>

#define Bn 2
#define Nn 20000
#define Cn 512
#define Sn 128
#define Hn 8
#define Dn 64
#define En 320000
#define EPSf 1e-6f
#define NBLK 313  // ceil(20000/64)

#define S_CHUNK 320
#define S_KB 63        // ceil(20000/320)
#define G_CHUNK 128
#define G_KB 157       // ceil(20000/128)

typedef __attribute__((ext_vector_type(4))) float f32x4;
typedef __attribute__((ext_vector_type(8))) short s16x8;

__device__ __forceinline__ unsigned short f2bf(float f) {
    unsigned u = __float_as_uint(f);
    return (unsigned short)((u + 0x7fffu + ((u >> 16) & 1u)) >> 16);
}
__device__ __forceinline__ float bf2f(unsigned short h) {
    return __uint_as_float(((unsigned)h) << 16);
}

// Swizzled LDS byte offset for a [128 rows][64 n] bf16 tile.
// Reads (16B chunks, n mult of 8): 2-way bank aliasing (free).
// Writes (u32 n-pairs): 2-way. Derivation in session notes.
__device__ __forceinline__ unsigned lds_off(int row, int n) {
    unsigned ch = ((((unsigned)n >> 3) ^ ((unsigned)row & 7u) ^ (((unsigned)row >> 3) & 7u)) & 7u);
    return (unsigned)row * 128u + ch * 16u + ((unsigned)n & 7u) * 2u;
}

// ---------------- K1: weights = softmax(x @ Ws + bs) -> bf16, accumulate wsum --
__global__ __launch_bounds__(256) void k_assign(
    const float* __restrict__ x, const float* __restrict__ Ws,
    const float* __restrict__ bs, unsigned short* __restrict__ weights,
    float* __restrict__ wsum)
{
    __shared__ float xt[32][68];
    __shared__ float wst[32][128];
    __shared__ float wsum_loc[128];

    int t = threadIdx.x;
    int tc = t & 31, tr = t >> 5;
    int b = blockIdx.x / NBLK;
    int rb = blockIdx.x % NBLK;
    int n0 = rb * 64;

    if (t < 128) wsum_loc[t] = 0.f;

    float acc[8][4];
    #pragma unroll
    for (int i = 0; i < 8; i++) {
        #pragma unroll
        for (int j = 0; j < 4; j++) acc[i][j] = 0.f;
    }

    const float* xb = x + (size_t)b * Nn * Cn;

    for (int k0 = 0; k0 < Cn; k0 += 32) {
        #pragma unroll
        for (int l = 0; l < 8; l++) {
            int idx = t + l * 256;
            int r = idx >> 5, kk = idx & 31;
            int n = n0 + r;
            xt[kk][r] = (n < Nn) ? xb[(size_t)n * Cn + k0 + kk] : 0.f;
        }
        #pragma unroll
        for (int l = 0; l < 16; l++) {
            int idx = t + l * 256;
            int kk = idx >> 7, s = idx & 127;
            wst[kk][s] = Ws[(size_t)(k0 + kk) * Sn + s];
        }
        __syncthreads();
        #pragma unroll
        for (int kk = 0; kk < 32; kk++) {
            float4 wv = *(const float4*)&wst[kk][tc * 4];
            float4 xa = *(const float4*)&xt[kk][tr * 8];
            float4 xc = *(const float4*)&xt[kk][tr * 8 + 4];
            float xs[8] = {xa.x, xa.y, xa.z, xa.w, xc.x, xc.y, xc.z, xc.w};
            float wf[4] = {wv.x, wv.y, wv.z, wv.w};
            #pragma unroll
            for (int i = 0; i < 8; i++) {
                #pragma unroll
                for (int j = 0; j < 4; j++) acc[i][j] += xs[i] * wf[j];
            }
        }
        __syncthreads();
    }

    float bsv[4];
    #pragma unroll
    for (int j = 0; j < 4; j++) bsv[j] = bs[tc * 4 + j];

    float wacc[4] = {0.f, 0.f, 0.f, 0.f};
    unsigned short* wb = weights + (size_t)b * Nn * Sn;
    #pragma unroll
    for (int i = 0; i < 8; i++) {
        int n = n0 + tr * 8 + i;
        float l0 = acc[i][0] + bsv[0];
        float l1 = acc[i][1] + bsv[1];
        float l2 = acc[i][2] + bsv[2];
        float l3 = acc[i][3] + bsv[3];
        float m = fmaxf(fmaxf(l0, l1), fmaxf(l2, l3));
        #pragma unroll
        for (int d = 1; d < 32; d <<= 1) m = fmaxf(m, __shfl_xor(m, d));
        float e0 = __expf(l0 - m), e1 = __expf(l1 - m);
        float e2 = __expf(l2 - m), e3 = __expf(l3 - m);
        float sm = e0 + e1 + e2 + e3;
        #pragma unroll
        for (int d = 1; d < 32; d <<= 1) sm += __shfl_xor(sm, d);
        float inv = 1.f / sm;
        if (n < Nn) {
            float w0 = e0 * inv, w1 = e1 * inv, w2 = e2 * inv, w3 = e3 * inv;
            ushort4 st = make_ushort4(f2bf(w0), f2bf(w1), f2bf(w2), f2bf(w3));
            *(ushort4*)&wb[(size_t)n * Sn + tc * 4] = st;
            wacc[0] += w0; wacc[1] += w1; wacc[2] += w2; wacc[3] += w3;
        }
    }
    __syncthreads();
    #pragma unroll
    for (int j = 0; j < 4; j++) atomicAdd(&wsum_loc[tc * 4 + j], wacc[j]);
    __syncthreads();
    if (t < 128) atomicAdd(&wsum[b * Sn + t], wsum_loc[t]);
}

// ---------------- CSR build: degree histogram ----------------------------------
__global__ __launch_bounds__(256) void k_deg(
    const int* __restrict__ adj, int* __restrict__ deg)
{
    int e = blockIdx.x * 256 + threadIdx.x;
    if (e < En) atomicAdd(&deg[adj[e]], 1);
}

// ---------------- CSR build: single-block prefix scan over N -------------------
__global__ __launch_bounds__(1024) void k_scan(
    const int* __restrict__ deg, int* __restrict__ offs)
{
    __shared__ int buf[1024];
    __shared__ int runs;
    int t = threadIdx.x;
    if (t == 0) { offs[0] = 0; runs = 0; }
    __syncthreads();
    for (int base = 0; base < Nn; base += 1024) {
        int v = (base + t < Nn) ? deg[base + t] : 0;
        buf[t] = v;
        __syncthreads();
        #pragma unroll
        for (int d = 1; d < 1024; d <<= 1) {
            int add = (t >= d) ? buf[t - d] : 0;
            __syncthreads();
            buf[t] += add;
            __syncthreads();
        }
        if (base + t < Nn) offs[base + t + 1] = runs + buf[t];
        __syncthreads();
        if (t == 1023) runs += buf[1023];
        __syncthreads();
    }
}

// ---------------- CSR build: fill edge ids -------------------------------------
__global__ __launch_bounds__(256) void k_fill(
    const int* __restrict__ adj, const int* __restrict__ offs,
    int* __restrict__ cursor, int* __restrict__ eid)
{
    int e = blockIdx.x * 256 + threadIdx.x;
    if (e < En) {
        int r = adj[e];
        int p = atomicAdd(&cursor[r], 1);
        eid[offs[r] + p] = e;
    }
}

// ---------------- K3': gw[b,r,:] = sum_{e in row r} v_e * w[b,col_e,:] ---------
__global__ __launch_bounds__(128) void k_gather(
    const unsigned short* __restrict__ weights, const int* __restrict__ adj,
    const float* __restrict__ vals, const int* __restrict__ offs,
    const int* __restrict__ eid, float* __restrict__ gw)
{
    int r = blockIdx.x;
    int s = threadIdx.x;
    int o0 = offs[r], o1 = offs[r + 1];
    const unsigned short* w0 = weights;
    const unsigned short* w1 = weights + (size_t)Nn * Sn;
    float a0 = 0.f, a1 = 0.f;
    for (int j = o0; j < o1; j++) {
        int e = eid[j];
        int c = adj[En + e];
        float v = vals[e];
        a0 += v * bf2f(w0[(size_t)c * Sn + s]);
        a1 += v * bf2f(w1[(size_t)c * Sn + s]);
    }
    gw[(size_t)r * Sn + s] = a0;
    gw[(size_t)Nn * Sn + (size_t)r * Sn + s] = a1;
}

// ---------------- staging: 64 n-rows x 128 cols of A(bf16) and B(f32) ----------
__device__ __forceinline__ void stage_tiles(
    const unsigned short* __restrict__ wA, const float* __restrict__ Bsrc,
    int Bstride, int c0, int nbase, unsigned* At32, unsigned* Bt32, int t)
{
    int c = t & 15;
    int p0 = t >> 4;
    #pragma unroll
    for (int half = 0; half < 2; half++) {
        int pp = p0 + half * 16;      // pair index 0..31
        int nl = 2 * pp;              // local row (even)
        int ng = nbase + nl;
        // ---- A (bf16 source) ----
        s16x8 a0 = {0,0,0,0,0,0,0,0}, a1 = {0,0,0,0,0,0,0,0};
        if (ng < Nn)     a0 = *(const s16x8*)(wA + (size_t)ng * Sn + 8 * c);
        if (ng + 1 < Nn) a1 = *(const s16x8*)(wA + (size_t)(ng + 1) * Sn + 8 * c);
        #pragma unroll
        for (int i = 0; i < 8; i++) {
            unsigned val = ((unsigned)(unsigned short)a0[i]) |
                           (((unsigned)(unsigned short)a1[i]) << 16);
            At32[lds_off(8 * c + i, nl) >> 2] = val;
        }
        // ---- B (f32 source) ----
        float b0[8], b1[8];
        if (ng < Nn) {
            float4 v0 = *(const float4*)(Bsrc + (size_t)ng * Bstride + c0 + 8 * c);
            float4 v1 = *(const float4*)(Bsrc + (size_t)ng * Bstride + c0 + 8 * c + 4);
            b0[0]=v0.x; b0[1]=v0.y; b0[2]=v0.z; b0[3]=v0.w;
            b0[4]=v1.x; b0[5]=v1.y; b0[6]=v1.z; b0[7]=v1.w;
        } else {
            #pragma unroll
            for (int i = 0; i < 8; i++) b0[i] = 0.f;
        }
        if (ng + 1 < Nn) {
            float4 v0 = *(const float4*)(Bsrc + (size_t)(ng + 1) * Bstride + c0 + 8 * c);
            float4 v1 = *(const float4*)(Bsrc + (size_t)(ng + 1) * Bstride + c0 + 8 * c + 4);
            b1[0]=v0.x; b1[1]=v0.y; b1[2]=v0.z; b1[3]=v0.w;
            b1[4]=v1.x; b1[5]=v1.y; b1[6]=v1.z; b1[7]=v1.w;
        } else {
            #pragma unroll
            for (int i = 0; i < 8; i++) b1[i] = 0.f;
        }
        #pragma unroll
        for (int i = 0; i < 8; i++) {
            unsigned val = (unsigned)f2bf(b0[i]) | (((unsigned)f2bf(b1[i])) << 16);
            Bt32[lds_off(8 * c + i, nl) >> 2] = val;
        }
    }
}

// ---------------- K2'/K4': partial[s][c] = sum_{n in chunk} w[n,s]*B[n,c] ------
// MFMA 16x16x32 bf16. Block: 4 waves, 128x128 output tile over one K-chunk.
__global__ __launch_bounds__(256) void k_mm(
    const unsigned short* __restrict__ wAall, const float* __restrict__ Ball,
    int Bstride, int nCb, int kbCount, int chunk,
    float* __restrict__ partial)
{
    __shared__ __align__(16) unsigned At32[4096];
    __shared__ __align__(16) unsigned Bt32[4096];
    int t = threadIdx.x;
    int lane = t & 63;
    int wid = t >> 6;
    int ws = wid & 1, wc = wid >> 1;
    int blk = blockIdx.x;
    int b = blk / (nCb * kbCount);
    int rem = blk % (nCb * kbCount);
    int cb = rem / kbCount;
    int kb = rem % kbCount;
    int n0 = kb * chunk;
    int c0 = cb * 128;
    const unsigned short* wA = wAall + (size_t)b * Nn * Sn;
    const float* Bsrc = Ball + (size_t)b * Nn * Bstride;

    f32x4 acc[4][4];
    const f32x4 fz = {0.f, 0.f, 0.f, 0.f};
    #pragma unroll
    for (int i = 0; i < 4; i++) {
        #pragma unroll
        for (int j = 0; j < 4; j++) acc[i][j] = fz;
    }

    int l15 = lane & 15, lg = lane >> 4;

    for (int kt = 0; kt < chunk; kt += 64) {
        stage_tiles(wA, Bsrc, Bstride, c0, n0 + kt, At32, Bt32, t);
        __syncthreads();
        #pragma unroll
        for (int m = 0; m < 2; m++) {
            s16x8 af[4], bfr[4];
            #pragma unroll
            for (int i = 0; i < 4; i++) {
                int row = ws * 64 + i * 16 + l15;
                af[i] = *(const s16x8*)((const char*)At32 + lds_off(row, m * 32 + lg * 8));
            }
            #pragma unroll
            for (int j = 0; j < 4; j++) {
                int row = wc * 64 + j * 16 + l15;
                bfr[j] = *(const s16x8*)((const char*)Bt32 + lds_off(row, m * 32 + lg * 8));
            }
            #pragma unroll
            for (int i = 0; i < 4; i++) {
                #pragma unroll
                for (int j = 0; j < 4; j++)
                    acc[i][j] = __builtin_amdgcn_mfma_f32_16x16x32_bf16(
                        af[i], bfr[j], acc[i][j], 0, 0, 0);
            }
        }
        __syncthreads();
    }

    float* pp = partial + (size_t)blk * 16384;
    #pragma unroll
    for (int i = 0; i < 4; i++) {
        int srow = ws * 64 + i * 16 + lg * 4;
        #pragma unroll
        for (int j = 0; j < 4; j++) {
            int ccol = wc * 64 + j * 16 + l15;
            #pragma unroll
            for (int r = 0; r < 4; r++)
                pp[(size_t)(srow + r) * 128 + ccol] = acc[i][j][r];
        }
    }
}

// ---------------- reduce partials -> slices (with /wsum) -----------------------
__global__ __launch_bounds__(256) void k_reduceS(
    const float* __restrict__ partial, const float* __restrict__ wsum,
    float* __restrict__ slices)
{
    int g = blockIdx.x * 256 + threadIdx.x;   // 0..131071
    int c = g & 127;
    int s = (g >> 7) & 127;
    int cb = (g >> 14) & 3;
    int b = g >> 16;
    const float* pp = partial + (size_t)(b * 4 + cb) * S_KB * 16384 + (size_t)s * 128 + c;
    float sum = 0.f;
    #pragma unroll 7
    for (int kb = 0; kb < S_KB; kb++) sum += pp[(size_t)kb * 16384];
    slices[((size_t)b * Sn + s) * Cn + cb * 128 + c] = sum / fmaxf(wsum[b * Sn + s], EPSf);
}

// ---------------- reduce partials -> gb_raw ------------------------------------
__global__ __launch_bounds__(256) void k_reduceG(
    const float* __restrict__ partial, float* __restrict__ gb_raw)
{
    int g = blockIdx.x * 256 + threadIdx.x;   // 0..32767
    int t2 = g & 127;
    int s = (g >> 7) & 127;
    int b = g >> 14;
    const float* pp = partial + (size_t)b * G_KB * 16384 + (size_t)s * 128 + t2;
    float sum = 0.f;
    #pragma unroll 8
    for (int kb = 0; kb < G_KB; kb++) sum += pp[(size_t)kb * 16384];
    gb_raw[(size_t)b * 16384 + (size_t)s * 128 + t2] = sum;
}

// ---------------- K4b: symmetrize, row-normalize, log --------------------------
__global__ __launch_bounds__(128) void k_gb_fin(
    const float* __restrict__ gb_raw, float* __restrict__ gb)
{
    int bid = blockIdx.x;
    int b = bid >> 7, i = bid & 127;
    int j = threadIdx.x;
    const float* gr = gb_raw + (size_t)b * Sn * Sn;
    float sym = 0.5f * (gr[i * Sn + j] + gr[j * Sn + i]);
    float sum = sym;
    #pragma unroll
    for (int d = 1; d < 64; d <<= 1) sum += __shfl_xor(sum, d);
    __shared__ float wred[2];
    if ((j & 63) == 0) wred[j >> 6] = sum;
    __syncthreads();
    sum = wred[0] + wred[1];
    float r = fmaxf(sum, EPSf);
    gb[(size_t)b * Sn * Sn + (size_t)i * Sn + j] = logf(fmaxf(sym / r, EPSf));
}

// ---------------- K5/K7: out[m,c] = in[m,:] @ W[:,c] + bias[c], M=256 ----------
__global__ __launch_bounds__(256) void k_lin(
    const float* __restrict__ in, const float* __restrict__ W,
    const float* __restrict__ bias, float* __restrict__ out)
{
    __shared__ float it[8][512];
    int t = threadIdx.x;
    int m0 = blockIdx.x * 8;
    int c = blockIdx.y * 256 + t;
    #pragma unroll
    for (int l = 0; l < 16; l++) {
        int idx = t + l * 256;
        int r = idx >> 9, kk = idx & 511;
        it[r][kk] = in[(size_t)(m0 + r) * Cn + kk];
    }
    __syncthreads();
    float acc[8] = {0.f,0.f,0.f,0.f,0.f,0.f,0.f,0.f};
    #pragma unroll 4
    for (int kk = 0; kk < Cn; kk++) {
        float wv = W[(size_t)kk * Cn + c];
        #pragma unroll
        for (int r = 0; r < 8; r++) acc[r] += it[r][kk] * wv;
    }
    float bv = bias[c];
    #pragma unroll
    for (int r = 0; r < 8; r++) out[(size_t)(m0 + r) * Cn + c] = acc[r] + bv;
}

// ---------------- K6: attention per (b,h,i) ------------------------------------
__global__ __launch_bounds__(128) void k_attn(
    const float* __restrict__ q, const float* __restrict__ k,
    const float* __restrict__ v, const float* __restrict__ gb,
    const float* __restrict__ beta_raw, float* __restrict__ attn_out)
{
    __shared__ float kv[128][65];
    __shared__ float qv[64];
    __shared__ float p[128];
    __shared__ float wred[2][2];

    int t = threadIdx.x;
    int bid = blockIdx.x;
    int b = bid / (Hn * Sn);
    int h = (bid / Sn) % Hn;
    int i = bid % Sn;
    size_t base = (size_t)b * Sn * Cn + (size_t)h * Dn;

    if (t < 64) qv[t] = q[base + (size_t)i * Cn + t];
    for (int l = 0; l < 64; l++) {
        int idx = t + l * 128;
        int j = idx >> 6, d = idx & 63;
        kv[j][d] = k[base + (size_t)j * Cn + d];
    }
    __syncthreads();

    float dot = 0.f;
    #pragma unroll
    for (int d = 0; d < 64; d++) dot += qv[d] * kv[t][d];

    float beta = log1pf(__expf(beta_raw[0]));
    float logit = dot * 0.125f + beta * gb[(size_t)b * Sn * Sn + (size_t)i * Sn + t];

    float m = logit;
    #pragma unroll
    for (int d = 1; d < 64; d <<= 1) m = fmaxf(m, __shfl_xor(m, d));
    if ((t & 63) == 0) wred[0][t >> 6] = m;
    __syncthreads();
    m = fmaxf(wred[0][0], wred[0][1]);
    float e = __expf(logit - m);
    float sm = e;
    #pragma unroll
    for (int d = 1; d < 64; d <<= 1) sm += __shfl_xor(sm, d);
    if ((t & 63) == 0) wred[1][t >> 6] = sm;
    __syncthreads();
    sm = wred[1][0] + wred[1][1];
    p[t] = e / sm;
    __syncthreads();

    for (int l = 0; l < 64; l++) {
        int idx = t + l * 128;
        int j = idx >> 6, d = idx & 63;
        kv[j][d] = v[base + (size_t)j * Cn + d];
    }
    __syncthreads();

    if (t < 64) {
        float o = 0.f;
        #pragma unroll 8
        for (int j = 0; j < 128; j++) o += p[j] * kv[j][t];
        attn_out[base + (size_t)i * Cn + t] = o;
    }
}

// ---------------- K8: out[b,n,c] = sum_s w[b,n,s] * so[b,s,c] ------------------
__global__ __launch_bounds__(256) void k_out(
    const unsigned short* __restrict__ weights, const float* __restrict__ so,
    float* __restrict__ out)
{
    __shared__ float wt[16][68];
    __shared__ float st[16][68];
    int t = threadIdx.x;
    int tc = t & 15, tr = t >> 4;
    int blk = blockIdx.x;
    int b = blk / (NBLK * 8);
    int rb = (blk / 8) % NBLK;
    int cb = blk & 7;
    int n0 = rb * 64, c0 = cb * 64;
    const unsigned short* wb = weights + (size_t)b * Nn * Sn;
    const float* sb = so + (size_t)b * Sn * Cn;

    float acc[4][4];
    #pragma unroll
    for (int i = 0; i < 4; i++) {
        #pragma unroll
        for (int j = 0; j < 4; j++) acc[i][j] = 0.f;
    }

    for (int k0 = 0; k0 < Sn; k0 += 16) {
        #pragma unroll
        for (int l = 0; l < 4; l++) {
            int idx = t + l * 256;
            int r = idx >> 4, kk = idx & 15;
            int n = n0 + r;
            wt[kk][r] = (n < Nn) ? bf2f(wb[(size_t)n * Sn + k0 + kk]) : 0.f;
        }
        #pragma unroll
        for (int l = 0; l < 4; l++) {
            int idx = t + l * 256;
            int kk = idx >> 6, c = idx & 63;
            st[kk][c] = sb[(size_t)(k0 + kk) * Cn + c0 + c];
        }
        __syncthreads();
        #pragma unroll
        for (int kk = 0; kk < 16; kk++) {
            float4 sv = *(const float4*)&st[kk][tc * 4];
            float4 wv = *(const float4*)&wt[kk][tr * 4];
            float wf[4] = {wv.x, wv.y, wv.z, wv.w};
            float sf[4] = {sv.x, sv.y, sv.z, sv.w};
            #pragma unroll
            for (int i = 0; i < 4; i++) {
                #pragma unroll
                for (int j = 0; j < 4; j++) acc[i][j] += wf[i] * sf[j];
            }
        }
        __syncthreads();
    }
    #pragma unroll
    for (int i = 0; i < 4; i++) {
        int n = n0 + tr * 4 + i;
        if (n < Nn) {
            float4 o = make_float4(acc[i][0], acc[i][1], acc[i][2], acc[i][3]);
            *(float4*)&out[((size_t)b * Nn + n) * Cn + c0 + tc * 4] = o;
        }
    }
}

extern "C" void kernel_launch(void* const* d_in, const int* in_sizes, int n_in,
                              void* d_out, int out_size, void* d_ws, size_t ws_size,
                              hipStream_t stream)
{
    const float* x  = (const float*)d_in[0];
    const int* adj  = (const int*)d_in[1];
    const float* av = (const float*)d_in[2];
    const float* Ws = (const float*)d_in[3];
    const float* bs = (const float*)d_in[4];
    const float* Wq = (const float*)d_in[5];
    const float* bq = (const float*)d_in[6];
    const float* Wk = (const float*)d_in[7];
    const float* bk = (const float*)d_in[8];
    const float* Wv = (const float*)d_in[9];
    const float* bv = (const float*)d_in[10];
    const float* Wo = (const float*)d_in[11];
    const float* bo = (const float*)d_in[12];
    const float* br = (const float*)d_in[13];
    float* out = (float*)d_out;
    (void)in_sizes; (void)n_in; (void)out_size; (void)ws_size;

    char* ws = (char*)d_ws;
    size_t off = 0;
    unsigned short* wb16 = (unsigned short*)(ws + off); off += (size_t)Bn * Nn * Sn * 2; // 10.24 MB
    float* gw         = (float*)(ws + off); off += (size_t)Bn * Nn * Sn * 4;             // 20.48 MB
    float* slices     = (float*)(ws + off); off += (size_t)Bn * Sn * Cn * 4;
    float* wsum       = (float*)(ws + off); off += 1024;
    float* gb_raw     = (float*)(ws + off); off += (size_t)Bn * Sn * Sn * 4;
    float* gb         = (float*)(ws + off); off += (size_t)Bn * Sn * Sn * 4;
    float* q          = (float*)(ws + off); off += (size_t)Bn * Sn * Cn * 4;
    float* kbuf       = (float*)(ws + off); off += (size_t)Bn * Sn * Cn * 4;
    float* vbuf       = (float*)(ws + off); off += (size_t)Bn * Sn * Cn * 4;
    float* attn_out   = (float*)(ws + off); off += (size_t)Bn * Sn * Cn * 4;
    float* slices_out = (float*)(ws + off); off += (size_t)Bn * Sn * Cn * 4;
    // Union region U: CSR buffers live [k_deg .. k_gather], then partialS
    // [k_mm(slices) .. k_reduceS], then partialG [k_mm(gb) .. k_reduceG].
    char* U = ws + off;
    int* deg    = (int*)(U);                // 80,128 B
    int* cursor = (int*)(U + 80128);        // 80,128 B
    int* offs   = (int*)(U + 160256);       // 80,384 B
    int* eid    = (int*)(U + 240640);       // 1,280,000 B
    float* partialS = (float*)U;            // 504 * 64 KB = 33.0 MB
    float* partialG = (float*)U;            // 314 * 64 KB = 20.6 MB

    hipMemsetAsync(wsum, 0, 1024, stream);
    hipMemsetAsync(U, 0, 160256, stream);   // deg + cursor

    k_assign<<<Bn * NBLK, 256, 0, stream>>>(x, Ws, bs, wb16, wsum);

    // CSR build + gather
    k_deg<<<(En + 255) / 256, 256, 0, stream>>>(adj, deg);
    k_scan<<<1, 1024, 0, stream>>>(deg, offs);
    k_fill<<<(En + 255) / 256, 256, 0, stream>>>(adj, offs, cursor, eid);
    k_gather<<<Nn, 128, 0, stream>>>(wb16, adj, av, offs, eid, gw);

    // slices = wT @ x / wsum  (MFMA partials + reduce; clobbers dead CSR region)
    k_mm<<<Bn * 4 * S_KB, 256, 0, stream>>>(wb16, x, Cn, 4, S_KB, S_CHUNK, partialS);
    k_reduceS<<<(Bn * Sn * Cn) / 256, 256, 0, stream>>>(partialS, wsum, slices);

    // gb_raw = wT @ gw (MFMA partials + reduce)
    k_mm<<<Bn * G_KB, 256, 0, stream>>>(wb16, gw, Sn, 1, G_KB, G_CHUNK, partialG);
    k_reduceG<<<(Bn * Sn * Sn) / 256, 256, 0, stream>>>(partialG, gb_raw);
    k_gb_fin<<<Bn * Sn, 128, 0, stream>>>(gb_raw, gb);

    k_lin<<<dim3(32, 2), 256, 0, stream>>>(slices, Wq, bq, q);
    k_lin<<<dim3(32, 2), 256, 0, stream>>>(slices, Wk, bk, kbuf);
    k_lin<<<dim3(32, 2), 256, 0, stream>>>(slices, Wv, bv, vbuf);
    k_attn<<<Bn * Hn * Sn, 128, 0, stream>>>(q, kbuf, vbuf, gb, br, attn_out);
    k_lin<<<dim3(32, 2), 256, 0, stream>>>(attn_out, Wo, bo, slices_out);
    k_out<<<Bn * NBLK * 8, 256, 0, stream>>>(wb16, slices_out, out);
}

// Round 4
// 432.222 us; speedup vs baseline: 2.5125x; 1.2778x over previous
//
#include <hip/hip_runtime.h>
#include <math.h>

#define Bn 2
#define Nn 20000
#define Cn 512
#define Sn 128
#define Hn 8
#define Dn 64
#define En 320000
#define EPSf 1e-6f
#define NBLK 313   // ceil(20000/64)
#define NB128 157  // ceil(20000/128)

#define S_CHUNK 320
#define S_KB 63        // ceil(20000/320)
#define G_CHUNK 128
#define G_KB 157       // ceil(20000/128)

typedef __attribute__((ext_vector_type(4))) float f32x4;
typedef __attribute__((ext_vector_type(8))) short s16x8;

__device__ __forceinline__ unsigned short f2bf(float f) {
    unsigned u = __float_as_uint(f);
    return (unsigned short)((u + 0x7fffu + ((u >> 16) & 1u)) >> 16);
}
__device__ __forceinline__ float bf2f(unsigned short h) {
    return __uint_as_float(((unsigned)h) << 16);
}

// Swizzled LDS byte offset for a [128 rows][64 k] bf16 tile.
// Frag reads (16B, k mult of 8): 2-way bank aliasing (free per m136).
__device__ __forceinline__ unsigned lds_off(int row, int n) {
    unsigned ch = ((((unsigned)n >> 3) ^ ((unsigned)row & 7u) ^ (((unsigned)row >> 3) & 7u)) & 7u);
    return (unsigned)row * 128u + ch * 16u + ((unsigned)n & 7u) * 2u;
}

// ---- stage [128 rows][64 k] bf16 tile from f32 row-major source ---------------
__device__ __forceinline__ void stage_f32tile(
    const float* __restrict__ src, int stride, int nvalid, unsigned* dst, int t)
{
    #pragma unroll
    for (int l = 0; l < 2; l++) {
        int task = t + l * 256;
        int row = task >> 2, seg = task & 3;
        float v[16];
        if (row < nvalid) {
            const float4* p = (const float4*)(src + (size_t)row * stride + seg * 16);
            float4 a = p[0], bq = p[1], c = p[2], d = p[3];
            v[0]=a.x; v[1]=a.y; v[2]=a.z; v[3]=a.w;
            v[4]=bq.x; v[5]=bq.y; v[6]=bq.z; v[7]=bq.w;
            v[8]=c.x; v[9]=c.y; v[10]=c.z; v[11]=c.w;
            v[12]=d.x; v[13]=d.y; v[14]=d.z; v[15]=d.w;
        } else {
            #pragma unroll
            for (int i = 0; i < 16; i++) v[i] = 0.f;
        }
        #pragma unroll
        for (int h = 0; h < 2; h++) {
            uint4 u;
            u.x = (unsigned)f2bf(v[h*8+0]) | (((unsigned)f2bf(v[h*8+1])) << 16);
            u.y = (unsigned)f2bf(v[h*8+2]) | (((unsigned)f2bf(v[h*8+3])) << 16);
            u.z = (unsigned)f2bf(v[h*8+4]) | (((unsigned)f2bf(v[h*8+5])) << 16);
            u.w = (unsigned)f2bf(v[h*8+6]) | (((unsigned)f2bf(v[h*8+7])) << 16);
            *(uint4*)((char*)dst + lds_off(row, seg * 16 + h * 8)) = u;
        }
    }
}

// ---- stage [128 rows][64 k] bf16 tile from bf16 row-major source --------------
__device__ __forceinline__ void stage_bf16tile(
    const unsigned short* __restrict__ src, int stride, int nvalid, unsigned* dst, int t)
{
    #pragma unroll
    for (int l = 0; l < 2; l++) {
        int task = t + l * 256;
        int row = task >> 2, seg = task & 3;
        s16x8 a = {0,0,0,0,0,0,0,0}, b = {0,0,0,0,0,0,0,0};
        if (row < nvalid) {
            a = *(const s16x8*)(src + (size_t)row * stride + seg * 16);
            b = *(const s16x8*)(src + (size_t)row * stride + seg * 16 + 8);
        }
        *(s16x8*)((char*)dst + lds_off(row, seg * 16)) = a;
        *(s16x8*)((char*)dst + lds_off(row, seg * 16 + 8)) = b;
    }
}

// ---------------- prep: WsT[s][k] bf16 <- Ws[k][s] f32 -------------------------
__global__ __launch_bounds__(256) void k_prepWsT(
    const float* __restrict__ Ws, unsigned short* __restrict__ WsT)
{
    __shared__ float tile[32][33];
    int t = threadIdx.x;
    int k0 = blockIdx.x * 32;   // 16
    int s0 = blockIdx.y * 32;   // 4
    #pragma unroll
    for (int l = 0; l < 4; l++) {
        int idx = t + l * 256;
        int r = idx >> 5, c = idx & 31;
        tile[r][c] = Ws[(size_t)(k0 + r) * Sn + s0 + c];
    }
    __syncthreads();
    #pragma unroll
    for (int l = 0; l < 4; l++) {
        int idx = t + l * 256;
        int r = idx >> 5, c = idx & 31;
        WsT[(size_t)(s0 + r) * Cn + k0 + c] = f2bf(tile[c][r]);
    }
}

// ---------------- prep: SoT[b][c][s] bf16 <- slices_out[b][s][c] f32 -----------
__global__ __launch_bounds__(256) void k_prepSoT(
    const float* __restrict__ so, unsigned short* __restrict__ SoT)
{
    __shared__ float tile[32][33];
    int t = threadIdx.x;
    int s0 = blockIdx.x * 32;   // 4
    int c0 = blockIdx.y * 32;   // 16
    int b = blockIdx.z;
    #pragma unroll
    for (int l = 0; l < 4; l++) {
        int idx = t + l * 256;
        int r = idx >> 5, c = idx & 31;
        tile[r][c] = so[(size_t)b * Sn * Cn + (size_t)(s0 + r) * Cn + c0 + c];
    }
    __syncthreads();
    #pragma unroll
    for (int l = 0; l < 4; l++) {
        int idx = t + l * 256;
        int r = idx >> 5, c = idx & 31;
        SoT[(size_t)b * Cn * Sn + (size_t)(c0 + r) * Sn + s0 + c] = f2bf(tile[c][r]);
    }
}

// ---------------- K1': weights = softmax(x @ Ws + bs) via MFMA -----------------
// Block: 4 waves, 128 n-rows x 128 s-cols, K=512 in 8 stages of 64.
// Wave w owns rows [w*32, w*32+32): acc[i=2][j=8] 16x16 frags.
__global__ __launch_bounds__(256) void k_assign2(
    const float* __restrict__ x, const unsigned short* __restrict__ WsT,
    const float* __restrict__ bs, unsigned short* __restrict__ weights,
    float* __restrict__ wsum)
{
    __shared__ __align__(16) unsigned At32[4096];   // 16 KB
    __shared__ __align__(16) unsigned Bt32[4096];   // 16 KB
    __shared__ float wsum_loc[128];

    int t = threadIdx.x;
    int lane = t & 63;
    int wid = t >> 6;
    int l15 = lane & 15, lg = lane >> 4;
    int blk = blockIdx.x;
    int b = blk / NB128;
    int rb = blk % NB128;
    int n0 = rb * 128;
    int nvalid = Nn - n0; if (nvalid > 128) nvalid = 128;
    const float* xb = x + (size_t)b * Nn * Cn;

    if (t < 128) wsum_loc[t] = 0.f;

    f32x4 acc[2][8];
    const f32x4 fz = {0.f, 0.f, 0.f, 0.f};
    #pragma unroll
    for (int i = 0; i < 2; i++) {
        #pragma unroll
        for (int j = 0; j < 8; j++) acc[i][j] = fz;
    }

    for (int ks = 0; ks < 8; ks++) {
        stage_f32tile(xb + (size_t)n0 * Cn + ks * 64, Cn, nvalid, At32, t);
        stage_bf16tile(WsT + ks * 64, Cn, 128, Bt32, t);
        __syncthreads();
        #pragma unroll
        for (int m = 0; m < 2; m++) {
            s16x8 af[2];
            #pragma unroll
            for (int i = 0; i < 2; i++)
                af[i] = *(const s16x8*)((const char*)At32 +
                        lds_off(wid * 32 + i * 16 + l15, m * 32 + lg * 8));
            #pragma unroll
            for (int j = 0; j < 8; j++) {
                s16x8 bf = *(const s16x8*)((const char*)Bt32 +
                        lds_off(j * 16 + l15, m * 32 + lg * 8));
                #pragma unroll
                for (int i = 0; i < 2; i++)
                    acc[i][j] = __builtin_amdgcn_mfma_f32_16x16x32_bf16(
                        af[i], bf, acc[i][j], 0, 0, 0);
            }
        }
        __syncthreads();
    }

    float bsv[8];
    #pragma unroll
    for (int j = 0; j < 8; j++) bsv[j] = bs[j * 16 + l15];

    unsigned short* wb = weights + (size_t)b * Nn * Sn;
    float wacc[8] = {0.f,0.f,0.f,0.f,0.f,0.f,0.f,0.f};
    #pragma unroll
    for (int i = 0; i < 2; i++) {
        #pragma unroll
        for (int r = 0; r < 4; r++) {
            float lv[8];
            #pragma unroll
            for (int j = 0; j < 8; j++) lv[j] = acc[i][j][r] + bsv[j];
            float m = lv[0];
            #pragma unroll
            for (int j = 1; j < 8; j++) m = fmaxf(m, lv[j]);
            m = fmaxf(m, __shfl_xor(m, 1));
            m = fmaxf(m, __shfl_xor(m, 2));
            m = fmaxf(m, __shfl_xor(m, 4));
            m = fmaxf(m, __shfl_xor(m, 8));
            float e[8], sm = 0.f;
            #pragma unroll
            for (int j = 0; j < 8; j++) { e[j] = __expf(lv[j] - m); sm += e[j]; }
            sm += __shfl_xor(sm, 1);
            sm += __shfl_xor(sm, 2);
            sm += __shfl_xor(sm, 4);
            sm += __shfl_xor(sm, 8);
            float inv = 1.f / sm;
            int rloc = wid * 32 + i * 16 + lg * 4 + r;
            int n = n0 + rloc;
            bool valid = (n < Nn);
            #pragma unroll
            for (int j = 0; j < 8; j++) {
                float w = e[j] * inv;
                if (valid) {
                    wb[(size_t)n * Sn + j * 16 + l15] = f2bf(w);
                    wacc[j] += w;
                }
            }
        }
    }
    // wsum: reduce across lg groups, then LDS, then global
    #pragma unroll
    for (int j = 0; j < 8; j++) {
        wacc[j] += __shfl_xor(wacc[j], 16);
        wacc[j] += __shfl_xor(wacc[j], 32);
    }
    if (lg == 0) {
        #pragma unroll
        for (int j = 0; j < 8; j++) atomicAdd(&wsum_loc[j * 16 + l15], wacc[j]);
    }
    __syncthreads();
    if (t < 128) atomicAdd(&wsum[b * Sn + t], wsum_loc[t]);
}

// ---------------- CSR build: degree histogram ----------------------------------
__global__ __launch_bounds__(256) void k_deg(
    const int* __restrict__ adj, int* __restrict__ deg)
{
    int e = blockIdx.x * 256 + threadIdx.x;
    if (e < En) atomicAdd(&deg[adj[e]], 1);
}

// ---------------- CSR build: single-block prefix scan over N -------------------
__global__ __launch_bounds__(1024) void k_scan(
    const int* __restrict__ deg, int* __restrict__ offs)
{
    __shared__ int buf[1024];
    __shared__ int runs;
    int t = threadIdx.x;
    if (t == 0) { offs[0] = 0; runs = 0; }
    __syncthreads();
    for (int base = 0; base < Nn; base += 1024) {
        int v = (base + t < Nn) ? deg[base + t] : 0;
        buf[t] = v;
        __syncthreads();
        #pragma unroll
        for (int d = 1; d < 1024; d <<= 1) {
            int add = (t >= d) ? buf[t - d] : 0;
            __syncthreads();
            buf[t] += add;
            __syncthreads();
        }
        if (base + t < Nn) offs[base + t + 1] = runs + buf[t];
        __syncthreads();
        if (t == 1023) runs += buf[1023];
        __syncthreads();
    }
}

// ---------------- CSR build: fill edge ids -------------------------------------
__global__ __launch_bounds__(256) void k_fill(
    const int* __restrict__ adj, const int* __restrict__ offs,
    int* __restrict__ cursor, int* __restrict__ eid)
{
    int e = blockIdx.x * 256 + threadIdx.x;
    if (e < En) {
        int r = adj[e];
        int p = atomicAdd(&cursor[r], 1);
        eid[offs[r] + p] = e;
    }
}

// ---------------- K3': gw[b,r,:] = sum_{e in row r} v_e * w[b,col_e,:] ---------
__global__ __launch_bounds__(128) void k_gather(
    const unsigned short* __restrict__ weights, const int* __restrict__ adj,
    const float* __restrict__ vals, const int* __restrict__ offs,
    const int* __restrict__ eid, float* __restrict__ gw)
{
    int r = blockIdx.x;
    int s = threadIdx.x;
    int o0 = offs[r], o1 = offs[r + 1];
    const unsigned short* w0 = weights;
    const unsigned short* w1 = weights + (size_t)Nn * Sn;
    float a0 = 0.f, a1 = 0.f;
    for (int j = o0; j < o1; j++) {
        int e = eid[j];
        int c = adj[En + e];
        float v = vals[e];
        a0 += v * bf2f(w0[(size_t)c * Sn + s]);
        a1 += v * bf2f(w1[(size_t)c * Sn + s]);
    }
    gw[(size_t)r * Sn + s] = a0;
    gw[(size_t)Nn * Sn + (size_t)r * Sn + s] = a1;
}

// ---------------- staging for k_mm: 64 n-rows x 128 cols (A bf16, B f32) -------
__device__ __forceinline__ void stage_tiles(
    const unsigned short* __restrict__ wA, const float* __restrict__ Bsrc,
    int Bstride, int c0, int nbase, unsigned* At32, unsigned* Bt32, int t)
{
    int c = t & 15;
    int p0 = t >> 4;
    #pragma unroll
    for (int half = 0; half < 2; half++) {
        int pp = p0 + half * 16;
        int nl = 2 * pp;
        int ng = nbase + nl;
        s16x8 a0 = {0,0,0,0,0,0,0,0}, a1 = {0,0,0,0,0,0,0,0};
        if (ng < Nn)     a0 = *(const s16x8*)(wA + (size_t)ng * Sn + 8 * c);
        if (ng + 1 < Nn) a1 = *(const s16x8*)(wA + (size_t)(ng + 1) * Sn + 8 * c);
        #pragma unroll
        for (int i = 0; i < 8; i++) {
            unsigned val = ((unsigned)(unsigned short)a0[i]) |
                           (((unsigned)(unsigned short)a1[i]) << 16);
            At32[lds_off(8 * c + i, nl) >> 2] = val;
        }
        float b0[8], b1[8];
        if (ng < Nn) {
            float4 v0 = *(const float4*)(Bsrc + (size_t)ng * Bstride + c0 + 8 * c);
            float4 v1 = *(const float4*)(Bsrc + (size_t)ng * Bstride + c0 + 8 * c + 4);
            b0[0]=v0.x; b0[1]=v0.y; b0[2]=v0.z; b0[3]=v0.w;
            b0[4]=v1.x; b0[5]=v1.y; b0[6]=v1.z; b0[7]=v1.w;
        } else {
            #pragma unroll
            for (int i = 0; i < 8; i++) b0[i] = 0.f;
        }
        if (ng + 1 < Nn) {
            float4 v0 = *(const float4*)(Bsrc + (size_t)(ng + 1) * Bstride + c0 + 8 * c);
            float4 v1 = *(const float4*)(Bsrc + (size_t)(ng + 1) * Bstride + c0 + 8 * c + 4);
            b1[0]=v0.x; b1[1]=v0.y; b1[2]=v0.z; b1[3]=v0.w;
            b1[4]=v1.x; b1[5]=v1.y; b1[6]=v1.z; b1[7]=v1.w;
        } else {
            #pragma unroll
            for (int i = 0; i < 8; i++) b1[i] = 0.f;
        }
        #pragma unroll
        for (int i = 0; i < 8; i++) {
            unsigned val = (unsigned)f2bf(b0[i]) | (((unsigned)f2bf(b1[i])) << 16);
            Bt32[lds_off(8 * c + i, nl) >> 2] = val;
        }
    }
}

// ---------------- K2'/K4': partial[s][c] = sum_{n in chunk} w[n,s]*B[n,c] ------
__global__ __launch_bounds__(256) void k_mm(
    const unsigned short* __restrict__ wAall, const float* __restrict__ Ball,
    int Bstride, int nCb, int kbCount, int chunk,
    float* __restrict__ partial)
{
    __shared__ __align__(16) unsigned At32[4096];
    __shared__ __align__(16) unsigned Bt32[4096];
    int t = threadIdx.x;
    int lane = t & 63;
    int wid = t >> 6;
    int ws = wid & 1, wc = wid >> 1;
    int blk = blockIdx.x;
    int b = blk / (nCb * kbCount);
    int rem = blk % (nCb * kbCount);
    int cb = rem / kbCount;
    int kb = rem % kbCount;
    int n0 = kb * chunk;
    int c0 = cb * 128;
    const unsigned short* wA = wAall + (size_t)b * Nn * Sn;
    const float* Bsrc = Ball + (size_t)b * Nn * Bstride;

    f32x4 acc[4][4];
    const f32x4 fz = {0.f, 0.f, 0.f, 0.f};
    #pragma unroll
    for (int i = 0; i < 4; i++) {
        #pragma unroll
        for (int j = 0; j < 4; j++) acc[i][j] = fz;
    }

    int l15 = lane & 15, lg = lane >> 4;

    for (int kt = 0; kt < chunk; kt += 64) {
        stage_tiles(wA, Bsrc, Bstride, c0, n0 + kt, At32, Bt32, t);
        __syncthreads();
        #pragma unroll
        for (int m = 0; m < 2; m++) {
            s16x8 af[4], bfr[4];
            #pragma unroll
            for (int i = 0; i < 4; i++) {
                int row = ws * 64 + i * 16 + l15;
                af[i] = *(const s16x8*)((const char*)At32 + lds_off(row, m * 32 + lg * 8));
            }
            #pragma unroll
            for (int j = 0; j < 4; j++) {
                int row = wc * 64 + j * 16 + l15;
                bfr[j] = *(const s16x8*)((const char*)Bt32 + lds_off(row, m * 32 + lg * 8));
            }
            #pragma unroll
            for (int i = 0; i < 4; i++) {
                #pragma unroll
                for (int j = 0; j < 4; j++)
                    acc[i][j] = __builtin_amdgcn_mfma_f32_16x16x32_bf16(
                        af[i], bfr[j], acc[i][j], 0, 0, 0);
            }
        }
        __syncthreads();
    }

    float* pp = partial + (size_t)blk * 16384;
    #pragma unroll
    for (int i = 0; i < 4; i++) {
        int srow = ws * 64 + i * 16 + lg * 4;
        #pragma unroll
        for (int j = 0; j < 4; j++) {
            int ccol = wc * 64 + j * 16 + l15;
            #pragma unroll
            for (int r = 0; r < 4; r++)
                pp[(size_t)(srow + r) * 128 + ccol] = acc[i][j][r];
        }
    }
}

// ---------------- reduce partials -> slices (with /wsum) -----------------------
__global__ __launch_bounds__(256) void k_reduceS(
    const float* __restrict__ partial, const float* __restrict__ wsum,
    float* __restrict__ slices)
{
    int g = blockIdx.x * 256 + threadIdx.x;
    int c = g & 127;
    int s = (g >> 7) & 127;
    int cb = (g >> 14) & 3;
    int b = g >> 16;
    const float* pp = partial + (size_t)(b * 4 + cb) * S_KB * 16384 + (size_t)s * 128 + c;
    float sum = 0.f;
    #pragma unroll 7
    for (int kb = 0; kb < S_KB; kb++) sum += pp[(size_t)kb * 16384];
    slices[((size_t)b * Sn + s) * Cn + cb * 128 + c] = sum / fmaxf(wsum[b * Sn + s], EPSf);
}

// ---------------- reduce partials -> gb_raw ------------------------------------
__global__ __launch_bounds__(256) void k_reduceG(
    const float* __restrict__ partial, float* __restrict__ gb_raw)
{
    int g = blockIdx.x * 256 + threadIdx.x;
    int t2 = g & 127;
    int s = (g >> 7) & 127;
    int b = g >> 14;
    const float* pp = partial + (size_t)b * G_KB * 16384 + (size_t)s * 128 + t2;
    float sum = 0.f;
    #pragma unroll 8
    for (int kb = 0; kb < G_KB; kb++) sum += pp[(size_t)kb * 16384];
    gb_raw[(size_t)b * 16384 + (size_t)s * 128 + t2] = sum;
}

// ---------------- K4b: symmetrize, row-normalize, log --------------------------
__global__ __launch_bounds__(128) void k_gb_fin(
    const float* __restrict__ gb_raw, float* __restrict__ gb)
{
    int bid = blockIdx.x;
    int b = bid >> 7, i = bid & 127;
    int j = threadIdx.x;
    const float* gr = gb_raw + (size_t)b * Sn * Sn;
    float sym = 0.5f * (gr[i * Sn + j] + gr[j * Sn + i]);
    float sum = sym;
    #pragma unroll
    for (int d = 1; d < 64; d <<= 1) sum += __shfl_xor(sum, d);
    __shared__ float wred[2];
    if ((j & 63) == 0) wred[j >> 6] = sum;
    __syncthreads();
    sum = wred[0] + wred[1];
    float r = fmaxf(sum, EPSf);
    gb[(size_t)b * Sn * Sn + (size_t)i * Sn + j] = logf(fmaxf(sym / r, EPSf));
}

// ---------------- K5/K7: out[m,c] = in[m,:] @ W[:,c] + bias[c], M=256 ----------
__global__ __launch_bounds__(256) void k_lin(
    const float* __restrict__ in, const float* __restrict__ W,
    const float* __restrict__ bias, float* __restrict__ out)
{
    __shared__ float it[8][512];
    int t = threadIdx.x;
    int m0 = blockIdx.x * 8;
    int c = blockIdx.y * 256 + t;
    #pragma unroll
    for (int l = 0; l < 16; l++) {
        int idx = t + l * 256;
        int r = idx >> 9, kk = idx & 511;
        it[r][kk] = in[(size_t)(m0 + r) * Cn + kk];
    }
    __syncthreads();
    float acc[8] = {0.f,0.f,0.f,0.f,0.f,0.f,0.f,0.f};
    #pragma unroll 4
    for (int kk = 0; kk < Cn; kk++) {
        float wv = W[(size_t)kk * Cn + c];
        #pragma unroll
        for (int r = 0; r < 8; r++) acc[r] += it[r][kk] * wv;
    }
    float bv = bias[c];
    #pragma unroll
    for (int r = 0; r < 8; r++) out[(size_t)(m0 + r) * Cn + c] = acc[r] + bv;
}

// ---------------- K6: attention per (b,h,i) ------------------------------------
__global__ __launch_bounds__(128) void k_attn(
    const float* __restrict__ q, const float* __restrict__ k,
    const float* __restrict__ v, const float* __restrict__ gb,
    const float* __restrict__ beta_raw, float* __restrict__ attn_out)
{
    __shared__ float kv[128][65];
    __shared__ float qv[64];
    __shared__ float p[128];
    __shared__ float wred[2][2];

    int t = threadIdx.x;
    int bid = blockIdx.x;
    int b = bid / (Hn * Sn);
    int h = (bid / Sn) % Hn;
    int i = bid % Sn;
    size_t base = (size_t)b * Sn * Cn + (size_t)h * Dn;

    if (t < 64) qv[t] = q[base + (size_t)i * Cn + t];
    for (int l = 0; l < 64; l++) {
        int idx = t + l * 128;
        int j = idx >> 6, d = idx & 63;
        kv[j][d] = k[base + (size_t)j * Cn + d];
    }
    __syncthreads();

    float dot = 0.f;
    #pragma unroll
    for (int d = 0; d < 64; d++) dot += qv[d] * kv[t][d];

    float beta = log1pf(__expf(beta_raw[0]));
    float logit = dot * 0.125f + beta * gb[(size_t)b * Sn * Sn + (size_t)i * Sn + t];

    float m = logit;
    #pragma unroll
    for (int d = 1; d < 64; d <<= 1) m = fmaxf(m, __shfl_xor(m, d));
    if ((t & 63) == 0) wred[0][t >> 6] = m;
    __syncthreads();
    m = fmaxf(wred[0][0], wred[0][1]);
    float e = __expf(logit - m);
    float sm = e;
    #pragma unroll
    for (int d = 1; d < 64; d <<= 1) sm += __shfl_xor(sm, d);
    if ((t & 63) == 0) wred[1][t >> 6] = sm;
    __syncthreads();
    sm = wred[1][0] + wred[1][1];
    p[t] = e / sm;
    __syncthreads();

    for (int l = 0; l < 64; l++) {
        int idx = t + l * 128;
        int j = idx >> 6, d = idx & 63;
        kv[j][d] = v[base + (size_t)j * Cn + d];
    }
    __syncthreads();

    if (t < 64) {
        float o = 0.f;
        #pragma unroll 8
        for (int j = 0; j < 128; j++) o += p[j] * kv[j][t];
        attn_out[base + (size_t)i * Cn + t] = o;
    }
}

// ---------------- K8': out[n][c] = sum_s w[n,s]*so[s,c] via MFMA ---------------
// Block: 4 waves (2x2), 128 n x 128 c, K=128 in 2 stages of 64.
__global__ __launch_bounds__(256) void k_out2(
    const unsigned short* __restrict__ wAll, const unsigned short* __restrict__ SoT,
    float* __restrict__ out)
{
    __shared__ __align__(16) unsigned At32[4096];
    __shared__ __align__(16) unsigned Bt32[4096];
    int t = threadIdx.x;
    int lane = t & 63;
    int wid = t >> 6;
    int ws = wid & 1, wc = wid >> 1;
    int l15 = lane & 15, lg = lane >> 4;
    int blk = blockIdx.x;
    int b = blk / (NB128 * 4);
    int rem = blk % (NB128 * 4);
    int rb = rem >> 2;
    int cb = rem & 3;
    int n0 = rb * 128, c0 = cb * 128;
    int nvalid = Nn - n0; if (nvalid > 128) nvalid = 128;
    const unsigned short* wb = wAll + (size_t)b * Nn * Sn;
    const unsigned short* sb = SoT + (size_t)b * Cn * Sn;

    f32x4 acc[4][4];
    const f32x4 fz = {0.f, 0.f, 0.f, 0.f};
    #pragma unroll
    for (int i = 0; i < 4; i++) {
        #pragma unroll
        for (int j = 0; j < 4; j++) acc[i][j] = fz;
    }

    #pragma unroll
    for (int ksi = 0; ksi < 2; ksi++) {
        stage_bf16tile(wb + (size_t)n0 * Sn + ksi * 64, Sn, nvalid, At32, t);
        stage_bf16tile(sb + (size_t)c0 * Sn + ksi * 64, Sn, 128, Bt32, t);
        __syncthreads();
        #pragma unroll
        for (int m = 0; m < 2; m++) {
            s16x8 af[4], bfr[4];
            #pragma unroll
            for (int i = 0; i < 4; i++)
                af[i] = *(const s16x8*)((const char*)At32 +
                        lds_off(ws * 64 + i * 16 + l15, m * 32 + lg * 8));
            #pragma unroll
            for (int j = 0; j < 4; j++)
                bfr[j] = *(const s16x8*)((const char*)Bt32 +
                        lds_off(wc * 64 + j * 16 + l15, m * 32 + lg * 8));
            #pragma unroll
            for (int i = 0; i < 4; i++) {
                #pragma unroll
                for (int j = 0; j < 4; j++)
                    acc[i][j] = __builtin_amdgcn_mfma_f32_16x16x32_bf16(
                        af[i], bfr[j], acc[i][j], 0, 0, 0);
            }
        }
        __syncthreads();
    }

    #pragma unroll
    for (int i = 0; i < 4; i++) {
        #pragma unroll
        for (int r = 0; r < 4; r++) {
            int n = n0 + ws * 64 + i * 16 + lg * 4 + r;
            if (n < Nn) {
                #pragma unroll
                for (int j = 0; j < 4; j++)
                    out[((size_t)b * Nn + n) * Cn + c0 + wc * 64 + j * 16 + l15] =
                        acc[i][j][r];
            }
        }
    }
}

extern "C" void kernel_launch(void* const* d_in, const int* in_sizes, int n_in,
                              void* d_out, int out_size, void* d_ws, size_t ws_size,
                              hipStream_t stream)
{
    const float* x  = (const float*)d_in[0];
    const int* adj  = (const int*)d_in[1];
    const float* av = (const float*)d_in[2];
    const float* Ws = (const float*)d_in[3];
    const float* bs = (const float*)d_in[4];
    const float* Wq = (const float*)d_in[5];
    const float* bq = (const float*)d_in[6];
    const float* Wk = (const float*)d_in[7];
    const float* bk = (const float*)d_in[8];
    const float* Wv = (const float*)d_in[9];
    const float* bv = (const float*)d_in[10];
    const float* Wo = (const float*)d_in[11];
    const float* bo = (const float*)d_in[12];
    const float* br = (const float*)d_in[13];
    float* out = (float*)d_out;
    (void)in_sizes; (void)n_in; (void)out_size; (void)ws_size;

    char* ws = (char*)d_ws;
    size_t off = 0;
    unsigned short* wb16 = (unsigned short*)(ws + off); off += (size_t)Bn * Nn * Sn * 2; // 10.24 MB
    float* gw         = (float*)(ws + off); off += (size_t)Bn * Nn * Sn * 4;             // 20.48 MB
    float* slices     = (float*)(ws + off); off += (size_t)Bn * Sn * Cn * 4;
    float* wsum       = (float*)(ws + off); off += 1024;
    float* gb_raw     = (float*)(ws + off); off += (size_t)Bn * Sn * Sn * 4;
    float* gb         = (float*)(ws + off); off += (size_t)Bn * Sn * Sn * 4;
    float* q          = (float*)(ws + off); off += (size_t)Bn * Sn * Cn * 4;
    float* kbuf       = (float*)(ws + off); off += (size_t)Bn * Sn * Cn * 4;
    float* vbuf       = (float*)(ws + off); off += (size_t)Bn * Sn * Cn * 4;
    float* attn_out   = (float*)(ws + off); off += (size_t)Bn * Sn * Cn * 4;
    float* slices_out = (float*)(ws + off); off += (size_t)Bn * Sn * Cn * 4;
    unsigned short* WsT = (unsigned short*)(ws + off); off += (size_t)Sn * Cn * 2;       // 128 KB
    unsigned short* SoT = (unsigned short*)(ws + off); off += (size_t)Bn * Cn * Sn * 2;  // 256 KB
    // Union region U: CSR buffers live [k_deg .. k_gather], then partialS
    // [k_mm(slices) .. k_reduceS], then partialG [k_mm(gb) .. k_reduceG].
    char* U = ws + off;
    int* deg    = (int*)(U);
    int* cursor = (int*)(U + 80128);
    int* offs   = (int*)(U + 160256);
    int* eid    = (int*)(U + 240640);
    float* partialS = (float*)U;            // 504 * 64 KB = 33.0 MB
    float* partialG = (float*)U;            // 314 * 64 KB = 20.6 MB

    hipMemsetAsync(wsum, 0, 1024, stream);
    hipMemsetAsync(U, 0, 160256, stream);   // deg + cursor

    k_prepWsT<<<dim3(16, 4), 256, 0, stream>>>(Ws, WsT);
    k_assign2<<<Bn * NB128, 256, 0, stream>>>(x, WsT, bs, wb16, wsum);

    // CSR build + gather
    k_deg<<<(En + 255) / 256, 256, 0, stream>>>(adj, deg);
    k_scan<<<1, 1024, 0, stream>>>(deg, offs);
    k_fill<<<(En + 255) / 256, 256, 0, stream>>>(adj, offs, cursor, eid);
    k_gather<<<Nn, 128, 0, stream>>>(wb16, adj, av, offs, eid, gw);

    // slices = wT @ x / wsum  (MFMA partials + reduce)
    k_mm<<<Bn * 4 * S_KB, 256, 0, stream>>>(wb16, x, Cn, 4, S_KB, S_CHUNK, partialS);
    k_reduceS<<<(Bn * Sn * Cn) / 256, 256, 0, stream>>>(partialS, wsum, slices);

    // gb_raw = wT @ gw (MFMA partials + reduce)
    k_mm<<<Bn * G_KB, 256, 0, stream>>>(wb16, gw, Sn, 1, G_KB, G_CHUNK, partialG);
    k_reduceG<<<(Bn * Sn * Sn) / 256, 256, 0, stream>>>(partialG, gb_raw);
    k_gb_fin<<<Bn * Sn, 128, 0, stream>>>(gb_raw, gb);

    k_lin<<<dim3(32, 2), 256, 0, stream>>>(slices, Wq, bq, q);
    k_lin<<<dim3(32, 2), 256, 0, stream>>>(slices, Wk, bk, kbuf);
    k_lin<<<dim3(32, 2), 256, 0, stream>>>(slices, Wv, bv, vbuf);
    k_attn<<<Bn * Hn * Sn, 128, 0, stream>>>(q, kbuf, vbuf, gb, br, attn_out);
    k_lin<<<dim3(32, 2), 256, 0, stream>>>(attn_out, Wo, bo, slices_out);

    k_prepSoT<<<dim3(4, 16, Bn), 256, 0, stream>>>(slices_out, SoT);
    k_out2<<<Bn * NB128 * 4, 256, 0, stream>>>(wb16, SoT, out);
}

// Round 5
// 369.512 us; speedup vs baseline: 2.9389x; 1.1697x over previous
//
#include <hip/hip_runtime.h>
#include <math.h>

#define Bn 2
#define Nn 20000
#define Cn 512
#define Sn 128
#define Hn 8
#define Dn 64
#define En 320000
#define EPSf 1e-6f
#define NB128 157  // ceil(20000/128)

#define S_CHUNK 640
#define S_KB 32        // 32*640 = 20480 >= 20000
#define G_CHUNK 256
#define G_KB 79        // 79*256 = 20224 >= 20000

typedef __attribute__((ext_vector_type(4))) float f32x4;
typedef __attribute__((ext_vector_type(8))) short s16x8;

__device__ __forceinline__ unsigned short f2bf(float f) {
    unsigned u = __float_as_uint(f);
    return (unsigned short)((u + 0x7fffu + ((u >> 16) & 1u)) >> 16);
}
__device__ __forceinline__ float bf2f(unsigned short h) {
    return __uint_as_float(((unsigned)h) << 16);
}

// Swizzled LDS byte offset for a [128 rows][64 k] bf16 tile.
// Frag reads (16B, k mult of 8): 2-way bank aliasing (free per m136).
__device__ __forceinline__ unsigned lds_off(int row, int n) {
    unsigned ch = ((((unsigned)n >> 3) ^ ((unsigned)row & 7u) ^ (((unsigned)row >> 3) & 7u)) & 7u);
    return (unsigned)row * 128u + ch * 16u + ((unsigned)n & 7u) * 2u;
}

// ---- stage [128 rows][64 k] bf16 tile from bf16 row-major source (row=out dim)
__device__ __forceinline__ void stage_bf16tile(
    const unsigned short* __restrict__ src, int stride, int nvalid, unsigned* dst, int t)
{
    #pragma unroll
    for (int l = 0; l < 2; l++) {
        int task = t + l * 256;
        int row = task >> 2, seg = task & 3;
        s16x8 a = {0,0,0,0,0,0,0,0}, b = {0,0,0,0,0,0,0,0};
        if (row < nvalid) {
            a = *(const s16x8*)(src + (size_t)row * stride + seg * 16);
            b = *(const s16x8*)(src + (size_t)row * stride + seg * 16 + 8);
        }
        *(s16x8*)((char*)dst + lds_off(row, seg * 16)) = a;
        *(s16x8*)((char*)dst + lds_off(row, seg * 16 + 8)) = b;
    }
}

// ---- stage transpose-pack: [out:128][k(n):64] tile from [n][out] bf16 source --
__device__ __forceinline__ void stage_pairtile(
    const unsigned short* __restrict__ src, int stride, int c0,
    int nbase, int nlimit, unsigned* dst, int t)
{
    int c = t & 15;
    int p0 = t >> 4;
    #pragma unroll
    for (int half = 0; half < 2; half++) {
        int pp = p0 + half * 16;
        int nl = 2 * pp;
        int ng = nbase + nl;
        s16x8 a0 = {0,0,0,0,0,0,0,0}, a1 = {0,0,0,0,0,0,0,0};
        if (ng < nlimit)     a0 = *(const s16x8*)(src + (size_t)ng * stride + c0 + 8 * c);
        if (ng + 1 < nlimit) a1 = *(const s16x8*)(src + (size_t)(ng + 1) * stride + c0 + 8 * c);
        #pragma unroll
        for (int i = 0; i < 8; i++) {
            unsigned val = ((unsigned)(unsigned short)a0[i]) |
                           (((unsigned)(unsigned short)a1[i]) << 16);
            dst[lds_off(8 * c + i, nl) >> 2] = val;
        }
    }
}

// ---------------- prep: WsT[s][k] bf16 <- Ws[k][s] f32 -------------------------
__global__ __launch_bounds__(256) void k_prepWsT(
    const float* __restrict__ Ws, unsigned short* __restrict__ WsT)
{
    __shared__ float tile[32][33];
    int t = threadIdx.x;
    int k0 = blockIdx.x * 32;
    int s0 = blockIdx.y * 32;
    #pragma unroll
    for (int l = 0; l < 4; l++) {
        int idx = t + l * 256;
        int r = idx >> 5, c = idx & 31;
        tile[r][c] = Ws[(size_t)(k0 + r) * Sn + s0 + c];
    }
    __syncthreads();
    #pragma unroll
    for (int l = 0; l < 4; l++) {
        int idx = t + l * 256;
        int r = idx >> 5, c = idx & 31;
        WsT[(size_t)(s0 + r) * Cn + k0 + c] = f2bf(tile[c][r]);
    }
}

// ---------------- prep: SoT[b][c][s] bf16 <- slices_out[b][s][c] f32 -----------
__global__ __launch_bounds__(256) void k_prepSoT(
    const float* __restrict__ so, unsigned short* __restrict__ SoT)
{
    __shared__ float tile[32][33];
    int t = threadIdx.x;
    int s0 = blockIdx.x * 32;
    int c0 = blockIdx.y * 32;
    int b = blockIdx.z;
    #pragma unroll
    for (int l = 0; l < 4; l++) {
        int idx = t + l * 256;
        int r = idx >> 5, c = idx & 31;
        tile[r][c] = so[(size_t)b * Sn * Cn + (size_t)(s0 + r) * Cn + c0 + c];
    }
    __syncthreads();
    #pragma unroll
    for (int l = 0; l < 4; l++) {
        int idx = t + l * 256;
        int r = idx >> 5, c = idx & 31;
        SoT[(size_t)b * Cn * Sn + (size_t)(c0 + r) * Sn + s0 + c] = f2bf(tile[c][r]);
    }
}

// ---------------- K1': weights = softmax(x @ Ws + bs) via MFMA -----------------
// Also write-throughs the staged bf16 x tiles to xb16 (read by k_mm-slices).
__global__ __launch_bounds__(256) void k_assign2(
    const float* __restrict__ x, const unsigned short* __restrict__ WsT,
    const float* __restrict__ bs, unsigned short* __restrict__ weights,
    unsigned short* __restrict__ xb16, float* __restrict__ wsum)
{
    __shared__ __align__(16) unsigned At32[4096];
    __shared__ __align__(16) unsigned Bt32[4096];
    __shared__ float wsum_loc[128];

    int t = threadIdx.x;
    int lane = t & 63;
    int wid = t >> 6;
    int l15 = lane & 15, lg = lane >> 4;
    int blk = blockIdx.x;
    int b = blk / NB128;
    int rb = blk % NB128;
    int n0 = rb * 128;
    int nvalid = Nn - n0; if (nvalid > 128) nvalid = 128;
    const float* xb = x + (size_t)b * Nn * Cn;
    unsigned short* xb16g = xb16 + (size_t)b * Nn * Cn;

    if (t < 128) wsum_loc[t] = 0.f;

    f32x4 acc[2][8];
    const f32x4 fz = {0.f, 0.f, 0.f, 0.f};
    #pragma unroll
    for (int i = 0; i < 2; i++) {
        #pragma unroll
        for (int j = 0; j < 8; j++) acc[i][j] = fz;
    }

    for (int ks = 0; ks < 8; ks++) {
        // stage x f32 -> LDS bf16 tile + write-through to xb16
        #pragma unroll
        for (int l = 0; l < 2; l++) {
            int task = t + l * 256;
            int row = task >> 2, seg = task & 3;
            bool ok = (row < nvalid);
            float v[16];
            if (ok) {
                const float4* p = (const float4*)(xb + (size_t)(n0 + row) * Cn + ks * 64 + seg * 16);
                float4 a = p[0], bq = p[1], c = p[2], d = p[3];
                v[0]=a.x; v[1]=a.y; v[2]=a.z; v[3]=a.w;
                v[4]=bq.x; v[5]=bq.y; v[6]=bq.z; v[7]=bq.w;
                v[8]=c.x; v[9]=c.y; v[10]=c.z; v[11]=c.w;
                v[12]=d.x; v[13]=d.y; v[14]=d.z; v[15]=d.w;
            } else {
                #pragma unroll
                for (int i = 0; i < 16; i++) v[i] = 0.f;
            }
            uint4 u[2];
            #pragma unroll
            for (int h = 0; h < 2; h++) {
                u[h].x = (unsigned)f2bf(v[h*8+0]) | (((unsigned)f2bf(v[h*8+1])) << 16);
                u[h].y = (unsigned)f2bf(v[h*8+2]) | (((unsigned)f2bf(v[h*8+3])) << 16);
                u[h].z = (unsigned)f2bf(v[h*8+4]) | (((unsigned)f2bf(v[h*8+5])) << 16);
                u[h].w = (unsigned)f2bf(v[h*8+6]) | (((unsigned)f2bf(v[h*8+7])) << 16);
                *(uint4*)((char*)At32 + lds_off(row, seg * 16 + h * 8)) = u[h];
            }
            if (ok) {
                uint4* dst = (uint4*)(xb16g + (size_t)(n0 + row) * Cn + ks * 64 + seg * 16);
                dst[0] = u[0]; dst[1] = u[1];
            }
        }
        stage_bf16tile(WsT + ks * 64, Cn, 128, Bt32, t);
        __syncthreads();
        #pragma unroll
        for (int m = 0; m < 2; m++) {
            s16x8 af[2];
            #pragma unroll
            for (int i = 0; i < 2; i++)
                af[i] = *(const s16x8*)((const char*)At32 +
                        lds_off(wid * 32 + i * 16 + l15, m * 32 + lg * 8));
            #pragma unroll
            for (int j = 0; j < 8; j++) {
                s16x8 bf = *(const s16x8*)((const char*)Bt32 +
                        lds_off(j * 16 + l15, m * 32 + lg * 8));
                #pragma unroll
                for (int i = 0; i < 2; i++)
                    acc[i][j] = __builtin_amdgcn_mfma_f32_16x16x32_bf16(
                        af[i], bf, acc[i][j], 0, 0, 0);
            }
        }
        __syncthreads();
    }

    float bsv[8];
    #pragma unroll
    for (int j = 0; j < 8; j++) bsv[j] = bs[j * 16 + l15];

    unsigned short* wb = weights + (size_t)b * Nn * Sn;
    float wacc[8] = {0.f,0.f,0.f,0.f,0.f,0.f,0.f,0.f};
    #pragma unroll
    for (int i = 0; i < 2; i++) {
        #pragma unroll
        for (int r = 0; r < 4; r++) {
            float lv[8];
            #pragma unroll
            for (int j = 0; j < 8; j++) lv[j] = acc[i][j][r] + bsv[j];
            float m = lv[0];
            #pragma unroll
            for (int j = 1; j < 8; j++) m = fmaxf(m, lv[j]);
            m = fmaxf(m, __shfl_xor(m, 1));
            m = fmaxf(m, __shfl_xor(m, 2));
            m = fmaxf(m, __shfl_xor(m, 4));
            m = fmaxf(m, __shfl_xor(m, 8));
            float e[8], sm = 0.f;
            #pragma unroll
            for (int j = 0; j < 8; j++) { e[j] = __expf(lv[j] - m); sm += e[j]; }
            sm += __shfl_xor(sm, 1);
            sm += __shfl_xor(sm, 2);
            sm += __shfl_xor(sm, 4);
            sm += __shfl_xor(sm, 8);
            float inv = 1.f / sm;
            int n = n0 + wid * 32 + i * 16 + lg * 4 + r;
            bool valid = (n < Nn);
            #pragma unroll
            for (int j = 0; j < 8; j++) {
                float w = e[j] * inv;
                if (valid) {
                    wb[(size_t)n * Sn + j * 16 + l15] = f2bf(w);
                    wacc[j] += w;
                }
            }
        }
    }
    #pragma unroll
    for (int j = 0; j < 8; j++) {
        wacc[j] += __shfl_xor(wacc[j], 16);
        wacc[j] += __shfl_xor(wacc[j], 32);
    }
    if (lg == 0) {
        #pragma unroll
        for (int j = 0; j < 8; j++) atomicAdd(&wsum_loc[j * 16 + l15], wacc[j]);
    }
    __syncthreads();
    if (t < 128) atomicAdd(&wsum[b * Sn + t], wsum_loc[t]);
}

// ---------------- CSR build: degree histogram ----------------------------------
__global__ __launch_bounds__(256) void k_deg(
    const int* __restrict__ adj, int* __restrict__ deg)
{
    int e = blockIdx.x * 256 + threadIdx.x;
    if (e < En) atomicAdd(&deg[adj[e]], 1);
}

// ---------------- CSR build: single-block wave-shuffle prefix scan -------------
__global__ __launch_bounds__(1024) void k_scan(
    const int* __restrict__ deg, int* __restrict__ offs)
{
    __shared__ int wsums[16];
    __shared__ int excl[16];
    __shared__ int runsS;
    __shared__ int totS;
    int t = threadIdx.x;
    int lane = t & 63;
    int w = t >> 6;
    if (t == 0) { offs[0] = 0; runsS = 0; }
    __syncthreads();
    for (int base = 0; base < Nn; base += 1024) {
        int v = (base + t < Nn) ? deg[base + t] : 0;
        int sv = v;
        #pragma unroll
        for (int d = 1; d < 64; d <<= 1) {
            int u = __shfl_up(sv, d);
            if (lane >= d) sv += u;
        }
        if (lane == 63) wsums[w] = sv;
        __syncthreads();
        if (t < 16) {
            int xv = wsums[t];
            int sw = xv;
            #pragma unroll
            for (int d = 1; d < 16; d <<= 1) {
                int u = __shfl_up(sw, d);
                if (t >= d) sw += u;
            }
            excl[t] = sw - xv;
            if (t == 15) totS = sw;
        }
        __syncthreads();
        if (base + t < Nn) offs[base + t + 1] = runsS + excl[w] + sv;
        __syncthreads();
        if (t == 0) runsS += totS;
        __syncthreads();
    }
}

// ---------------- CSR build: fill packed (col, val) edge records ---------------
__global__ __launch_bounds__(256) void k_fill(
    const int* __restrict__ adj, const float* __restrict__ vals,
    const int* __restrict__ offs, int* __restrict__ cursor,
    int2* __restrict__ epack)
{
    int e = blockIdx.x * 256 + threadIdx.x;
    if (e < En) {
        int r = adj[e];
        int p = atomicAdd(&cursor[r], 1);
        epack[offs[r] + p] = make_int2(adj[En + e], __float_as_int(vals[e]));
    }
}

// ---------------- K3': gw[b,r,:] = sum_{edges} v * w[b,col,:] -> bf16 ----------
__global__ __launch_bounds__(128) void k_gather(
    const unsigned short* __restrict__ weights, const int2* __restrict__ epack,
    const int* __restrict__ offs, unsigned short* __restrict__ gwb)
{
    int r = blockIdx.x;
    int s = threadIdx.x;
    int o0 = offs[r], o1 = offs[r + 1];
    const unsigned short* w0 = weights;
    const unsigned short* w1 = weights + (size_t)Nn * Sn;
    float a0 = 0.f, a1 = 0.f;
    int j = o0;
    for (; j + 4 <= o1; j += 4) {
        int2 e0 = epack[j], e1 = epack[j + 1], e2 = epack[j + 2], e3 = epack[j + 3];
        float v0 = __int_as_float(e0.y), v1 = __int_as_float(e1.y);
        float v2 = __int_as_float(e2.y), v3 = __int_as_float(e3.y);
        float p00 = bf2f(w0[(size_t)e0.x * Sn + s]);
        float p01 = bf2f(w1[(size_t)e0.x * Sn + s]);
        float p10 = bf2f(w0[(size_t)e1.x * Sn + s]);
        float p11 = bf2f(w1[(size_t)e1.x * Sn + s]);
        float p20 = bf2f(w0[(size_t)e2.x * Sn + s]);
        float p21 = bf2f(w1[(size_t)e2.x * Sn + s]);
        float p30 = bf2f(w0[(size_t)e3.x * Sn + s]);
        float p31 = bf2f(w1[(size_t)e3.x * Sn + s]);
        a0 += v0 * p00 + v1 * p10 + v2 * p20 + v3 * p30;
        a1 += v0 * p01 + v1 * p11 + v2 * p21 + v3 * p31;
    }
    for (; j < o1; j++) {
        int2 e = epack[j];
        float v = __int_as_float(e.y);
        a0 += v * bf2f(w0[(size_t)e.x * Sn + s]);
        a1 += v * bf2f(w1[(size_t)e.x * Sn + s]);
    }
    gwb[(size_t)r * Sn + s] = f2bf(a0);
    gwb[(size_t)Nn * Sn + (size_t)r * Sn + s] = f2bf(a1);
}

// ---------------- K2'/K4': partial[s][c] = sum_{n in chunk} w[n,s]*B[n,c] ------
// Pure bf16 MFMA, both operands transpose-packed from k-major storage.
__global__ __launch_bounds__(256) void k_mm(
    const unsigned short* __restrict__ wAall, const unsigned short* __restrict__ Ball,
    int Bstride, int nCb, int kbCount, int chunk,
    float* __restrict__ partial)
{
    __shared__ __align__(16) unsigned At32[4096];
    __shared__ __align__(16) unsigned Bt32[4096];
    int t = threadIdx.x;
    int lane = t & 63;
    int wid = t >> 6;
    int ws = wid & 1, wc = wid >> 1;
    int blk = blockIdx.x;
    int b = blk / (nCb * kbCount);
    int rem = blk % (nCb * kbCount);
    int cb = rem / kbCount;
    int kb = rem % kbCount;
    int n0 = kb * chunk;
    int c0 = cb * 128;
    const unsigned short* wA = wAall + (size_t)b * Nn * Sn;
    const unsigned short* Bsrc = Ball + (size_t)b * Nn * Bstride;

    f32x4 acc[4][4];
    const f32x4 fz = {0.f, 0.f, 0.f, 0.f};
    #pragma unroll
    for (int i = 0; i < 4; i++) {
        #pragma unroll
        for (int j = 0; j < 4; j++) acc[i][j] = fz;
    }

    int l15 = lane & 15, lg = lane >> 4;

    for (int kt = 0; kt < chunk; kt += 64) {
        stage_pairtile(wA, Sn, 0, n0 + kt, Nn, At32, t);
        stage_pairtile(Bsrc, Bstride, c0, n0 + kt, Nn, Bt32, t);
        __syncthreads();
        #pragma unroll
        for (int m = 0; m < 2; m++) {
            s16x8 af[4], bfr[4];
            #pragma unroll
            for (int i = 0; i < 4; i++) {
                int row = ws * 64 + i * 16 + l15;
                af[i] = *(const s16x8*)((const char*)At32 + lds_off(row, m * 32 + lg * 8));
            }
            #pragma unroll
            for (int j = 0; j < 4; j++) {
                int row = wc * 64 + j * 16 + l15;
                bfr[j] = *(const s16x8*)((const char*)Bt32 + lds_off(row, m * 32 + lg * 8));
            }
            #pragma unroll
            for (int i = 0; i < 4; i++) {
                #pragma unroll
                for (int j = 0; j < 4; j++)
                    acc[i][j] = __builtin_amdgcn_mfma_f32_16x16x32_bf16(
                        af[i], bfr[j], acc[i][j], 0, 0, 0);
            }
        }
        __syncthreads();
    }

    float* pp = partial + (size_t)blk * 16384;
    #pragma unroll
    for (int i = 0; i < 4; i++) {
        int srow = ws * 64 + i * 16 + lg * 4;
        #pragma unroll
        for (int j = 0; j < 4; j++) {
            int ccol = wc * 64 + j * 16 + l15;
            #pragma unroll
            for (int r = 0; r < 4; r++)
                pp[(size_t)(srow + r) * 128 + ccol] = acc[i][j][r];
        }
    }
}

// ---------------- reduce partials -> slices (with /wsum) -----------------------
__global__ __launch_bounds__(256) void k_reduceS(
    const float* __restrict__ partial, const float* __restrict__ wsum,
    float* __restrict__ slices)
{
    int g = blockIdx.x * 256 + threadIdx.x;
    int c = g & 127;
    int s = (g >> 7) & 127;
    int cb = (g >> 14) & 3;
    int b = g >> 16;
    const float* pp = partial + (size_t)(b * 4 + cb) * S_KB * 16384 + (size_t)s * 128 + c;
    float sum = 0.f;
    #pragma unroll 8
    for (int kb = 0; kb < S_KB; kb++) sum += pp[(size_t)kb * 16384];
    slices[((size_t)b * Sn + s) * Cn + cb * 128 + c] = sum / fmaxf(wsum[b * Sn + s], EPSf);
}

// ---------------- reduce partials -> gb_raw ------------------------------------
__global__ __launch_bounds__(256) void k_reduceG(
    const float* __restrict__ partial, float* __restrict__ gb_raw)
{
    int g = blockIdx.x * 256 + threadIdx.x;
    int t2 = g & 127;
    int s = (g >> 7) & 127;
    int b = g >> 14;
    const float* pp = partial + (size_t)b * G_KB * 16384 + (size_t)s * 128 + t2;
    float sum = 0.f;
    #pragma unroll 8
    for (int kb = 0; kb < G_KB; kb++) sum += pp[(size_t)kb * 16384];
    gb_raw[(size_t)b * 16384 + (size_t)s * 128 + t2] = sum;
}

// ---------------- K4b: symmetrize, row-normalize, log --------------------------
__global__ __launch_bounds__(128) void k_gb_fin(
    const float* __restrict__ gb_raw, float* __restrict__ gb)
{
    int bid = blockIdx.x;
    int b = bid >> 7, i = bid & 127;
    int j = threadIdx.x;
    const float* gr = gb_raw + (size_t)b * Sn * Sn;
    float sym = 0.5f * (gr[i * Sn + j] + gr[j * Sn + i]);
    float sum = sym;
    #pragma unroll
    for (int d = 1; d < 64; d <<= 1) sum += __shfl_xor(sum, d);
    __shared__ float wred[2];
    if ((j & 63) == 0) wred[j >> 6] = sum;
    __syncthreads();
    sum = wred[0] + wred[1];
    float r = fmaxf(sum, EPSf);
    gb[(size_t)b * Sn * Sn + (size_t)i * Sn + j] = logf(fmaxf(sym / r, EPSf));
}

// ---------------- K5/K7: out[m,c] = in[m,:] @ W[:,c] + bias[c], M=256 ----------
__global__ __launch_bounds__(256) void k_lin(
    const float* __restrict__ in, const float* __restrict__ W,
    const float* __restrict__ bias, float* __restrict__ out)
{
    __shared__ float it[8][512];
    int t = threadIdx.x;
    int m0 = blockIdx.x * 8;
    int c = blockIdx.y * 256 + t;
    #pragma unroll
    for (int l = 0; l < 16; l++) {
        int idx = t + l * 256;
        int r = idx >> 9, kk = idx & 511;
        it[r][kk] = in[(size_t)(m0 + r) * Cn + kk];
    }
    __syncthreads();
    float acc[8] = {0.f,0.f,0.f,0.f,0.f,0.f,0.f,0.f};
    #pragma unroll 4
    for (int kk = 0; kk < Cn; kk++) {
        float wv = W[(size_t)kk * Cn + c];
        #pragma unroll
        for (int r = 0; r < 8; r++) acc[r] += it[r][kk] * wv;
    }
    float bv = bias[c];
    #pragma unroll
    for (int r = 0; r < 8; r++) out[(size_t)(m0 + r) * Cn + c] = acc[r] + bv;
}

// ---------------- K6: attention per (b,h,i) ------------------------------------
__global__ __launch_bounds__(128) void k_attn(
    const float* __restrict__ q, const float* __restrict__ k,
    const float* __restrict__ v, const float* __restrict__ gb,
    const float* __restrict__ beta_raw, float* __restrict__ attn_out)
{
    __shared__ float kv[128][65];
    __shared__ float qv[64];
    __shared__ float p[128];
    __shared__ float wred[2][2];

    int t = threadIdx.x;
    int bid = blockIdx.x;
    int b = bid / (Hn * Sn);
    int h = (bid / Sn) % Hn;
    int i = bid % Sn;
    size_t base = (size_t)b * Sn * Cn + (size_t)h * Dn;

    if (t < 64) qv[t] = q[base + (size_t)i * Cn + t];
    for (int l = 0; l < 64; l++) {
        int idx = t + l * 128;
        int j = idx >> 6, d = idx & 63;
        kv[j][d] = k[base + (size_t)j * Cn + d];
    }
    __syncthreads();

    float dot = 0.f;
    #pragma unroll
    for (int d = 0; d < 64; d++) dot += qv[d] * kv[t][d];

    float beta = log1pf(__expf(beta_raw[0]));
    float logit = dot * 0.125f + beta * gb[(size_t)b * Sn * Sn + (size_t)i * Sn + t];

    float m = logit;
    #pragma unroll
    for (int d = 1; d < 64; d <<= 1) m = fmaxf(m, __shfl_xor(m, d));
    if ((t & 63) == 0) wred[0][t >> 6] = m;
    __syncthreads();
    m = fmaxf(wred[0][0], wred[0][1]);
    float e = __expf(logit - m);
    float sm = e;
    #pragma unroll
    for (int d = 1; d < 64; d <<= 1) sm += __shfl_xor(sm, d);
    if ((t & 63) == 0) wred[1][t >> 6] = sm;
    __syncthreads();
    sm = wred[1][0] + wred[1][1];
    p[t] = e / sm;
    __syncthreads();

    for (int l = 0; l < 64; l++) {
        int idx = t + l * 128;
        int j = idx >> 6, d = idx & 63;
        kv[j][d] = v[base + (size_t)j * Cn + d];
    }
    __syncthreads();

    if (t < 64) {
        float o = 0.f;
        #pragma unroll 8
        for (int j = 0; j < 128; j++) o += p[j] * kv[j][t];
        attn_out[base + (size_t)i * Cn + t] = o;
    }
}

// ---------------- K8': out[n][c] = sum_s w[n,s]*so[s,c] via MFMA ---------------
__global__ __launch_bounds__(256) void k_out2(
    const unsigned short* __restrict__ wAll, const unsigned short* __restrict__ SoT,
    float* __restrict__ out)
{
    __shared__ __align__(16) unsigned At32[4096];
    __shared__ __align__(16) unsigned Bt32[4096];
    int t = threadIdx.x;
    int lane = t & 63;
    int wid = t >> 6;
    int ws = wid & 1, wc = wid >> 1;
    int l15 = lane & 15, lg = lane >> 4;
    int blk = blockIdx.x;
    int b = blk / (NB128 * 4);
    int rem = blk % (NB128 * 4);
    int rb = rem >> 2;
    int cb = rem & 3;
    int n0 = rb * 128, c0 = cb * 128;
    int nvalid = Nn - n0; if (nvalid > 128) nvalid = 128;
    const unsigned short* wb = wAll + (size_t)b * Nn * Sn;
    const unsigned short* sb = SoT + (size_t)b * Cn * Sn;

    f32x4 acc[4][4];
    const f32x4 fz = {0.f, 0.f, 0.f, 0.f};
    #pragma unroll
    for (int i = 0; i < 4; i++) {
        #pragma unroll
        for (int j = 0; j < 4; j++) acc[i][j] = fz;
    }

    #pragma unroll
    for (int ksi = 0; ksi < 2; ksi++) {
        stage_bf16tile(wb + (size_t)n0 * Sn + ksi * 64, Sn, nvalid, At32, t);
        stage_bf16tile(sb + (size_t)c0 * Sn + ksi * 64, Sn, 128, Bt32, t);
        __syncthreads();
        #pragma unroll
        for (int m = 0; m < 2; m++) {
            s16x8 af[4], bfr[4];
            #pragma unroll
            for (int i = 0; i < 4; i++)
                af[i] = *(const s16x8*)((const char*)At32 +
                        lds_off(ws * 64 + i * 16 + l15, m * 32 + lg * 8));
            #pragma unroll
            for (int j = 0; j < 4; j++)
                bfr[j] = *(const s16x8*)((const char*)Bt32 +
                        lds_off(wc * 64 + j * 16 + l15, m * 32 + lg * 8));
            #pragma unroll
            for (int i = 0; i < 4; i++) {
                #pragma unroll
                for (int j = 0; j < 4; j++)
                    acc[i][j] = __builtin_amdgcn_mfma_f32_16x16x32_bf16(
                        af[i], bfr[j], acc[i][j], 0, 0, 0);
            }
        }
        __syncthreads();
    }

    #pragma unroll
    for (int i = 0; i < 4; i++) {
        #pragma unroll
        for (int r = 0; r < 4; r++) {
            int n = n0 + ws * 64 + i * 16 + lg * 4 + r;
            if (n < Nn) {
                #pragma unroll
                for (int j = 0; j < 4; j++)
                    out[((size_t)b * Nn + n) * Cn + c0 + wc * 64 + j * 16 + l15] =
                        acc[i][j][r];
            }
        }
    }
}

extern "C" void kernel_launch(void* const* d_in, const int* in_sizes, int n_in,
                              void* d_out, int out_size, void* d_ws, size_t ws_size,
                              hipStream_t stream)
{
    const float* x  = (const float*)d_in[0];
    const int* adj  = (const int*)d_in[1];
    const float* av = (const float*)d_in[2];
    const float* Ws = (const float*)d_in[3];
    const float* bs = (const float*)d_in[4];
    const float* Wq = (const float*)d_in[5];
    const float* bq = (const float*)d_in[6];
    const float* Wk = (const float*)d_in[7];
    const float* bk = (const float*)d_in[8];
    const float* Wv = (const float*)d_in[9];
    const float* bv = (const float*)d_in[10];
    const float* Wo = (const float*)d_in[11];
    const float* bo = (const float*)d_in[12];
    const float* br = (const float*)d_in[13];
    float* out = (float*)d_out;
    (void)in_sizes; (void)n_in; (void)out_size; (void)ws_size;

    char* ws = (char*)d_ws;
    size_t off = 0;
    unsigned short* wb16  = (unsigned short*)(ws + off); off += (size_t)Bn * Nn * Sn * 2; // 10.24 MB
    unsigned short* xb16  = (unsigned short*)(ws + off); off += (size_t)Bn * Nn * Cn * 2; // 40.96 MB
    unsigned short* gwb16 = (unsigned short*)(ws + off); off += (size_t)Bn * Nn * Sn * 2; // 10.24 MB
    float* slices     = (float*)(ws + off); off += (size_t)Bn * Sn * Cn * 4;
    float* wsum       = (float*)(ws + off); off += 1024;
    float* gb_raw     = (float*)(ws + off); off += (size_t)Bn * Sn * Sn * 4;
    float* gb         = (float*)(ws + off); off += (size_t)Bn * Sn * Sn * 4;
    float* q          = (float*)(ws + off); off += (size_t)Bn * Sn * Cn * 4;
    float* kbuf       = (float*)(ws + off); off += (size_t)Bn * Sn * Cn * 4;
    float* vbuf       = (float*)(ws + off); off += (size_t)Bn * Sn * Cn * 4;
    float* attn_out   = (float*)(ws + off); off += (size_t)Bn * Sn * Cn * 4;
    float* slices_out = (float*)(ws + off); off += (size_t)Bn * Sn * Cn * 4;
    unsigned short* WsT = (unsigned short*)(ws + off); off += (size_t)Sn * Cn * 2;
    unsigned short* SoT = (unsigned short*)(ws + off); off += (size_t)Bn * Cn * Sn * 2;
    // Union region U: CSR buffers live [k_deg .. k_gather], then partialS
    // [k_mm(slices) .. k_reduceS], then partialG [k_mm(gb) .. k_reduceG].
    char* U = ws + off;
    int*  deg    = (int*)(U);
    int*  cursor = (int*)(U + 80128);
    int*  offs   = (int*)(U + 160256);
    int2* epack  = (int2*)(U + 240640);     // 2.56 MB
    float* partialS = (float*)U;            // 256 * 64 KB = 16.8 MB
    float* partialG = (float*)U;            // 158 * 64 KB = 10.4 MB

    hipMemsetAsync(wsum, 0, 1024, stream);
    hipMemsetAsync(U, 0, 160256, stream);   // deg + cursor

    k_prepWsT<<<dim3(16, 4), 256, 0, stream>>>(Ws, WsT);
    k_assign2<<<Bn * NB128, 256, 0, stream>>>(x, WsT, bs, wb16, xb16, wsum);

    // CSR build + gather (bf16 gw)
    k_deg<<<(En + 255) / 256, 256, 0, stream>>>(adj, deg);
    k_scan<<<1, 1024, 0, stream>>>(deg, offs);
    k_fill<<<(En + 255) / 256, 256, 0, stream>>>(adj, av, offs, cursor, epack);
    k_gather<<<Nn, 128, 0, stream>>>(wb16, epack, offs, gwb16);

    // slices = wT @ x / wsum  (pure-bf16 MFMA partials + reduce)
    k_mm<<<Bn * 4 * S_KB, 256, 0, stream>>>(wb16, xb16, Cn, 4, S_KB, S_CHUNK, partialS);
    k_reduceS<<<(Bn * Sn * Cn) / 256, 256, 0, stream>>>(partialS, wsum, slices);

    // gb_raw = wT @ gw (pure-bf16 MFMA partials + reduce)
    k_mm<<<Bn * G_KB, 256, 0, stream>>>(wb16, gwb16, Sn, 1, G_KB, G_CHUNK, partialG);
    k_reduceG<<<(Bn * Sn * Sn) / 256, 256, 0, stream>>>(partialG, gb_raw);
    k_gb_fin<<<Bn * Sn, 128, 0, stream>>>(gb_raw, gb);

    k_lin<<<dim3(32, 2), 256, 0, stream>>>(slices, Wq, bq, q);
    k_lin<<<dim3(32, 2), 256, 0, stream>>>(slices, Wk, bk, kbuf);
    k_lin<<<dim3(32, 2), 256, 0, stream>>>(slices, Wv, bv, vbuf);
    k_attn<<<Bn * Hn * Sn, 128, 0, stream>>>(q, kbuf, vbuf, gb, br, attn_out);
    k_lin<<<dim3(32, 2), 256, 0, stream>>>(attn_out, Wo, bo, slices_out);

    k_prepSoT<<<dim3(4, 16, Bn), 256, 0, stream>>>(slices_out, SoT);
    k_out2<<<Bn * NB128 * 4, 256, 0, stream>>>(wb16, SoT, out);
}

// Round 6
// 263.875 us; speedup vs baseline: 4.1154x; 1.4003x over previous
//
#include <hip/hip_runtime.h>
#include <math.h>

#define Bn 2
#define Nn 20000
#define Cn 512
#define Sn 128
#define Hn 8
#define Dn 64
#define En 320000
#define EPSf 1e-6f
#define NB128 157  // ceil(20000/128)

#define S_CHUNK 640
#define S_KB 32        // 32*640 = 20480 >= 20000
#define G_CHUNK 256
#define G_KB 79        // 79*256 = 20224 >= 20000

typedef __attribute__((ext_vector_type(4))) float f32x4;
typedef __attribute__((ext_vector_type(8))) short s16x8;

__device__ __forceinline__ unsigned short f2bf(float f) {
    unsigned u = __float_as_uint(f);
    return (unsigned short)((u + 0x7fffu + ((u >> 16) & 1u)) >> 16);
}
__device__ __forceinline__ float bf2f(unsigned short h) {
    return __uint_as_float(((unsigned)h) << 16);
}

// Swizzled LDS byte offset for a [128 rows][64 k] bf16 tile.
// Frag reads (16B, k mult of 8): 2-way bank aliasing (free per m136).
__device__ __forceinline__ unsigned lds_off(int row, int n) {
    unsigned ch = ((((unsigned)n >> 3) ^ ((unsigned)row & 7u) ^ (((unsigned)row >> 3) & 7u)) & 7u);
    return (unsigned)row * 128u + ch * 16u + ((unsigned)n & 7u) * 2u;
}

// ---- stage [128 rows][64 k] bf16 tile from bf16 row-major source (row=out dim)
__device__ __forceinline__ void stage_bf16tile(
    const unsigned short* __restrict__ src, int stride, int nvalid, unsigned* dst, int t)
{
    #pragma unroll
    for (int l = 0; l < 2; l++) {
        int task = t + l * 256;
        int row = task >> 2, seg = task & 3;
        s16x8 a = {0,0,0,0,0,0,0,0}, b = {0,0,0,0,0,0,0,0};
        if (row < nvalid) {
            a = *(const s16x8*)(src + (size_t)row * stride + seg * 16);
            b = *(const s16x8*)(src + (size_t)row * stride + seg * 16 + 8);
        }
        *(s16x8*)((char*)dst + lds_off(row, seg * 16)) = a;
        *(s16x8*)((char*)dst + lds_off(row, seg * 16 + 8)) = b;
    }
}

// ---- stage transpose-pack: [out:128][k(n):64] tile from [n][out] bf16 source --
__device__ __forceinline__ void stage_pairtile(
    const unsigned short* __restrict__ src, int stride, int c0,
    int nbase, int nlimit, unsigned* dst, int t)
{
    int c = t & 15;
    int p0 = t >> 4;
    #pragma unroll
    for (int half = 0; half < 2; half++) {
        int pp = p0 + half * 16;
        int nl = 2 * pp;
        int ng = nbase + nl;
        s16x8 a0 = {0,0,0,0,0,0,0,0}, a1 = {0,0,0,0,0,0,0,0};
        if (ng < nlimit)     a0 = *(const s16x8*)(src + (size_t)ng * stride + c0 + 8 * c);
        if (ng + 1 < nlimit) a1 = *(const s16x8*)(src + (size_t)(ng + 1) * stride + c0 + 8 * c);
        #pragma unroll
        for (int i = 0; i < 8; i++) {
            unsigned val = ((unsigned)(unsigned short)a0[i]) |
                           (((unsigned)(unsigned short)a1[i]) << 16);
            dst[lds_off(8 * c + i, nl) >> 2] = val;
        }
    }
}

// ---------------- prep: WsT[s][k] bf16 <- Ws[k][s] f32 -------------------------
__global__ __launch_bounds__(256) void k_prepWsT(
    const float* __restrict__ Ws, unsigned short* __restrict__ WsT)
{
    __shared__ float tile[32][33];
    int t = threadIdx.x;
    int k0 = blockIdx.x * 32;
    int s0 = blockIdx.y * 32;
    #pragma unroll
    for (int l = 0; l < 4; l++) {
        int idx = t + l * 256;
        int r = idx >> 5, c = idx & 31;
        tile[r][c] = Ws[(size_t)(k0 + r) * Sn + s0 + c];
    }
    __syncthreads();
    #pragma unroll
    for (int l = 0; l < 4; l++) {
        int idx = t + l * 256;
        int r = idx >> 5, c = idx & 31;
        WsT[(size_t)(s0 + r) * Cn + k0 + c] = f2bf(tile[c][r]);
    }
}

// ---------------- prep: WT[z][c_out][k] bf16 <- W_z[k][c_out] f32 --------------
__global__ __launch_bounds__(256) void k_prepWT(
    const float* __restrict__ Wq, const float* __restrict__ Wk,
    const float* __restrict__ Wv, const float* __restrict__ Wo,
    unsigned short* __restrict__ WT)
{
    __shared__ float tile[32][33];
    int t = threadIdx.x;
    int z = blockIdx.z;
    const float* W = (z == 0) ? Wq : (z == 1) ? Wk : (z == 2) ? Wv : Wo;
    unsigned short* dst = WT + (size_t)z * Cn * Cn;
    int k0 = blockIdx.x * 32;
    int c0 = blockIdx.y * 32;
    #pragma unroll
    for (int l = 0; l < 4; l++) {
        int idx = t + l * 256;
        int r = idx >> 5, c = idx & 31;
        tile[r][c] = W[(size_t)(k0 + r) * Cn + c0 + c];
    }
    __syncthreads();
    #pragma unroll
    for (int l = 0; l < 4; l++) {
        int idx = t + l * 256;
        int r = idx >> 5, c = idx & 31;
        dst[(size_t)(c0 + r) * Cn + k0 + c] = f2bf(tile[c][r]);
    }
}

// ---------------- K1': weights = softmax(x @ Ws + bs) via MFMA -----------------
// Also write-throughs the staged bf16 x tiles to xb16 (read by k_mm-slices).
__global__ __launch_bounds__(256) void k_assign2(
    const float* __restrict__ x, const unsigned short* __restrict__ WsT,
    const float* __restrict__ bs, unsigned short* __restrict__ weights,
    unsigned short* __restrict__ xb16, float* __restrict__ wsum)
{
    __shared__ __align__(16) unsigned At32[4096];
    __shared__ __align__(16) unsigned Bt32[4096];
    __shared__ float wsum_loc[128];

    int t = threadIdx.x;
    int lane = t & 63;
    int wid = t >> 6;
    int l15 = lane & 15, lg = lane >> 4;
    int blk = blockIdx.x;
    int b = blk / NB128;
    int rb = blk % NB128;
    int n0 = rb * 128;
    int nvalid = Nn - n0; if (nvalid > 128) nvalid = 128;
    const float* xb = x + (size_t)b * Nn * Cn;
    unsigned short* xb16g = xb16 + (size_t)b * Nn * Cn;

    if (t < 128) wsum_loc[t] = 0.f;

    f32x4 acc[2][8];
    const f32x4 fz = {0.f, 0.f, 0.f, 0.f};
    #pragma unroll
    for (int i = 0; i < 2; i++) {
        #pragma unroll
        for (int j = 0; j < 8; j++) acc[i][j] = fz;
    }

    for (int ks = 0; ks < 8; ks++) {
        #pragma unroll
        for (int l = 0; l < 2; l++) {
            int task = t + l * 256;
            int row = task >> 2, seg = task & 3;
            bool ok = (row < nvalid);
            float v[16];
            if (ok) {
                const float4* p = (const float4*)(xb + (size_t)(n0 + row) * Cn + ks * 64 + seg * 16);
                float4 a = p[0], bq = p[1], c = p[2], d = p[3];
                v[0]=a.x; v[1]=a.y; v[2]=a.z; v[3]=a.w;
                v[4]=bq.x; v[5]=bq.y; v[6]=bq.z; v[7]=bq.w;
                v[8]=c.x; v[9]=c.y; v[10]=c.z; v[11]=c.w;
                v[12]=d.x; v[13]=d.y; v[14]=d.z; v[15]=d.w;
            } else {
                #pragma unroll
                for (int i = 0; i < 16; i++) v[i] = 0.f;
            }
            uint4 u[2];
            #pragma unroll
            for (int h = 0; h < 2; h++) {
                u[h].x = (unsigned)f2bf(v[h*8+0]) | (((unsigned)f2bf(v[h*8+1])) << 16);
                u[h].y = (unsigned)f2bf(v[h*8+2]) | (((unsigned)f2bf(v[h*8+3])) << 16);
                u[h].z = (unsigned)f2bf(v[h*8+4]) | (((unsigned)f2bf(v[h*8+5])) << 16);
                u[h].w = (unsigned)f2bf(v[h*8+6]) | (((unsigned)f2bf(v[h*8+7])) << 16);
                *(uint4*)((char*)At32 + lds_off(row, seg * 16 + h * 8)) = u[h];
            }
            if (ok) {
                uint4* dst = (uint4*)(xb16g + (size_t)(n0 + row) * Cn + ks * 64 + seg * 16);
                dst[0] = u[0]; dst[1] = u[1];
            }
        }
        stage_bf16tile(WsT + ks * 64, Cn, 128, Bt32, t);
        __syncthreads();
        #pragma unroll
        for (int m = 0; m < 2; m++) {
            s16x8 af[2];
            #pragma unroll
            for (int i = 0; i < 2; i++)
                af[i] = *(const s16x8*)((const char*)At32 +
                        lds_off(wid * 32 + i * 16 + l15, m * 32 + lg * 8));
            #pragma unroll
            for (int j = 0; j < 8; j++) {
                s16x8 bf = *(const s16x8*)((const char*)Bt32 +
                        lds_off(j * 16 + l15, m * 32 + lg * 8));
                #pragma unroll
                for (int i = 0; i < 2; i++)
                    acc[i][j] = __builtin_amdgcn_mfma_f32_16x16x32_bf16(
                        af[i], bf, acc[i][j], 0, 0, 0);
            }
        }
        __syncthreads();
    }

    float bsv[8];
    #pragma unroll
    for (int j = 0; j < 8; j++) bsv[j] = bs[j * 16 + l15];

    unsigned short* wb = weights + (size_t)b * Nn * Sn;
    float wacc[8] = {0.f,0.f,0.f,0.f,0.f,0.f,0.f,0.f};
    #pragma unroll
    for (int i = 0; i < 2; i++) {
        #pragma unroll
        for (int r = 0; r < 4; r++) {
            float lv[8];
            #pragma unroll
            for (int j = 0; j < 8; j++) lv[j] = acc[i][j][r] + bsv[j];
            float m = lv[0];
            #pragma unroll
            for (int j = 1; j < 8; j++) m = fmaxf(m, lv[j]);
            m = fmaxf(m, __shfl_xor(m, 1));
            m = fmaxf(m, __shfl_xor(m, 2));
            m = fmaxf(m, __shfl_xor(m, 4));
            m = fmaxf(m, __shfl_xor(m, 8));
            float e[8], sm = 0.f;
            #pragma unroll
            for (int j = 0; j < 8; j++) { e[j] = __expf(lv[j] - m); sm += e[j]; }
            sm += __shfl_xor(sm, 1);
            sm += __shfl_xor(sm, 2);
            sm += __shfl_xor(sm, 4);
            sm += __shfl_xor(sm, 8);
            float inv = 1.f / sm;
            int n = n0 + wid * 32 + i * 16 + lg * 4 + r;
            bool valid = (n < Nn);
            #pragma unroll
            for (int j = 0; j < 8; j++) {
                float w = e[j] * inv;
                if (valid) {
                    wb[(size_t)n * Sn + j * 16 + l15] = f2bf(w);
                    wacc[j] += w;
                }
            }
        }
    }
    #pragma unroll
    for (int j = 0; j < 8; j++) {
        wacc[j] += __shfl_xor(wacc[j], 16);
        wacc[j] += __shfl_xor(wacc[j], 32);
    }
    if (lg == 0) {
        #pragma unroll
        for (int j = 0; j < 8; j++) atomicAdd(&wsum_loc[j * 16 + l15], wacc[j]);
    }
    __syncthreads();
    if (t < 128) atomicAdd(&wsum[b * Sn + t], wsum_loc[t]);
}

// ---------------- CSR build: degree histogram ----------------------------------
__global__ __launch_bounds__(256) void k_deg(
    const int* __restrict__ adj, int* __restrict__ deg)
{
    int e = blockIdx.x * 256 + threadIdx.x;
    if (e < En) atomicAdd(&deg[adj[e]], 1);
}

// ---------------- CSR build: single-block wave-shuffle prefix scan -------------
__global__ __launch_bounds__(1024) void k_scan(
    const int* __restrict__ deg, int* __restrict__ offs)
{
    __shared__ int wsums[16];
    __shared__ int excl[16];
    __shared__ int runsS;
    __shared__ int totS;
    int t = threadIdx.x;
    int lane = t & 63;
    int w = t >> 6;
    if (t == 0) { offs[0] = 0; runsS = 0; }
    __syncthreads();
    for (int base = 0; base < Nn; base += 1024) {
        int v = (base + t < Nn) ? deg[base + t] : 0;
        int sv = v;
        #pragma unroll
        for (int d = 1; d < 64; d <<= 1) {
            int u = __shfl_up(sv, d);
            if (lane >= d) sv += u;
        }
        if (lane == 63) wsums[w] = sv;
        __syncthreads();
        if (t < 16) {
            int xv = wsums[t];
            int sw = xv;
            #pragma unroll
            for (int d = 1; d < 16; d <<= 1) {
                int u = __shfl_up(sw, d);
                if (t >= d) sw += u;
            }
            excl[t] = sw - xv;
            if (t == 15) totS = sw;
        }
        __syncthreads();
        if (base + t < Nn) offs[base + t + 1] = runsS + excl[w] + sv;
        __syncthreads();
        if (t == 0) runsS += totS;
        __syncthreads();
    }
}

// ---------------- CSR build: fill packed (col, val) edge records ---------------
__global__ __launch_bounds__(256) void k_fill(
    const int* __restrict__ adj, const float* __restrict__ vals,
    const int* __restrict__ offs, int* __restrict__ cursor,
    int2* __restrict__ epack)
{
    int e = blockIdx.x * 256 + threadIdx.x;
    if (e < En) {
        int r = adj[e];
        int p = atomicAdd(&cursor[r], 1);
        epack[offs[r] + p] = make_int2(adj[En + e], __float_as_int(vals[e]));
    }
}

// ---------------- K3': gw[b,r,:] = sum_{edges} v * w[b,col,:] -> bf16 ----------
__global__ __launch_bounds__(128) void k_gather(
    const unsigned short* __restrict__ weights, const int2* __restrict__ epack,
    const int* __restrict__ offs, unsigned short* __restrict__ gwb)
{
    int r = blockIdx.x;
    int s = threadIdx.x;
    int o0 = offs[r], o1 = offs[r + 1];
    const unsigned short* w0 = weights;
    const unsigned short* w1 = weights + (size_t)Nn * Sn;
    float a0 = 0.f, a1 = 0.f;
    int j = o0;
    for (; j + 4 <= o1; j += 4) {
        int2 e0 = epack[j], e1 = epack[j + 1], e2 = epack[j + 2], e3 = epack[j + 3];
        float v0 = __int_as_float(e0.y), v1 = __int_as_float(e1.y);
        float v2 = __int_as_float(e2.y), v3 = __int_as_float(e3.y);
        float p00 = bf2f(w0[(size_t)e0.x * Sn + s]);
        float p01 = bf2f(w1[(size_t)e0.x * Sn + s]);
        float p10 = bf2f(w0[(size_t)e1.x * Sn + s]);
        float p11 = bf2f(w1[(size_t)e1.x * Sn + s]);
        float p20 = bf2f(w0[(size_t)e2.x * Sn + s]);
        float p21 = bf2f(w1[(size_t)e2.x * Sn + s]);
        float p30 = bf2f(w0[(size_t)e3.x * Sn + s]);
        float p31 = bf2f(w1[(size_t)e3.x * Sn + s]);
        a0 += v0 * p00 + v1 * p10 + v2 * p20 + v3 * p30;
        a1 += v0 * p01 + v1 * p11 + v2 * p21 + v3 * p31;
    }
    for (; j < o1; j++) {
        int2 e = epack[j];
        float v = __int_as_float(e.y);
        a0 += v * bf2f(w0[(size_t)e.x * Sn + s]);
        a1 += v * bf2f(w1[(size_t)e.x * Sn + s]);
    }
    gwb[(size_t)r * Sn + s] = f2bf(a0);
    gwb[(size_t)Nn * Sn + (size_t)r * Sn + s] = f2bf(a1);
}

// ---------------- K2'/K4': partial[s][c] = sum_{n in chunk} w[n,s]*B[n,c] ------
__global__ __launch_bounds__(256) void k_mm(
    const unsigned short* __restrict__ wAall, const unsigned short* __restrict__ Ball,
    int Bstride, int nCb, int kbCount, int chunk,
    float* __restrict__ partial)
{
    __shared__ __align__(16) unsigned At32[4096];
    __shared__ __align__(16) unsigned Bt32[4096];
    int t = threadIdx.x;
    int lane = t & 63;
    int wid = t >> 6;
    int ws = wid & 1, wc = wid >> 1;
    int blk = blockIdx.x;
    int b = blk / (nCb * kbCount);
    int rem = blk % (nCb * kbCount);
    int cb = rem / kbCount;
    int kb = rem % kbCount;
    int n0 = kb * chunk;
    int c0 = cb * 128;
    const unsigned short* wA = wAall + (size_t)b * Nn * Sn;
    const unsigned short* Bsrc = Ball + (size_t)b * Nn * Bstride;

    f32x4 acc[4][4];
    const f32x4 fz = {0.f, 0.f, 0.f, 0.f};
    #pragma unroll
    for (int i = 0; i < 4; i++) {
        #pragma unroll
        for (int j = 0; j < 4; j++) acc[i][j] = fz;
    }

    int l15 = lane & 15, lg = lane >> 4;

    for (int kt = 0; kt < chunk; kt += 64) {
        stage_pairtile(wA, Sn, 0, n0 + kt, Nn, At32, t);
        stage_pairtile(Bsrc, Bstride, c0, n0 + kt, Nn, Bt32, t);
        __syncthreads();
        #pragma unroll
        for (int m = 0; m < 2; m++) {
            s16x8 af[4], bfr[4];
            #pragma unroll
            for (int i = 0; i < 4; i++) {
                int row = ws * 64 + i * 16 + l15;
                af[i] = *(const s16x8*)((const char*)At32 + lds_off(row, m * 32 + lg * 8));
            }
            #pragma unroll
            for (int j = 0; j < 4; j++) {
                int row = wc * 64 + j * 16 + l15;
                bfr[j] = *(const s16x8*)((const char*)Bt32 + lds_off(row, m * 32 + lg * 8));
            }
            #pragma unroll
            for (int i = 0; i < 4; i++) {
                #pragma unroll
                for (int j = 0; j < 4; j++)
                    acc[i][j] = __builtin_amdgcn_mfma_f32_16x16x32_bf16(
                        af[i], bfr[j], acc[i][j], 0, 0, 0);
            }
        }
        __syncthreads();
    }

    float* pp = partial + (size_t)blk * 16384;
    #pragma unroll
    for (int i = 0; i < 4; i++) {
        int srow = ws * 64 + i * 16 + lg * 4;
        #pragma unroll
        for (int j = 0; j < 4; j++) {
            int ccol = wc * 64 + j * 16 + l15;
            #pragma unroll
            for (int r = 0; r < 4; r++)
                pp[(size_t)(srow + r) * 128 + ccol] = acc[i][j][r];
        }
    }
}

// ---------------- reduce partials -> sl16 (with /wsum) -------------------------
__global__ __launch_bounds__(256) void k_reduceS(
    const float* __restrict__ partial, const float* __restrict__ wsum,
    unsigned short* __restrict__ sl16)
{
    int g = blockIdx.x * 256 + threadIdx.x;
    int c = g & 127;
    int s = (g >> 7) & 127;
    int cb = (g >> 14) & 3;
    int b = g >> 16;
    const float* pp = partial + (size_t)(b * 4 + cb) * S_KB * 16384 + (size_t)s * 128 + c;
    float sum = 0.f;
    #pragma unroll 8
    for (int kb = 0; kb < S_KB; kb++) sum += pp[(size_t)kb * 16384];
    sl16[((size_t)b * Sn + s) * Cn + cb * 128 + c] =
        f2bf(sum / fmaxf(wsum[b * Sn + s], EPSf));
}

// ---------------- reduce partials -> gb_raw ------------------------------------
__global__ __launch_bounds__(256) void k_reduceG(
    const float* __restrict__ partial, float* __restrict__ gb_raw)
{
    int g = blockIdx.x * 256 + threadIdx.x;
    int t2 = g & 127;
    int s = (g >> 7) & 127;
    int b = g >> 14;
    const float* pp = partial + (size_t)b * G_KB * 16384 + (size_t)s * 128 + t2;
    float sum = 0.f;
    #pragma unroll 8
    for (int kb = 0; kb < G_KB; kb++) sum += pp[(size_t)kb * 16384];
    gb_raw[(size_t)b * 16384 + (size_t)s * 128 + t2] = sum;
}

// ---------------- K4b: symmetrize, row-normalize, log --------------------------
__global__ __launch_bounds__(128) void k_gb_fin(
    const float* __restrict__ gb_raw, float* __restrict__ gb)
{
    int bid = blockIdx.x;
    int b = bid >> 7, i = bid & 127;
    int j = threadIdx.x;
    const float* gr = gb_raw + (size_t)b * Sn * Sn;
    float sym = 0.5f * (gr[i * Sn + j] + gr[j * Sn + i]);
    float sum = sym;
    #pragma unroll
    for (int d = 1; d < 64; d <<= 1) sum += __shfl_xor(sum, d);
    __shared__ float wred[2];
    if ((j & 63) == 0) wred[j >> 6] = sum;
    __syncthreads();
    sum = wred[0] + wred[1];
    float r = fmaxf(sum, EPSf);
    gb[(size_t)b * Sn * Sn + (size_t)i * Sn + j] = logf(fmaxf(sym / r, EPSf));
}

// ---------------- K5': q/k/v = sl16 @ WT[z] + bias, MFMA, fused ----------------
// Grid: (rb=2, cb=4, sel=3). 128x128 tile, K=512 in 8 stages.
__global__ __launch_bounds__(256) void k_qkv(
    const unsigned short* __restrict__ sl16, const unsigned short* __restrict__ WT,
    const float* __restrict__ bq, const float* __restrict__ bk,
    const float* __restrict__ bv,
    float* __restrict__ q, float* __restrict__ kb, float* __restrict__ vb)
{
    __shared__ __align__(16) unsigned At32[4096];
    __shared__ __align__(16) unsigned Bt32[4096];
    int t = threadIdx.x;
    int lane = t & 63;
    int wid = t >> 6;
    int ws = wid & 1, wc = wid >> 1;
    int l15 = lane & 15, lg = lane >> 4;
    int rb = blockIdx.x, cb = blockIdx.y, sel = blockIdx.z;
    const unsigned short* Bmat = WT + (size_t)sel * Cn * Cn;
    const float* bias = (sel == 0) ? bq : (sel == 1) ? bk : bv;
    float* outp = (sel == 0) ? q : (sel == 1) ? kb : vb;

    f32x4 acc[4][4];
    const f32x4 fz = {0.f, 0.f, 0.f, 0.f};
    #pragma unroll
    for (int i = 0; i < 4; i++) {
        #pragma unroll
        for (int j = 0; j < 4; j++) acc[i][j] = fz;
    }

    for (int ks = 0; ks < 8; ks++) {
        stage_bf16tile(sl16 + (size_t)rb * 128 * Cn + ks * 64, Cn, 128, At32, t);
        stage_bf16tile(Bmat + (size_t)cb * 128 * Cn + ks * 64, Cn, 128, Bt32, t);
        __syncthreads();
        #pragma unroll
        for (int m = 0; m < 2; m++) {
            s16x8 af[4], bfr[4];
            #pragma unroll
            for (int i = 0; i < 4; i++)
                af[i] = *(const s16x8*)((const char*)At32 +
                        lds_off(ws * 64 + i * 16 + l15, m * 32 + lg * 8));
            #pragma unroll
            for (int j = 0; j < 4; j++)
                bfr[j] = *(const s16x8*)((const char*)Bt32 +
                        lds_off(wc * 64 + j * 16 + l15, m * 32 + lg * 8));
            #pragma unroll
            for (int i = 0; i < 4; i++) {
                #pragma unroll
                for (int j = 0; j < 4; j++)
                    acc[i][j] = __builtin_amdgcn_mfma_f32_16x16x32_bf16(
                        af[i], bfr[j], acc[i][j], 0, 0, 0);
            }
        }
        __syncthreads();
    }

    float bvv[4];
    #pragma unroll
    for (int j = 0; j < 4; j++) bvv[j] = bias[cb * 128 + wc * 64 + j * 16 + l15];
    #pragma unroll
    for (int i = 0; i < 4; i++) {
        #pragma unroll
        for (int r = 0; r < 4; r++) {
            int m = rb * 128 + ws * 64 + i * 16 + lg * 4 + r;
            #pragma unroll
            for (int j = 0; j < 4; j++)
                outp[(size_t)m * Cn + cb * 128 + wc * 64 + j * 16 + l15] =
                    acc[i][j][r] + bvv[j];
        }
    }
}

// ---------------- K6: attention per (b,h,i) -> bf16 out ------------------------
__global__ __launch_bounds__(128) void k_attn(
    const float* __restrict__ q, const float* __restrict__ k,
    const float* __restrict__ v, const float* __restrict__ gb,
    const float* __restrict__ beta_raw, unsigned short* __restrict__ attn16)
{
    __shared__ float kv[128][65];
    __shared__ float qv[64];
    __shared__ float p[128];
    __shared__ float wred[2][2];

    int t = threadIdx.x;
    int bid = blockIdx.x;
    int b = bid / (Hn * Sn);
    int h = (bid / Sn) % Hn;
    int i = bid % Sn;
    size_t base = (size_t)b * Sn * Cn + (size_t)h * Dn;

    if (t < 64) qv[t] = q[base + (size_t)i * Cn + t];
    for (int l = 0; l < 64; l++) {
        int idx = t + l * 128;
        int j = idx >> 6, d = idx & 63;
        kv[j][d] = k[base + (size_t)j * Cn + d];
    }
    __syncthreads();

    float dot = 0.f;
    #pragma unroll
    for (int d = 0; d < 64; d++) dot += qv[d] * kv[t][d];

    float beta = log1pf(__expf(beta_raw[0]));
    float logit = dot * 0.125f + beta * gb[(size_t)b * Sn * Sn + (size_t)i * Sn + t];

    float m = logit;
    #pragma unroll
    for (int d = 1; d < 64; d <<= 1) m = fmaxf(m, __shfl_xor(m, d));
    if ((t & 63) == 0) wred[0][t >> 6] = m;
    __syncthreads();
    m = fmaxf(wred[0][0], wred[0][1]);
    float e = __expf(logit - m);
    float sm = e;
    #pragma unroll
    for (int d = 1; d < 64; d <<= 1) sm += __shfl_xor(sm, d);
    if ((t & 63) == 0) wred[1][t >> 6] = sm;
    __syncthreads();
    sm = wred[1][0] + wred[1][1];
    p[t] = e / sm;
    __syncthreads();

    for (int l = 0; l < 64; l++) {
        int idx = t + l * 128;
        int j = idx >> 6, d = idx & 63;
        kv[j][d] = v[base + (size_t)j * Cn + d];
    }
    __syncthreads();

    if (t < 64) {
        float o = 0.f;
        #pragma unroll 8
        for (int j = 0; j < 128; j++) o += p[j] * kv[j][t];
        attn16[base + (size_t)i * Cn + t] = f2bf(o);
    }
}

// ---------------- K7': SoT[b][c][s] = (attn16 @ WoT + bo)^T bf16 ---------------
// Grid: (rb=b=2, cb=4). 128x128 tile, K=512 in 8 stages.
__global__ __launch_bounds__(256) void k_wo(
    const unsigned short* __restrict__ attn16, const unsigned short* __restrict__ WoT,
    const float* __restrict__ bo, unsigned short* __restrict__ SoT)
{
    __shared__ __align__(16) unsigned At32[4096];
    __shared__ __align__(16) unsigned Bt32[4096];
    int t = threadIdx.x;
    int lane = t & 63;
    int wid = t >> 6;
    int ws = wid & 1, wc = wid >> 1;
    int l15 = lane & 15, lg = lane >> 4;
    int b = blockIdx.x, cb = blockIdx.y;

    f32x4 acc[4][4];
    const f32x4 fz = {0.f, 0.f, 0.f, 0.f};
    #pragma unroll
    for (int i = 0; i < 4; i++) {
        #pragma unroll
        for (int j = 0; j < 4; j++) acc[i][j] = fz;
    }

    for (int ks = 0; ks < 8; ks++) {
        stage_bf16tile(attn16 + (size_t)b * 128 * Cn + ks * 64, Cn, 128, At32, t);
        stage_bf16tile(WoT + (size_t)cb * 128 * Cn + ks * 64, Cn, 128, Bt32, t);
        __syncthreads();
        #pragma unroll
        for (int m = 0; m < 2; m++) {
            s16x8 af[4], bfr[4];
            #pragma unroll
            for (int i = 0; i < 4; i++)
                af[i] = *(const s16x8*)((const char*)At32 +
                        lds_off(ws * 64 + i * 16 + l15, m * 32 + lg * 8));
            #pragma unroll
            for (int j = 0; j < 4; j++)
                bfr[j] = *(const s16x8*)((const char*)Bt32 +
                        lds_off(wc * 64 + j * 16 + l15, m * 32 + lg * 8));
            #pragma unroll
            for (int i = 0; i < 4; i++) {
                #pragma unroll
                for (int j = 0; j < 4; j++)
                    acc[i][j] = __builtin_amdgcn_mfma_f32_16x16x32_bf16(
                        af[i], bfr[j], acc[i][j], 0, 0, 0);
            }
        }
        __syncthreads();
    }

    float bvv[4];
    #pragma unroll
    for (int j = 0; j < 4; j++) bvv[j] = bo[cb * 128 + wc * 64 + j * 16 + l15];
    unsigned short* sb = SoT + (size_t)b * Cn * Sn;
    #pragma unroll
    for (int i = 0; i < 4; i++) {
        #pragma unroll
        for (int j = 0; j < 4; j++) {
            int c = cb * 128 + wc * 64 + j * 16 + l15;
            #pragma unroll
            for (int r = 0; r < 4; r++) {
                int s = ws * 64 + i * 16 + lg * 4 + r;
                sb[(size_t)c * Sn + s] = f2bf(acc[i][j][r] + bvv[j]);
            }
        }
    }
}

// ---------------- K8': out[n][c] = sum_s w[n,s]*so[s,c] via MFMA ---------------
__global__ __launch_bounds__(256) void k_out2(
    const unsigned short* __restrict__ wAll, const unsigned short* __restrict__ SoT,
    float* __restrict__ out)
{
    __shared__ __align__(16) unsigned At32[4096];
    __shared__ __align__(16) unsigned Bt32[4096];
    int t = threadIdx.x;
    int lane = t & 63;
    int wid = t >> 6;
    int ws = wid & 1, wc = wid >> 1;
    int l15 = lane & 15, lg = lane >> 4;
    int blk = blockIdx.x;
    int b = blk / (NB128 * 4);
    int rem = blk % (NB128 * 4);
    int rb = rem >> 2;
    int cb = rem & 3;
    int n0 = rb * 128, c0 = cb * 128;
    int nvalid = Nn - n0; if (nvalid > 128) nvalid = 128;
    const unsigned short* wb = wAll + (size_t)b * Nn * Sn;
    const unsigned short* sb = SoT + (size_t)b * Cn * Sn;

    f32x4 acc[4][4];
    const f32x4 fz = {0.f, 0.f, 0.f, 0.f};
    #pragma unroll
    for (int i = 0; i < 4; i++) {
        #pragma unroll
        for (int j = 0; j < 4; j++) acc[i][j] = fz;
    }

    #pragma unroll
    for (int ksi = 0; ksi < 2; ksi++) {
        stage_bf16tile(wb + (size_t)n0 * Sn + ksi * 64, Sn, nvalid, At32, t);
        stage_bf16tile(sb + (size_t)c0 * Sn + ksi * 64, Sn, 128, Bt32, t);
        __syncthreads();
        #pragma unroll
        for (int m = 0; m < 2; m++) {
            s16x8 af[4], bfr[4];
            #pragma unroll
            for (int i = 0; i < 4; i++)
                af[i] = *(const s16x8*)((const char*)At32 +
                        lds_off(ws * 64 + i * 16 + l15, m * 32 + lg * 8));
            #pragma unroll
            for (int j = 0; j < 4; j++)
                bfr[j] = *(const s16x8*)((const char*)Bt32 +
                        lds_off(wc * 64 + j * 16 + l15, m * 32 + lg * 8));
            #pragma unroll
            for (int i = 0; i < 4; i++) {
                #pragma unroll
                for (int j = 0; j < 4; j++)
                    acc[i][j] = __builtin_amdgcn_mfma_f32_16x16x32_bf16(
                        af[i], bfr[j], acc[i][j], 0, 0, 0);
            }
        }
        __syncthreads();
    }

    #pragma unroll
    for (int i = 0; i < 4; i++) {
        #pragma unroll
        for (int r = 0; r < 4; r++) {
            int n = n0 + ws * 64 + i * 16 + lg * 4 + r;
            if (n < Nn) {
                #pragma unroll
                for (int j = 0; j < 4; j++)
                    out[((size_t)b * Nn + n) * Cn + c0 + wc * 64 + j * 16 + l15] =
                        acc[i][j][r];
            }
        }
    }
}

extern "C" void kernel_launch(void* const* d_in, const int* in_sizes, int n_in,
                              void* d_out, int out_size, void* d_ws, size_t ws_size,
                              hipStream_t stream)
{
    const float* x  = (const float*)d_in[0];
    const int* adj  = (const int*)d_in[1];
    const float* av = (const float*)d_in[2];
    const float* Ws = (const float*)d_in[3];
    const float* bs = (const float*)d_in[4];
    const float* Wq = (const float*)d_in[5];
    const float* bq = (const float*)d_in[6];
    const float* Wk = (const float*)d_in[7];
    const float* bk = (const float*)d_in[8];
    const float* Wv = (const float*)d_in[9];
    const float* bv = (const float*)d_in[10];
    const float* Wo = (const float*)d_in[11];
    const float* bo = (const float*)d_in[12];
    const float* br = (const float*)d_in[13];
    float* out = (float*)d_out;
    (void)in_sizes; (void)n_in; (void)out_size; (void)ws_size;

    char* ws = (char*)d_ws;
    size_t off = 0;
    unsigned short* wb16  = (unsigned short*)(ws + off); off += (size_t)Bn * Nn * Sn * 2; // 10.24 MB
    unsigned short* xb16  = (unsigned short*)(ws + off); off += (size_t)Bn * Nn * Cn * 2; // 40.96 MB
    unsigned short* gwb16 = (unsigned short*)(ws + off); off += (size_t)Bn * Nn * Sn * 2; // 10.24 MB
    unsigned short* sl16  = (unsigned short*)(ws + off); off += (size_t)Bn * Sn * Cn * 2; // 256 KB
    float* wsum       = (float*)(ws + off); off += 1024;
    float* gb_raw     = (float*)(ws + off); off += (size_t)Bn * Sn * Sn * 4;
    float* gb         = (float*)(ws + off); off += (size_t)Bn * Sn * Sn * 4;
    float* q          = (float*)(ws + off); off += (size_t)Bn * Sn * Cn * 4;
    float* kbuf       = (float*)(ws + off); off += (size_t)Bn * Sn * Cn * 4;
    float* vbuf       = (float*)(ws + off); off += (size_t)Bn * Sn * Cn * 4;
    unsigned short* attn16 = (unsigned short*)(ws + off); off += (size_t)Bn * Sn * Cn * 2;
    unsigned short* WsT = (unsigned short*)(ws + off); off += (size_t)Sn * Cn * 2;
    unsigned short* WT  = (unsigned short*)(ws + off); off += (size_t)4 * Cn * Cn * 2;   // 2 MB
    unsigned short* SoT = (unsigned short*)(ws + off); off += (size_t)Bn * Cn * Sn * 2;
    // Union region U: CSR buffers live [k_deg .. k_gather], then partialS
    // [k_mm(slices) .. k_reduceS], then partialG [k_mm(gb) .. k_reduceG].
    char* U = ws + off;
    int*  deg    = (int*)(U);
    int*  cursor = (int*)(U + 80128);
    int*  offs   = (int*)(U + 160256);
    int2* epack  = (int2*)(U + 240640);     // 2.56 MB
    float* partialS = (float*)U;            // 256 * 64 KB = 16.8 MB
    float* partialG = (float*)U;            // 158 * 64 KB = 10.4 MB

    hipMemsetAsync(wsum, 0, 1024, stream);
    hipMemsetAsync(U, 0, 160256, stream);   // deg + cursor

    k_prepWsT<<<dim3(16, 4), 256, 0, stream>>>(Ws, WsT);
    k_prepWT<<<dim3(16, 16, 4), 256, 0, stream>>>(Wq, Wk, Wv, Wo, WT);
    k_assign2<<<Bn * NB128, 256, 0, stream>>>(x, WsT, bs, wb16, xb16, wsum);

    // CSR build + gather (bf16 gw)
    k_deg<<<(En + 255) / 256, 256, 0, stream>>>(adj, deg);
    k_scan<<<1, 1024, 0, stream>>>(deg, offs);
    k_fill<<<(En + 255) / 256, 256, 0, stream>>>(adj, av, offs, cursor, epack);
    k_gather<<<Nn, 128, 0, stream>>>(wb16, epack, offs, gwb16);

    // slices(bf16) = wT @ x / wsum  (pure-bf16 MFMA partials + reduce)
    k_mm<<<Bn * 4 * S_KB, 256, 0, stream>>>(wb16, xb16, Cn, 4, S_KB, S_CHUNK, partialS);
    k_reduceS<<<(Bn * Sn * Cn) / 256, 256, 0, stream>>>(partialS, wsum, sl16);

    // gb_raw = wT @ gw (pure-bf16 MFMA partials + reduce)
    k_mm<<<Bn * G_KB, 256, 0, stream>>>(wb16, gwb16, Sn, 1, G_KB, G_CHUNK, partialG);
    k_reduceG<<<(Bn * Sn * Sn) / 256, 256, 0, stream>>>(partialG, gb_raw);
    k_gb_fin<<<Bn * Sn, 128, 0, stream>>>(gb_raw, gb);

    // q/k/v via fused MFMA GEMM, then attention, then Wo (writes SoT directly)
    k_qkv<<<dim3(2, 4, 3), 256, 0, stream>>>(sl16, WT, bq, bk, bv, q, kbuf, vbuf);
    k_attn<<<Bn * Hn * Sn, 128, 0, stream>>>(q, kbuf, vbuf, gb, br, attn16);
    k_wo<<<dim3(2, 4), 256, 0, stream>>>(attn16, WT + (size_t)3 * Cn * Cn, bo, SoT);

    k_out2<<<Bn * NB128 * 4, 256, 0, stream>>>(wb16, SoT, out);
}

// Round 7
// 256.192 us; speedup vs baseline: 4.2388x; 1.0300x over previous
//
#include <hip/hip_runtime.h>
#include <math.h>

#define Bn 2
#define Nn 20000
#define Cn 512
#define Sn 128
#define Hn 8
#define Dn 64
#define En 320000
#define EPSf 1e-6f
#define NB64 313   // ceil(20000/64)
#define NB128 157  // ceil(20000/128)

#define S_CHUNK 320
#define S_KB 63        // 63*320 = 20160 >= 20000
#define G_CHUNK 128
#define G_KB 157       // 157*128 = 20096 >= 20000

typedef __attribute__((ext_vector_type(4))) float f32x4;
typedef __attribute__((ext_vector_type(8))) short s16x8;

__device__ __forceinline__ unsigned short f2bf(float f) {
    unsigned u = __float_as_uint(f);
    return (unsigned short)((u + 0x7fffu + ((u >> 16) & 1u)) >> 16);
}
__device__ __forceinline__ float bf2f(unsigned short h) {
    return __uint_as_float(((unsigned)h) << 16);
}

// Swizzled LDS byte offset for a [rows][64 k] bf16 tile (rows<=128).
// Frag reads (16B, k mult of 8): 2-way bank aliasing (free per m136).
__device__ __forceinline__ unsigned lds_off(int row, int n) {
    unsigned ch = ((((unsigned)n >> 3) ^ ((unsigned)row & 7u) ^ (((unsigned)row >> 3) & 7u)) & 7u);
    return (unsigned)row * 128u + ch * 16u + ((unsigned)n & 7u) * 2u;
}

// ---- stage [128 rows][64 k] bf16 tile from bf16 row-major source (row=out dim)
__device__ __forceinline__ void stage_bf16tile(
    const unsigned short* __restrict__ src, int stride, int nvalid, unsigned* dst, int t)
{
    #pragma unroll
    for (int l = 0; l < 2; l++) {
        int task = t + l * 256;
        int row = task >> 2, seg = task & 3;
        s16x8 a = {0,0,0,0,0,0,0,0}, b = {0,0,0,0,0,0,0,0};
        if (row < nvalid) {
            a = *(const s16x8*)(src + (size_t)row * stride + seg * 16);
            b = *(const s16x8*)(src + (size_t)row * stride + seg * 16 + 8);
        }
        *(s16x8*)((char*)dst + lds_off(row, seg * 16)) = a;
        *(s16x8*)((char*)dst + lds_off(row, seg * 16 + 8)) = b;
    }
}

// ---- stage transpose-pack: [out:128][k(n):64] tile from [n][out] bf16 source --
__device__ __forceinline__ void stage_pairtile(
    const unsigned short* __restrict__ src, int stride, int c0,
    int nbase, int nlimit, unsigned* dst, int t)
{
    int c = t & 15;
    int p0 = t >> 4;
    #pragma unroll
    for (int half = 0; half < 2; half++) {
        int pp = p0 + half * 16;
        int nl = 2 * pp;
        int ng = nbase + nl;
        s16x8 a0 = {0,0,0,0,0,0,0,0}, a1 = {0,0,0,0,0,0,0,0};
        if (ng < nlimit)     a0 = *(const s16x8*)(src + (size_t)ng * stride + c0 + 8 * c);
        if (ng + 1 < nlimit) a1 = *(const s16x8*)(src + (size_t)(ng + 1) * stride + c0 + 8 * c);
        #pragma unroll
        for (int i = 0; i < 8; i++) {
            unsigned val = ((unsigned)(unsigned short)a0[i]) |
                           (((unsigned)(unsigned short)a1[i]) << 16);
            dst[lds_off(8 * c + i, nl) >> 2] = val;
        }
    }
}

// ---- stage A(bf16 pairtile) + B(f32 source -> bf16) for k_mmS -----------------
__device__ __forceinline__ void stage_tilesF(
    const unsigned short* __restrict__ wA, const float* __restrict__ Bsrc,
    int Bstride, int c0, int nbase, unsigned* At32, unsigned* Bt32, int t)
{
    int c = t & 15;
    int p0 = t >> 4;
    #pragma unroll
    for (int half = 0; half < 2; half++) {
        int pp = p0 + half * 16;
        int nl = 2 * pp;
        int ng = nbase + nl;
        s16x8 a0 = {0,0,0,0,0,0,0,0}, a1 = {0,0,0,0,0,0,0,0};
        if (ng < Nn)     a0 = *(const s16x8*)(wA + (size_t)ng * Sn + 8 * c);
        if (ng + 1 < Nn) a1 = *(const s16x8*)(wA + (size_t)(ng + 1) * Sn + 8 * c);
        #pragma unroll
        for (int i = 0; i < 8; i++) {
            unsigned val = ((unsigned)(unsigned short)a0[i]) |
                           (((unsigned)(unsigned short)a1[i]) << 16);
            At32[lds_off(8 * c + i, nl) >> 2] = val;
        }
        float b0[8], b1[8];
        if (ng < Nn) {
            float4 v0 = *(const float4*)(Bsrc + (size_t)ng * Bstride + c0 + 8 * c);
            float4 v1 = *(const float4*)(Bsrc + (size_t)ng * Bstride + c0 + 8 * c + 4);
            b0[0]=v0.x; b0[1]=v0.y; b0[2]=v0.z; b0[3]=v0.w;
            b0[4]=v1.x; b0[5]=v1.y; b0[6]=v1.z; b0[7]=v1.w;
        } else {
            #pragma unroll
            for (int i = 0; i < 8; i++) b0[i] = 0.f;
        }
        if (ng + 1 < Nn) {
            float4 v0 = *(const float4*)(Bsrc + (size_t)(ng + 1) * Bstride + c0 + 8 * c);
            float4 v1 = *(const float4*)(Bsrc + (size_t)(ng + 1) * Bstride + c0 + 8 * c + 4);
            b1[0]=v0.x; b1[1]=v0.y; b1[2]=v0.z; b1[3]=v0.w;
            b1[4]=v1.x; b1[5]=v1.y; b1[6]=v1.z; b1[7]=v1.w;
        } else {
            #pragma unroll
            for (int i = 0; i < 8; i++) b1[i] = 0.f;
        }
        #pragma unroll
        for (int i = 0; i < 8; i++) {
            unsigned val = (unsigned)f2bf(b0[i]) | (((unsigned)f2bf(b1[i])) << 16);
            Bt32[lds_off(8 * c + i, nl) >> 2] = val;
        }
    }
}

// ---------------- prep: WsT[s][k] bf16 <- Ws[k][s] f32 -------------------------
__global__ __launch_bounds__(256) void k_prepWsT(
    const float* __restrict__ Ws, unsigned short* __restrict__ WsT)
{
    __shared__ float tile[32][33];
    int t = threadIdx.x;
    int k0 = blockIdx.x * 32;
    int s0 = blockIdx.y * 32;
    #pragma unroll
    for (int l = 0; l < 4; l++) {
        int idx = t + l * 256;
        int r = idx >> 5, c = idx & 31;
        tile[r][c] = Ws[(size_t)(k0 + r) * Sn + s0 + c];
    }
    __syncthreads();
    #pragma unroll
    for (int l = 0; l < 4; l++) {
        int idx = t + l * 256;
        int r = idx >> 5, c = idx & 31;
        WsT[(size_t)(s0 + r) * Cn + k0 + c] = f2bf(tile[c][r]);
    }
}

// ---------------- prep: WT[z][c_out][k] bf16 <- W_z[k][c_out] f32 --------------
__global__ __launch_bounds__(256) void k_prepWT(
    const float* __restrict__ Wq, const float* __restrict__ Wk,
    const float* __restrict__ Wv, const float* __restrict__ Wo,
    unsigned short* __restrict__ WT)
{
    __shared__ float tile[32][33];
    int t = threadIdx.x;
    int z = blockIdx.z;
    const float* W = (z == 0) ? Wq : (z == 1) ? Wk : (z == 2) ? Wv : Wo;
    unsigned short* dst = WT + (size_t)z * Cn * Cn;
    int k0 = blockIdx.x * 32;
    int c0 = blockIdx.y * 32;
    #pragma unroll
    for (int l = 0; l < 4; l++) {
        int idx = t + l * 256;
        int r = idx >> 5, c = idx & 31;
        tile[r][c] = W[(size_t)(k0 + r) * Cn + c0 + c];
    }
    __syncthreads();
    #pragma unroll
    for (int l = 0; l < 4; l++) {
        int idx = t + l * 256;
        int r = idx >> 5, c = idx & 31;
        dst[(size_t)(c0 + r) * Cn + k0 + c] = f2bf(tile[c][r]);
    }
}

// ---------------- K1'': weights = softmax(x @ Ws + bs), 64-row tiles -----------
// 626 blocks (2.4/CU), 4 waves; wave w owns rows [w*16, w*16+16), acc[8].
__global__ __launch_bounds__(256) void k_assign2(
    const float* __restrict__ x, const unsigned short* __restrict__ WsT,
    const float* __restrict__ bs, unsigned short* __restrict__ weights,
    float* __restrict__ wsum)
{
    __shared__ __align__(16) unsigned At32[2048];   // 8 KB: 64 rows x 64 k
    __shared__ __align__(16) unsigned Bt32[4096];   // 16 KB: 128 s x 64 k
    __shared__ float wsum_loc[128];

    int t = threadIdx.x;
    int lane = t & 63;
    int wid = t >> 6;
    int l15 = lane & 15, lg = lane >> 4;
    int blk = blockIdx.x;
    int b = blk / NB64;
    int rb = blk % NB64;
    int n0 = rb * 64;
    int nvalid = Nn - n0; if (nvalid > 64) nvalid = 64;
    const float* xb = x + (size_t)b * Nn * Cn;

    if (t < 128) wsum_loc[t] = 0.f;

    f32x4 acc[8];
    const f32x4 fz = {0.f, 0.f, 0.f, 0.f};
    #pragma unroll
    for (int j = 0; j < 8; j++) acc[j] = fz;

    for (int ks = 0; ks < 8; ks++) {
        // stage x f32 -> bf16 LDS: one task/thread (row=t>>2, seg=t&3)
        {
            int row = t >> 2, seg = t & 3;
            float v[16];
            if (row < nvalid) {
                const float4* p = (const float4*)(xb + (size_t)(n0 + row) * Cn + ks * 64 + seg * 16);
                float4 a = p[0], bq = p[1], c = p[2], d = p[3];
                v[0]=a.x; v[1]=a.y; v[2]=a.z; v[3]=a.w;
                v[4]=bq.x; v[5]=bq.y; v[6]=bq.z; v[7]=bq.w;
                v[8]=c.x; v[9]=c.y; v[10]=c.z; v[11]=c.w;
                v[12]=d.x; v[13]=d.y; v[14]=d.z; v[15]=d.w;
            } else {
                #pragma unroll
                for (int i = 0; i < 16; i++) v[i] = 0.f;
            }
            #pragma unroll
            for (int h = 0; h < 2; h++) {
                uint4 u;
                u.x = (unsigned)f2bf(v[h*8+0]) | (((unsigned)f2bf(v[h*8+1])) << 16);
                u.y = (unsigned)f2bf(v[h*8+2]) | (((unsigned)f2bf(v[h*8+3])) << 16);
                u.z = (unsigned)f2bf(v[h*8+4]) | (((unsigned)f2bf(v[h*8+5])) << 16);
                u.w = (unsigned)f2bf(v[h*8+6]) | (((unsigned)f2bf(v[h*8+7])) << 16);
                *(uint4*)((char*)At32 + lds_off(row, seg * 16 + h * 8)) = u;
            }
        }
        stage_bf16tile(WsT + ks * 64, Cn, 128, Bt32, t);
        __syncthreads();
        #pragma unroll
        for (int m = 0; m < 2; m++) {
            s16x8 af = *(const s16x8*)((const char*)At32 +
                       lds_off(wid * 16 + l15, m * 32 + lg * 8));
            #pragma unroll
            for (int j = 0; j < 8; j++) {
                s16x8 bf = *(const s16x8*)((const char*)Bt32 +
                           lds_off(j * 16 + l15, m * 32 + lg * 8));
                acc[j] = __builtin_amdgcn_mfma_f32_16x16x32_bf16(af, bf, acc[j], 0, 0, 0);
            }
        }
        __syncthreads();
    }

    float bsv[8];
    #pragma unroll
    for (int j = 0; j < 8; j++) bsv[j] = bs[j * 16 + l15];

    unsigned short* wb = weights + (size_t)b * Nn * Sn;
    float wacc[8] = {0.f,0.f,0.f,0.f,0.f,0.f,0.f,0.f};
    #pragma unroll
    for (int r = 0; r < 4; r++) {
        float lv[8];
        #pragma unroll
        for (int j = 0; j < 8; j++) lv[j] = acc[j][r] + bsv[j];
        float m = lv[0];
        #pragma unroll
        for (int j = 1; j < 8; j++) m = fmaxf(m, lv[j]);
        m = fmaxf(m, __shfl_xor(m, 1));
        m = fmaxf(m, __shfl_xor(m, 2));
        m = fmaxf(m, __shfl_xor(m, 4));
        m = fmaxf(m, __shfl_xor(m, 8));
        float e[8], sm = 0.f;
        #pragma unroll
        for (int j = 0; j < 8; j++) { e[j] = __expf(lv[j] - m); sm += e[j]; }
        sm += __shfl_xor(sm, 1);
        sm += __shfl_xor(sm, 2);
        sm += __shfl_xor(sm, 4);
        sm += __shfl_xor(sm, 8);
        float inv = 1.f / sm;
        int n = n0 + wid * 16 + lg * 4 + r;
        bool valid = (n < Nn);
        #pragma unroll
        for (int j = 0; j < 8; j++) {
            float w = e[j] * inv;
            if (valid) {
                wb[(size_t)n * Sn + j * 16 + l15] = f2bf(w);
                wacc[j] += w;
            }
        }
    }
    #pragma unroll
    for (int j = 0; j < 8; j++) {
        wacc[j] += __shfl_xor(wacc[j], 16);
        wacc[j] += __shfl_xor(wacc[j], 32);
    }
    if (lg == 0) {
        #pragma unroll
        for (int j = 0; j < 8; j++) atomicAdd(&wsum_loc[j * 16 + l15], wacc[j]);
    }
    __syncthreads();
    if (t < 128) atomicAdd(&wsum[b * Sn + t], wsum_loc[t]);
}

// ---------------- CSR build: degree histogram ----------------------------------
__global__ __launch_bounds__(256) void k_deg(
    const int* __restrict__ adj, int* __restrict__ deg)
{
    int e = blockIdx.x * 256 + threadIdx.x;
    if (e < En) atomicAdd(&deg[adj[e]], 1);
}

// ---------------- CSR build: single-block wave-shuffle prefix scan -------------
__global__ __launch_bounds__(1024) void k_scan(
    const int* __restrict__ deg, int* __restrict__ offs)
{
    __shared__ int wsums[16];
    __shared__ int excl[16];
    __shared__ int runsS;
    __shared__ int totS;
    int t = threadIdx.x;
    int lane = t & 63;
    int w = t >> 6;
    if (t == 0) { offs[0] = 0; runsS = 0; }
    __syncthreads();
    for (int base = 0; base < Nn; base += 1024) {
        int v = (base + t < Nn) ? deg[base + t] : 0;
        int sv = v;
        #pragma unroll
        for (int d = 1; d < 64; d <<= 1) {
            int u = __shfl_up(sv, d);
            if (lane >= d) sv += u;
        }
        if (lane == 63) wsums[w] = sv;
        __syncthreads();
        if (t < 16) {
            int xv = wsums[t];
            int sw = xv;
            #pragma unroll
            for (int d = 1; d < 16; d <<= 1) {
                int u = __shfl_up(sw, d);
                if (t >= d) sw += u;
            }
            excl[t] = sw - xv;
            if (t == 15) totS = sw;
        }
        __syncthreads();
        if (base + t < Nn) offs[base + t + 1] = runsS + excl[w] + sv;
        __syncthreads();
        if (t == 0) runsS += totS;
        __syncthreads();
    }
}

// ---------------- CSR build: fill packed (col, val) edge records ---------------
__global__ __launch_bounds__(256) void k_fill(
    const int* __restrict__ adj, const float* __restrict__ vals,
    const int* __restrict__ offs, int* __restrict__ cursor,
    int2* __restrict__ epack)
{
    int e = blockIdx.x * 256 + threadIdx.x;
    if (e < En) {
        int r = adj[e];
        int p = atomicAdd(&cursor[r], 1);
        epack[offs[r] + p] = make_int2(adj[En + e], __float_as_int(vals[e]));
    }
}

// ---------------- K3': gw[b,r,:] = sum_{edges} v * w[b,col,:] -> bf16 ----------
__global__ __launch_bounds__(128) void k_gather(
    const unsigned short* __restrict__ weights, const int2* __restrict__ epack,
    const int* __restrict__ offs, unsigned short* __restrict__ gwb)
{
    int r = blockIdx.x;
    int s = threadIdx.x;
    int o0 = offs[r], o1 = offs[r + 1];
    const unsigned short* w0 = weights;
    const unsigned short* w1 = weights + (size_t)Nn * Sn;
    float a0 = 0.f, a1 = 0.f;
    int j = o0;
    for (; j + 4 <= o1; j += 4) {
        int2 e0 = epack[j], e1 = epack[j + 1], e2 = epack[j + 2], e3 = epack[j + 3];
        float v0 = __int_as_float(e0.y), v1 = __int_as_float(e1.y);
        float v2 = __int_as_float(e2.y), v3 = __int_as_float(e3.y);
        float p00 = bf2f(w0[(size_t)e0.x * Sn + s]);
        float p01 = bf2f(w1[(size_t)e0.x * Sn + s]);
        float p10 = bf2f(w0[(size_t)e1.x * Sn + s]);
        float p11 = bf2f(w1[(size_t)e1.x * Sn + s]);
        float p20 = bf2f(w0[(size_t)e2.x * Sn + s]);
        float p21 = bf2f(w1[(size_t)e2.x * Sn + s]);
        float p30 = bf2f(w0[(size_t)e3.x * Sn + s]);
        float p31 = bf2f(w1[(size_t)e3.x * Sn + s]);
        a0 += v0 * p00 + v1 * p10 + v2 * p20 + v3 * p30;
        a1 += v0 * p01 + v1 * p11 + v2 * p21 + v3 * p31;
    }
    for (; j < o1; j++) {
        int2 e = epack[j];
        float v = __int_as_float(e.y);
        a0 += v * bf2f(w0[(size_t)e.x * Sn + s]);
        a1 += v * bf2f(w1[(size_t)e.x * Sn + s]);
    }
    gwb[(size_t)r * Sn + s] = f2bf(a0);
    gwb[(size_t)Nn * Sn + (size_t)r * Sn + s] = f2bf(a1);
}

// ---------------- K2': slices partials, A bf16 + B f32(x) ----------------------
__global__ __launch_bounds__(256) void k_mmS(
    const unsigned short* __restrict__ wAall, const float* __restrict__ xall,
    float* __restrict__ partial)
{
    __shared__ __align__(16) unsigned At32[4096];
    __shared__ __align__(16) unsigned Bt32[4096];
    int t = threadIdx.x;
    int lane = t & 63;
    int wid = t >> 6;
    int ws = wid & 1, wc = wid >> 1;
    int blk = blockIdx.x;
    int b = blk / (4 * S_KB);
    int rem = blk % (4 * S_KB);
    int cb = rem / S_KB;
    int kb = rem % S_KB;
    int n0 = kb * S_CHUNK;
    int c0 = cb * 128;
    const unsigned short* wA = wAall + (size_t)b * Nn * Sn;
    const float* Bsrc = xall + (size_t)b * Nn * Cn;

    f32x4 acc[4][4];
    const f32x4 fz = {0.f, 0.f, 0.f, 0.f};
    #pragma unroll
    for (int i = 0; i < 4; i++) {
        #pragma unroll
        for (int j = 0; j < 4; j++) acc[i][j] = fz;
    }

    int l15 = lane & 15, lg = lane >> 4;

    for (int kt = 0; kt < S_CHUNK; kt += 64) {
        stage_tilesF(wA, Bsrc, Cn, c0, n0 + kt, At32, Bt32, t);
        __syncthreads();
        #pragma unroll
        for (int m = 0; m < 2; m++) {
            s16x8 af[4], bfr[4];
            #pragma unroll
            for (int i = 0; i < 4; i++) {
                int row = ws * 64 + i * 16 + l15;
                af[i] = *(const s16x8*)((const char*)At32 + lds_off(row, m * 32 + lg * 8));
            }
            #pragma unroll
            for (int j = 0; j < 4; j++) {
                int row = wc * 64 + j * 16 + l15;
                bfr[j] = *(const s16x8*)((const char*)Bt32 + lds_off(row, m * 32 + lg * 8));
            }
            #pragma unroll
            for (int i = 0; i < 4; i++) {
                #pragma unroll
                for (int j = 0; j < 4; j++)
                    acc[i][j] = __builtin_amdgcn_mfma_f32_16x16x32_bf16(
                        af[i], bfr[j], acc[i][j], 0, 0, 0);
            }
        }
        __syncthreads();
    }

    float* pp = partial + (size_t)blk * 16384;
    #pragma unroll
    for (int i = 0; i < 4; i++) {
        int srow = ws * 64 + i * 16 + lg * 4;
        #pragma unroll
        for (int j = 0; j < 4; j++) {
            int ccol = wc * 64 + j * 16 + l15;
            #pragma unroll
            for (int r = 0; r < 4; r++)
                pp[(size_t)(srow + r) * 128 + ccol] = acc[i][j][r];
        }
    }
}

// ---------------- K4': gb partials, both operands bf16 -------------------------
__global__ __launch_bounds__(256) void k_mmG(
    const unsigned short* __restrict__ wAall, const unsigned short* __restrict__ gwall,
    float* __restrict__ partial)
{
    __shared__ __align__(16) unsigned At32[4096];
    __shared__ __align__(16) unsigned Bt32[4096];
    int t = threadIdx.x;
    int lane = t & 63;
    int wid = t >> 6;
    int ws = wid & 1, wc = wid >> 1;
    int blk = blockIdx.x;
    int b = blk / G_KB;
    int kb = blk % G_KB;
    int n0 = kb * G_CHUNK;
    const unsigned short* wA = wAall + (size_t)b * Nn * Sn;
    const unsigned short* Bsrc = gwall + (size_t)b * Nn * Sn;

    f32x4 acc[4][4];
    const f32x4 fz = {0.f, 0.f, 0.f, 0.f};
    #pragma unroll
    for (int i = 0; i < 4; i++) {
        #pragma unroll
        for (int j = 0; j < 4; j++) acc[i][j] = fz;
    }

    int l15 = lane & 15, lg = lane >> 4;

    for (int kt = 0; kt < G_CHUNK; kt += 64) {
        stage_pairtile(wA, Sn, 0, n0 + kt, Nn, At32, t);
        stage_pairtile(Bsrc, Sn, 0, n0 + kt, Nn, Bt32, t);
        __syncthreads();
        #pragma unroll
        for (int m = 0; m < 2; m++) {
            s16x8 af[4], bfr[4];
            #pragma unroll
            for (int i = 0; i < 4; i++) {
                int row = ws * 64 + i * 16 + l15;
                af[i] = *(const s16x8*)((const char*)At32 + lds_off(row, m * 32 + lg * 8));
            }
            #pragma unroll
            for (int j = 0; j < 4; j++) {
                int row = wc * 64 + j * 16 + l15;
                bfr[j] = *(const s16x8*)((const char*)Bt32 + lds_off(row, m * 32 + lg * 8));
            }
            #pragma unroll
            for (int i = 0; i < 4; i++) {
                #pragma unroll
                for (int j = 0; j < 4; j++)
                    acc[i][j] = __builtin_amdgcn_mfma_f32_16x16x32_bf16(
                        af[i], bfr[j], acc[i][j], 0, 0, 0);
            }
        }
        __syncthreads();
    }

    float* pp = partial + (size_t)blk * 16384;
    #pragma unroll
    for (int i = 0; i < 4; i++) {
        int srow = ws * 64 + i * 16 + lg * 4;
        #pragma unroll
        for (int j = 0; j < 4; j++) {
            int ccol = wc * 64 + j * 16 + l15;
            #pragma unroll
            for (int r = 0; r < 4; r++)
                pp[(size_t)(srow + r) * 128 + ccol] = acc[i][j][r];
        }
    }
}

// ---------------- reduce partials -> sl16 (with /wsum) -------------------------
__global__ __launch_bounds__(256) void k_reduceS(
    const float* __restrict__ partial, const float* __restrict__ wsum,
    unsigned short* __restrict__ sl16)
{
    int g = blockIdx.x * 256 + threadIdx.x;
    int c = g & 127;
    int s = (g >> 7) & 127;
    int cb = (g >> 14) & 3;
    int b = g >> 16;
    const float* pp = partial + (size_t)(b * 4 + cb) * S_KB * 16384 + (size_t)s * 128 + c;
    float sum = 0.f;
    #pragma unroll 7
    for (int kb = 0; kb < S_KB; kb++) sum += pp[(size_t)kb * 16384];
    sl16[((size_t)b * Sn + s) * Cn + cb * 128 + c] =
        f2bf(sum / fmaxf(wsum[b * Sn + s], EPSf));
}

// ---------------- reduce partials -> gb_raw ------------------------------------
__global__ __launch_bounds__(256) void k_reduceG(
    const float* __restrict__ partial, float* __restrict__ gb_raw)
{
    int g = blockIdx.x * 256 + threadIdx.x;
    int t2 = g & 127;
    int s = (g >> 7) & 127;
    int b = g >> 14;
    const float* pp = partial + (size_t)b * G_KB * 16384 + (size_t)s * 128 + t2;
    float sum = 0.f;
    #pragma unroll 8
    for (int kb = 0; kb < G_KB; kb++) sum += pp[(size_t)kb * 16384];
    gb_raw[(size_t)b * 16384 + (size_t)s * 128 + t2] = sum;
}

// ---------------- K4b: symmetrize, row-normalize, log --------------------------
__global__ __launch_bounds__(128) void k_gb_fin(
    const float* __restrict__ gb_raw, float* __restrict__ gb)
{
    int bid = blockIdx.x;
    int b = bid >> 7, i = bid & 127;
    int j = threadIdx.x;
    const float* gr = gb_raw + (size_t)b * Sn * Sn;
    float sym = 0.5f * (gr[i * Sn + j] + gr[j * Sn + i]);
    float sum = sym;
    #pragma unroll
    for (int d = 1; d < 64; d <<= 1) sum += __shfl_xor(sum, d);
    __shared__ float wred[2];
    if ((j & 63) == 0) wred[j >> 6] = sum;
    __syncthreads();
    sum = wred[0] + wred[1];
    float r = fmaxf(sum, EPSf);
    gb[(size_t)b * Sn * Sn + (size_t)i * Sn + j] = logf(fmaxf(sym / r, EPSf));
}

// ---------------- K5': q/k/v = sl16 @ WT[z] + bias, MFMA, fused ----------------
__global__ __launch_bounds__(256) void k_qkv(
    const unsigned short* __restrict__ sl16, const unsigned short* __restrict__ WT,
    const float* __restrict__ bq, const float* __restrict__ bk,
    const float* __restrict__ bv,
    float* __restrict__ q, float* __restrict__ kb, float* __restrict__ vb)
{
    __shared__ __align__(16) unsigned At32[4096];
    __shared__ __align__(16) unsigned Bt32[4096];
    int t = threadIdx.x;
    int lane = t & 63;
    int wid = t >> 6;
    int ws = wid & 1, wc = wid >> 1;
    int l15 = lane & 15, lg = lane >> 4;
    int rb = blockIdx.x, cb = blockIdx.y, sel = blockIdx.z;
    const unsigned short* Bmat = WT + (size_t)sel * Cn * Cn;
    const float* bias = (sel == 0) ? bq : (sel == 1) ? bk : bv;
    float* outp = (sel == 0) ? q : (sel == 1) ? kb : vb;

    f32x4 acc[4][4];
    const f32x4 fz = {0.f, 0.f, 0.f, 0.f};
    #pragma unroll
    for (int i = 0; i < 4; i++) {
        #pragma unroll
        for (int j = 0; j < 4; j++) acc[i][j] = fz;
    }

    for (int ks = 0; ks < 8; ks++) {
        stage_bf16tile(sl16 + (size_t)rb * 128 * Cn + ks * 64, Cn, 128, At32, t);
        stage_bf16tile(Bmat + (size_t)cb * 128 * Cn + ks * 64, Cn, 128, Bt32, t);
        __syncthreads();
        #pragma unroll
        for (int m = 0; m < 2; m++) {
            s16x8 af[4], bfr[4];
            #pragma unroll
            for (int i = 0; i < 4; i++)
                af[i] = *(const s16x8*)((const char*)At32 +
                        lds_off(ws * 64 + i * 16 + l15, m * 32 + lg * 8));
            #pragma unroll
            for (int j = 0; j < 4; j++)
                bfr[j] = *(const s16x8*)((const char*)Bt32 +
                        lds_off(wc * 64 + j * 16 + l15, m * 32 + lg * 8));
            #pragma unroll
            for (int i = 0; i < 4; i++) {
                #pragma unroll
                for (int j = 0; j < 4; j++)
                    acc[i][j] = __builtin_amdgcn_mfma_f32_16x16x32_bf16(
                        af[i], bfr[j], acc[i][j], 0, 0, 0);
            }
        }
        __syncthreads();
    }

    float bvv[4];
    #pragma unroll
    for (int j = 0; j < 4; j++) bvv[j] = bias[cb * 128 + wc * 64 + j * 16 + l15];
    #pragma unroll
    for (int i = 0; i < 4; i++) {
        #pragma unroll
        for (int r = 0; r < 4; r++) {
            int m = rb * 128 + ws * 64 + i * 16 + lg * 4 + r;
            #pragma unroll
            for (int j = 0; j < 4; j++)
                outp[(size_t)m * Cn + cb * 128 + wc * 64 + j * 16 + l15] =
                    acc[i][j][r] + bvv[j];
        }
    }
}

// ---------------- K6: attention per (b,h,i) -> bf16 out ------------------------
__global__ __launch_bounds__(128) void k_attn(
    const float* __restrict__ q, const float* __restrict__ k,
    const float* __restrict__ v, const float* __restrict__ gb,
    const float* __restrict__ beta_raw, unsigned short* __restrict__ attn16)
{
    __shared__ float kv[128][65];
    __shared__ float qv[64];
    __shared__ float p[128];
    __shared__ float wred[2][2];

    int t = threadIdx.x;
    int bid = blockIdx.x;
    int b = bid / (Hn * Sn);
    int h = (bid / Sn) % Hn;
    int i = bid % Sn;
    size_t base = (size_t)b * Sn * Cn + (size_t)h * Dn;

    if (t < 64) qv[t] = q[base + (size_t)i * Cn + t];
    for (int l = 0; l < 64; l++) {
        int idx = t + l * 128;
        int j = idx >> 6, d = idx & 63;
        kv[j][d] = k[base + (size_t)j * Cn + d];
    }
    __syncthreads();

    float dot = 0.f;
    #pragma unroll
    for (int d = 0; d < 64; d++) dot += qv[d] * kv[t][d];

    float beta = log1pf(__expf(beta_raw[0]));
    float logit = dot * 0.125f + beta * gb[(size_t)b * Sn * Sn + (size_t)i * Sn + t];

    float m = logit;
    #pragma unroll
    for (int d = 1; d < 64; d <<= 1) m = fmaxf(m, __shfl_xor(m, d));
    if ((t & 63) == 0) wred[0][t >> 6] = m;
    __syncthreads();
    m = fmaxf(wred[0][0], wred[0][1]);
    float e = __expf(logit - m);
    float sm = e;
    #pragma unroll
    for (int d = 1; d < 64; d <<= 1) sm += __shfl_xor(sm, d);
    if ((t & 63) == 0) wred[1][t >> 6] = sm;
    __syncthreads();
    sm = wred[1][0] + wred[1][1];
    p[t] = e / sm;
    __syncthreads();

    for (int l = 0; l < 64; l++) {
        int idx = t + l * 128;
        int j = idx >> 6, d = idx & 63;
        kv[j][d] = v[base + (size_t)j * Cn + d];
    }
    __syncthreads();

    if (t < 64) {
        float o = 0.f;
        #pragma unroll 8
        for (int j = 0; j < 128; j++) o += p[j] * kv[j][t];
        attn16[base + (size_t)i * Cn + t] = f2bf(o);
    }
}

// ---------------- K7': SoT[b][c][s] = (attn16 @ WoT + bo)^T bf16 ---------------
__global__ __launch_bounds__(256) void k_wo(
    const unsigned short* __restrict__ attn16, const unsigned short* __restrict__ WoT,
    const float* __restrict__ bo, unsigned short* __restrict__ SoT)
{
    __shared__ __align__(16) unsigned At32[4096];
    __shared__ __align__(16) unsigned Bt32[4096];
    int t = threadIdx.x;
    int lane = t & 63;
    int wid = t >> 6;
    int ws = wid & 1, wc = wid >> 1;
    int l15 = lane & 15, lg = lane >> 4;
    int b = blockIdx.x, cb = blockIdx.y;

    f32x4 acc[4][4];
    const f32x4 fz = {0.f, 0.f, 0.f, 0.f};
    #pragma unroll
    for (int i = 0; i < 4; i++) {
        #pragma unroll
        for (int j = 0; j < 4; j++) acc[i][j] = fz;
    }

    for (int ks = 0; ks < 8; ks++) {
        stage_bf16tile(attn16 + (size_t)b * 128 * Cn + ks * 64, Cn, 128, At32, t);
        stage_bf16tile(WoT + (size_t)cb * 128 * Cn + ks * 64, Cn, 128, Bt32, t);
        __syncthreads();
        #pragma unroll
        for (int m = 0; m < 2; m++) {
            s16x8 af[4], bfr[4];
            #pragma unroll
            for (int i = 0; i < 4; i++)
                af[i] = *(const s16x8*)((const char*)At32 +
                        lds_off(ws * 64 + i * 16 + l15, m * 32 + lg * 8));
            #pragma unroll
            for (int j = 0; j < 4; j++)
                bfr[j] = *(const s16x8*)((const char*)Bt32 +
                        lds_off(wc * 64 + j * 16 + l15, m * 32 + lg * 8));
            #pragma unroll
            for (int i = 0; i < 4; i++) {
                #pragma unroll
                for (int j = 0; j < 4; j++)
                    acc[i][j] = __builtin_amdgcn_mfma_f32_16x16x32_bf16(
                        af[i], bfr[j], acc[i][j], 0, 0, 0);
            }
        }
        __syncthreads();
    }

    float bvv[4];
    #pragma unroll
    for (int j = 0; j < 4; j++) bvv[j] = bo[cb * 128 + wc * 64 + j * 16 + l15];
    unsigned short* sb = SoT + (size_t)b * Cn * Sn;
    #pragma unroll
    for (int i = 0; i < 4; i++) {
        #pragma unroll
        for (int j = 0; j < 4; j++) {
            int c = cb * 128 + wc * 64 + j * 16 + l15;
            #pragma unroll
            for (int r = 0; r < 4; r++) {
                int s = ws * 64 + i * 16 + lg * 4 + r;
                sb[(size_t)c * Sn + s] = f2bf(acc[i][j][r] + bvv[j]);
            }
        }
    }
}

// ---------------- K8': out[n][c] = sum_s w[n,s]*so[s,c] via MFMA ---------------
__global__ __launch_bounds__(256) void k_out2(
    const unsigned short* __restrict__ wAll, const unsigned short* __restrict__ SoT,
    float* __restrict__ out)
{
    __shared__ __align__(16) unsigned At32[4096];
    __shared__ __align__(16) unsigned Bt32[4096];
    int t = threadIdx.x;
    int lane = t & 63;
    int wid = t >> 6;
    int ws = wid & 1, wc = wid >> 1;
    int l15 = lane & 15, lg = lane >> 4;
    int blk = blockIdx.x;
    int b = blk / (NB128 * 4);
    int rem = blk % (NB128 * 4);
    int rb = rem >> 2;
    int cb = rem & 3;
    int n0 = rb * 128, c0 = cb * 128;
    int nvalid = Nn - n0; if (nvalid > 128) nvalid = 128;
    const unsigned short* wb = wAll + (size_t)b * Nn * Sn;
    const unsigned short* sb = SoT + (size_t)b * Cn * Sn;

    f32x4 acc[4][4];
    const f32x4 fz = {0.f, 0.f, 0.f, 0.f};
    #pragma unroll
    for (int i = 0; i < 4; i++) {
        #pragma unroll
        for (int j = 0; j < 4; j++) acc[i][j] = fz;
    }

    #pragma unroll
    for (int ksi = 0; ksi < 2; ksi++) {
        stage_bf16tile(wb + (size_t)n0 * Sn + ksi * 64, Sn, nvalid, At32, t);
        stage_bf16tile(sb + (size_t)c0 * Sn + ksi * 64, Sn, 128, Bt32, t);
        __syncthreads();
        #pragma unroll
        for (int m = 0; m < 2; m++) {
            s16x8 af[4], bfr[4];
            #pragma unroll
            for (int i = 0; i < 4; i++)
                af[i] = *(const s16x8*)((const char*)At32 +
                        lds_off(ws * 64 + i * 16 + l15, m * 32 + lg * 8));
            #pragma unroll
            for (int j = 0; j < 4; j++)
                bfr[j] = *(const s16x8*)((const char*)Bt32 +
                        lds_off(wc * 64 + j * 16 + l15, m * 32 + lg * 8));
            #pragma unroll
            for (int i = 0; i < 4; i++) {
                #pragma unroll
                for (int j = 0; j < 4; j++)
                    acc[i][j] = __builtin_amdgcn_mfma_f32_16x16x32_bf16(
                        af[i], bfr[j], acc[i][j], 0, 0, 0);
            }
        }
        __syncthreads();
    }

    #pragma unroll
    for (int i = 0; i < 4; i++) {
        #pragma unroll
        for (int r = 0; r < 4; r++) {
            int n = n0 + ws * 64 + i * 16 + lg * 4 + r;
            if (n < Nn) {
                #pragma unroll
                for (int j = 0; j < 4; j++)
                    out[((size_t)b * Nn + n) * Cn + c0 + wc * 64 + j * 16 + l15] =
                        acc[i][j][r];
            }
        }
    }
}

extern "C" void kernel_launch(void* const* d_in, const int* in_sizes, int n_in,
                              void* d_out, int out_size, void* d_ws, size_t ws_size,
                              hipStream_t stream)
{
    const float* x  = (const float*)d_in[0];
    const int* adj  = (const int*)d_in[1];
    const float* av = (const float*)d_in[2];
    const float* Ws = (const float*)d_in[3];
    const float* bs = (const float*)d_in[4];
    const float* Wq = (const float*)d_in[5];
    const float* bq = (const float*)d_in[6];
    const float* Wk = (const float*)d_in[7];
    const float* bk = (const float*)d_in[8];
    const float* Wv = (const float*)d_in[9];
    const float* bv = (const float*)d_in[10];
    const float* Wo = (const float*)d_in[11];
    const float* bo = (const float*)d_in[12];
    const float* br = (const float*)d_in[13];
    float* out = (float*)d_out;
    (void)in_sizes; (void)n_in; (void)out_size; (void)ws_size;

    char* ws = (char*)d_ws;
    size_t off = 0;
    unsigned short* wb16  = (unsigned short*)(ws + off); off += (size_t)Bn * Nn * Sn * 2; // 10.24 MB
    unsigned short* gwb16 = (unsigned short*)(ws + off); off += (size_t)Bn * Nn * Sn * 2; // 10.24 MB
    unsigned short* sl16  = (unsigned short*)(ws + off); off += (size_t)Bn * Sn * Cn * 2; // 256 KB
    float* wsum       = (float*)(ws + off); off += 1024;
    float* gb_raw     = (float*)(ws + off); off += (size_t)Bn * Sn * Sn * 4;
    float* gb         = (float*)(ws + off); off += (size_t)Bn * Sn * Sn * 4;
    float* q          = (float*)(ws + off); off += (size_t)Bn * Sn * Cn * 4;
    float* kbuf       = (float*)(ws + off); off += (size_t)Bn * Sn * Cn * 4;
    float* vbuf       = (float*)(ws + off); off += (size_t)Bn * Sn * Cn * 4;
    unsigned short* attn16 = (unsigned short*)(ws + off); off += (size_t)Bn * Sn * Cn * 2;
    unsigned short* WsT = (unsigned short*)(ws + off); off += (size_t)Sn * Cn * 2;
    unsigned short* WT  = (unsigned short*)(ws + off); off += (size_t)4 * Cn * Cn * 2;   // 2 MB
    unsigned short* SoT = (unsigned short*)(ws + off); off += (size_t)Bn * Cn * Sn * 2;
    // Union region U: CSR buffers live [k_deg .. k_gather], then partialS
    // [k_mmS .. k_reduceS] (33.0 MB), then partialG [k_mmG .. k_reduceG] (20.6 MB).
    char* U = ws + off;
    int*  deg    = (int*)(U);
    int*  cursor = (int*)(U + 80128);
    int*  offs   = (int*)(U + 160256);
    int2* epack  = (int2*)(U + 240640);     // 2.56 MB
    float* partialS = (float*)U;            // 504 * 64 KB = 33.0 MB
    float* partialG = (float*)U;            // 314 * 64 KB = 20.6 MB

    hipMemsetAsync(wsum, 0, 1024, stream);
    hipMemsetAsync(U, 0, 160256, stream);   // deg + cursor

    k_prepWsT<<<dim3(16, 4), 256, 0, stream>>>(Ws, WsT);
    k_prepWT<<<dim3(16, 16, 4), 256, 0, stream>>>(Wq, Wk, Wv, Wo, WT);
    k_assign2<<<Bn * NB64, 256, 0, stream>>>(x, WsT, bs, wb16, wsum);

    // CSR build + gather (bf16 gw)
    k_deg<<<(En + 255) / 256, 256, 0, stream>>>(adj, deg);
    k_scan<<<1, 1024, 0, stream>>>(deg, offs);
    k_fill<<<(En + 255) / 256, 256, 0, stream>>>(adj, av, offs, cursor, epack);
    k_gather<<<Nn, 128, 0, stream>>>(wb16, epack, offs, gwb16);

    // slices(bf16) = wT @ x / wsum  (MFMA partials + reduce)
    k_mmS<<<Bn * 4 * S_KB, 256, 0, stream>>>(wb16, x, partialS);
    k_reduceS<<<(Bn * Sn * Cn) / 256, 256, 0, stream>>>(partialS, wsum, sl16);

    // gb_raw = wT @ gw (MFMA partials + reduce)
    k_mmG<<<Bn * G_KB, 256, 0, stream>>>(wb16, gwb16, partialG);
    k_reduceG<<<(Bn * Sn * Sn) / 256, 256, 0, stream>>>(partialG, gb_raw);
    k_gb_fin<<<Bn * Sn, 128, 0, stream>>>(gb_raw, gb);

    // q/k/v via fused MFMA GEMM, then attention, then Wo (writes SoT directly)
    k_qkv<<<dim3(2, 4, 3), 256, 0, stream>>>(sl16, WT, bq, bk, bv, q, kbuf, vbuf);
    k_attn<<<Bn * Hn * Sn, 128, 0, stream>>>(q, kbuf, vbuf, gb, br, attn16);
    k_wo<<<dim3(2, 4), 256, 0, stream>>>(attn16, WT + (size_t)3 * Cn * Cn, bo, SoT);

    k_out2<<<Bn * NB128 * 4, 256, 0, stream>>>(wb16, SoT, out);
}

// Round 9
// 253.756 us; speedup vs baseline: 4.2795x; 1.0096x over previous
//
#include <hip/hip_runtime.h>
#include <math.h>

#define Bn 2
#define Nn 20000
#define Cn 512
#define Sn 128
#define Hn 8
#define Dn 64
#define En 320000
#define EPSf 1e-6f
#define NB64 313   // ceil(20000/64)
#define NB128 157  // ceil(20000/128)

#define S_CHUNK 320
#define S_KB 63        // 63*320 = 20160 >= 20000
#define G_CHUNK 128
#define G_KB 157       // 157*128 = 20096 >= 20000

typedef __attribute__((ext_vector_type(4))) float f32x4;
typedef __attribute__((ext_vector_type(8))) short s16x8;

__device__ __forceinline__ unsigned short f2bf(float f) {
    unsigned u = __float_as_uint(f);
    return (unsigned short)((u + 0x7fffu + ((u >> 16) & 1u)) >> 16);
}
__device__ __forceinline__ float bf2f(unsigned short h) {
    return __uint_as_float(((unsigned)h) << 16);
}

// Swizzled LDS byte offset for a [rows][64 k] bf16 tile (rows<=128).
// Frag reads (16B, k mult of 8): 2-way bank aliasing (free per m136).
__device__ __forceinline__ unsigned lds_off(int row, int n) {
    unsigned ch = ((((unsigned)n >> 3) ^ ((unsigned)row & 7u) ^ (((unsigned)row >> 3) & 7u)) & 7u);
    return (unsigned)row * 128u + ch * 16u + ((unsigned)n & 7u) * 2u;
}

// ---- stage [128 rows][64 k] bf16 tile from bf16 row-major source (row=out dim)
__device__ __forceinline__ void stage_bf16tile(
    const unsigned short* __restrict__ src, int stride, int nvalid, unsigned* dst, int t)
{
    #pragma unroll
    for (int l = 0; l < 2; l++) {
        int task = t + l * 256;
        int row = task >> 2, seg = task & 3;
        s16x8 a = {0,0,0,0,0,0,0,0}, b = {0,0,0,0,0,0,0,0};
        if (row < nvalid) {
            a = *(const s16x8*)(src + (size_t)row * stride + seg * 16);
            b = *(const s16x8*)(src + (size_t)row * stride + seg * 16 + 8);
        }
        *(s16x8*)((char*)dst + lds_off(row, seg * 16)) = a;
        *(s16x8*)((char*)dst + lds_off(row, seg * 16 + 8)) = b;
    }
}

// ---- stage transpose-pack: [out:128][k(n):64] tile from [n][out] bf16 source --
__device__ __forceinline__ void stage_pairtile(
    const unsigned short* __restrict__ src, int stride, int c0,
    int nbase, int nlimit, unsigned* dst, int t)
{
    int c = t & 15;
    int p0 = t >> 4;
    #pragma unroll
    for (int half = 0; half < 2; half++) {
        int pp = p0 + half * 16;
        int nl = 2 * pp;
        int ng = nbase + nl;
        s16x8 a0 = {0,0,0,0,0,0,0,0}, a1 = {0,0,0,0,0,0,0,0};
        if (ng < nlimit)     a0 = *(const s16x8*)(src + (size_t)ng * stride + c0 + 8 * c);
        if (ng + 1 < nlimit) a1 = *(const s16x8*)(src + (size_t)(ng + 1) * stride + c0 + 8 * c);
        #pragma unroll
        for (int i = 0; i < 8; i++) {
            unsigned val = ((unsigned)(unsigned short)a0[i]) |
                           (((unsigned)(unsigned short)a1[i]) << 16);
            dst[lds_off(8 * c + i, nl) >> 2] = val;
        }
    }
}

// ---------------- prep: all weight transposes in one kernel --------------------
// z=0: WsT[s][k] <- Ws[k][s] (only blockIdx.y<4); z=1..4: WT[z-1][c][k] <- W[k][c]
__global__ __launch_bounds__(256) void k_prepW(
    const float* __restrict__ Ws, const float* __restrict__ Wq,
    const float* __restrict__ Wk, const float* __restrict__ Wv,
    const float* __restrict__ Wo, unsigned short* __restrict__ WsT,
    unsigned short* __restrict__ WT)
{
    __shared__ float tile[32][33];
    int t = threadIdx.x;
    int z = blockIdx.z;
    int k0 = blockIdx.x * 32;
    int c0 = blockIdx.y * 32;
    const float* W;
    unsigned short* dst;
    int ncols;
    if (z == 0) {
        if (c0 >= Sn) return;
        W = Ws; dst = WsT; ncols = Sn;
    } else {
        W = (z == 1) ? Wq : (z == 2) ? Wk : (z == 3) ? Wv : Wo;
        dst = WT + (size_t)(z - 1) * Cn * Cn; ncols = Cn;
    }
    #pragma unroll
    for (int l = 0; l < 4; l++) {
        int idx = t + l * 256;
        int r = idx >> 5, c = idx & 31;
        tile[r][c] = W[(size_t)(k0 + r) * ncols + c0 + c];
    }
    __syncthreads();
    #pragma unroll
    for (int l = 0; l < 4; l++) {
        int idx = t + l * 256;
        int r = idx >> 5, c = idx & 31;
        dst[(size_t)(c0 + r) * Cn + k0 + c] = f2bf(tile[c][r]);
    }
}

// ---------------- K1''': weights = softmax(x @ Ws + bs), pipelined -------------
// 626 blocks, 64-row tiles, double-buffered LDS + register prefetch (T14).
__global__ __launch_bounds__(256) void k_assign2(
    const float* __restrict__ x, const unsigned short* __restrict__ WsT,
    const float* __restrict__ bs, unsigned short* __restrict__ weights,
    float* __restrict__ wsum)
{
    __shared__ __align__(16) unsigned At32[2][2048];   // 2 x 8 KB (64 rows)
    __shared__ __align__(16) unsigned Bt32[2][4096];   // 2 x 16 KB (128 s)
    __shared__ float wsum_loc[128];

    int t = threadIdx.x;
    int lane = t & 63;
    int wid = t >> 6;
    int l15 = lane & 15, lg = lane >> 4;
    int blk = blockIdx.x;
    int b = blk / NB64;
    int rb = blk % NB64;
    int n0 = rb * 64;
    int nvalid = Nn - n0; if (nvalid > 64) nvalid = 64;
    const float* xb = x + (size_t)b * Nn * Cn;

    if (t < 128) wsum_loc[t] = 0.f;

    int arow = t >> 2, aseg = t & 3;
    bool aok = (arow < nvalid);
    const float4* aptr = (const float4*)(xb + (size_t)(n0 + arow) * Cn) + aseg * 4;
    int brow = t >> 2, bseg = t & 3;
    const unsigned short* bp0 = WsT + (size_t)brow * Cn + bseg * 16;
    const unsigned short* bp1 = WsT + (size_t)(brow + 64) * Cn + bseg * 16;

    const f32x4 fz = {0.f, 0.f, 0.f, 0.f};
    f32x4 acc[8];
    #pragma unroll
    for (int j = 0; j < 8; j++) acc[j] = fz;

    float4 ra[4];
    #pragma unroll
    for (int i = 0; i < 4; i++) ra[i] = make_float4(0.f, 0.f, 0.f, 0.f);
    s16x8 rb0a, rb0b, rb1a, rb1b;

    // prologue: issue loads for stage 0
    if (aok) { ra[0] = aptr[0]; ra[1] = aptr[1]; ra[2] = aptr[2]; ra[3] = aptr[3]; }
    rb0a = *(const s16x8*)(bp0);     rb0b = *(const s16x8*)(bp0 + 8);
    rb1a = *(const s16x8*)(bp1);     rb1b = *(const s16x8*)(bp1 + 8);

    int cur = 0;
    for (int ks = 0; ks < 8; ks++) {
        // write prefetched regs -> LDS[cur]
        {
            float v[16] = {ra[0].x, ra[0].y, ra[0].z, ra[0].w,
                           ra[1].x, ra[1].y, ra[1].z, ra[1].w,
                           ra[2].x, ra[2].y, ra[2].z, ra[2].w,
                           ra[3].x, ra[3].y, ra[3].z, ra[3].w};
            #pragma unroll
            for (int h = 0; h < 2; h++) {
                uint4 u;
                u.x = (unsigned)f2bf(v[h*8+0]) | (((unsigned)f2bf(v[h*8+1])) << 16);
                u.y = (unsigned)f2bf(v[h*8+2]) | (((unsigned)f2bf(v[h*8+3])) << 16);
                u.z = (unsigned)f2bf(v[h*8+4]) | (((unsigned)f2bf(v[h*8+5])) << 16);
                u.w = (unsigned)f2bf(v[h*8+6]) | (((unsigned)f2bf(v[h*8+7])) << 16);
                *(uint4*)((char*)At32[cur] + lds_off(arow, aseg * 16 + h * 8)) = u;
            }
            *(s16x8*)((char*)Bt32[cur] + lds_off(brow, bseg * 16)) = rb0a;
            *(s16x8*)((char*)Bt32[cur] + lds_off(brow, bseg * 16 + 8)) = rb0b;
            *(s16x8*)((char*)Bt32[cur] + lds_off(brow + 64, bseg * 16)) = rb1a;
            *(s16x8*)((char*)Bt32[cur] + lds_off(brow + 64, bseg * 16 + 8)) = rb1b;
        }
        // issue loads for stage ks+1 (in flight across barrier+MFMA)
        if (ks < 7) {
            int kn = ks + 1;
            if (aok) {
                ra[0] = aptr[kn*16]; ra[1] = aptr[kn*16+1];
                ra[2] = aptr[kn*16+2]; ra[3] = aptr[kn*16+3];
            }
            rb0a = *(const s16x8*)(bp0 + kn*64); rb0b = *(const s16x8*)(bp0 + kn*64 + 8);
            rb1a = *(const s16x8*)(bp1 + kn*64); rb1b = *(const s16x8*)(bp1 + kn*64 + 8);
        }
        __syncthreads();
        #pragma unroll
        for (int m = 0; m < 2; m++) {
            s16x8 af = *(const s16x8*)((const char*)At32[cur] +
                       lds_off(wid * 16 + l15, m * 32 + lg * 8));
            #pragma unroll
            for (int j = 0; j < 8; j++) {
                s16x8 bf = *(const s16x8*)((const char*)Bt32[cur] +
                           lds_off(j * 16 + l15, m * 32 + lg * 8));
                acc[j] = __builtin_amdgcn_mfma_f32_16x16x32_bf16(af, bf, acc[j], 0, 0, 0);
            }
        }
        __syncthreads();
        cur ^= 1;
    }

    float bsv[8];
    #pragma unroll
    for (int j = 0; j < 8; j++) bsv[j] = bs[j * 16 + l15];

    unsigned short* wb = weights + (size_t)b * Nn * Sn;
    unsigned short* wt = (unsigned short*)&At32[0][0];   // 16 KB = 64 x 128 bf16
    float wacc[8] = {0.f,0.f,0.f,0.f,0.f,0.f,0.f,0.f};
    #pragma unroll
    for (int r = 0; r < 4; r++) {
        float lv[8];
        #pragma unroll
        for (int j = 0; j < 8; j++) lv[j] = acc[j][r] + bsv[j];
        float m = lv[0];
        #pragma unroll
        for (int j = 1; j < 8; j++) m = fmaxf(m, lv[j]);
        m = fmaxf(m, __shfl_xor(m, 1));
        m = fmaxf(m, __shfl_xor(m, 2));
        m = fmaxf(m, __shfl_xor(m, 4));
        m = fmaxf(m, __shfl_xor(m, 8));
        float e[8], sm = 0.f;
        #pragma unroll
        for (int j = 0; j < 8; j++) { e[j] = __expf(lv[j] - m); sm += e[j]; }
        sm += __shfl_xor(sm, 1);
        sm += __shfl_xor(sm, 2);
        sm += __shfl_xor(sm, 4);
        sm += __shfl_xor(sm, 8);
        float inv = 1.f / sm;
        int rloc = wid * 16 + lg * 4 + r;
        bool valid = (n0 + rloc < Nn);
        #pragma unroll
        for (int j = 0; j < 8; j++) {
            float w = e[j] * inv;
            wt[rloc * 128 + j * 16 + l15] = f2bf(w);
            if (valid) wacc[j] += w;
        }
    }
    #pragma unroll
    for (int j = 0; j < 8; j++) {
        wacc[j] += __shfl_xor(wacc[j], 16);
        wacc[j] += __shfl_xor(wacc[j], 32);
    }
    if (lg == 0) {
        #pragma unroll
        for (int j = 0; j < 8; j++) atomicAdd(&wsum_loc[j * 16 + l15], wacc[j]);
    }
    __syncthreads();
    // coalesced writeout: 32 bf16 (4 x 16B) per thread  [R8 BUG FIX: was 2 uint4]
    {
        int orow = t >> 2, oseg = t & 3;
        if (orow < nvalid) {
            uint4* dst = (uint4*)(wb + (size_t)(n0 + orow) * Sn + oseg * 32);
            const uint4* src = (const uint4*)(wt + (size_t)orow * 128 + oseg * 32);
            dst[0] = src[0]; dst[1] = src[1]; dst[2] = src[2]; dst[3] = src[3];
        }
    }
    if (t < 128) atomicAdd(&wsum[b * Sn + t], wsum_loc[t]);
}

// ---------------- CSR build: degree histogram ----------------------------------
__global__ __launch_bounds__(256) void k_deg(
    const int* __restrict__ adj, int* __restrict__ deg)
{
    int e = blockIdx.x * 256 + threadIdx.x;
    if (e < En) atomicAdd(&deg[adj[e]], 1);
}

// ---------------- CSR build: single-block wave-shuffle prefix scan -------------
__global__ __launch_bounds__(1024) void k_scan(
    const int* __restrict__ deg, int* __restrict__ offs)
{
    __shared__ int wsums[16];
    __shared__ int excl[16];
    __shared__ int runsS;
    __shared__ int totS;
    int t = threadIdx.x;
    int lane = t & 63;
    int w = t >> 6;
    if (t == 0) { offs[0] = 0; runsS = 0; }
    __syncthreads();
    for (int base = 0; base < Nn; base += 1024) {
        int v = (base + t < Nn) ? deg[base + t] : 0;
        int sv = v;
        #pragma unroll
        for (int d = 1; d < 64; d <<= 1) {
            int u = __shfl_up(sv, d);
            if (lane >= d) sv += u;
        }
        if (lane == 63) wsums[w] = sv;
        __syncthreads();
        if (t < 16) {
            int xv = wsums[t];
            int sw = xv;
            #pragma unroll
            for (int d = 1; d < 16; d <<= 1) {
                int u = __shfl_up(sw, d);
                if (t >= d) sw += u;
            }
            excl[t] = sw - xv;
            if (t == 15) totS = sw;
        }
        __syncthreads();
        if (base + t < Nn) offs[base + t + 1] = runsS + excl[w] + sv;
        __syncthreads();
        if (t == 0) runsS += totS;
        __syncthreads();
    }
}

// ---------------- CSR build: fill packed (col, val) edge records ---------------
__global__ __launch_bounds__(256) void k_fill(
    const int* __restrict__ adj, const float* __restrict__ vals,
    const int* __restrict__ offs, int* __restrict__ cursor,
    int2* __restrict__ epack)
{
    int e = blockIdx.x * 256 + threadIdx.x;
    if (e < En) {
        int r = adj[e];
        int p = atomicAdd(&cursor[r], 1);
        epack[offs[r] + p] = make_int2(adj[En + e], __float_as_int(vals[e]));
    }
}

// ---------------- K3': gw[b,r,:] = sum_{edges} v * w[b,col,:] -> bf16 ----------
__global__ __launch_bounds__(128) void k_gather(
    const unsigned short* __restrict__ weights, const int2* __restrict__ epack,
    const int* __restrict__ offs, unsigned short* __restrict__ gwb)
{
    int r = blockIdx.x;
    int s = threadIdx.x;
    int o0 = offs[r], o1 = offs[r + 1];
    const unsigned short* w0 = weights;
    const unsigned short* w1 = weights + (size_t)Nn * Sn;
    float a0 = 0.f, a1 = 0.f;
    int j = o0;
    for (; j + 4 <= o1; j += 4) {
        int2 e0 = epack[j], e1 = epack[j + 1], e2 = epack[j + 2], e3 = epack[j + 3];
        float v0 = __int_as_float(e0.y), v1 = __int_as_float(e1.y);
        float v2 = __int_as_float(e2.y), v3 = __int_as_float(e3.y);
        float p00 = bf2f(w0[(size_t)e0.x * Sn + s]);
        float p01 = bf2f(w1[(size_t)e0.x * Sn + s]);
        float p10 = bf2f(w0[(size_t)e1.x * Sn + s]);
        float p11 = bf2f(w1[(size_t)e1.x * Sn + s]);
        float p20 = bf2f(w0[(size_t)e2.x * Sn + s]);
        float p21 = bf2f(w1[(size_t)e2.x * Sn + s]);
        float p30 = bf2f(w0[(size_t)e3.x * Sn + s]);
        float p31 = bf2f(w1[(size_t)e3.x * Sn + s]);
        a0 += v0 * p00 + v1 * p10 + v2 * p20 + v3 * p30;
        a1 += v0 * p01 + v1 * p11 + v2 * p21 + v3 * p31;
    }
    for (; j < o1; j++) {
        int2 e = epack[j];
        float v = __int_as_float(e.y);
        a0 += v * bf2f(w0[(size_t)e.x * Sn + s]);
        a1 += v * bf2f(w1[(size_t)e.x * Sn + s]);
    }
    gwb[(size_t)r * Sn + s] = f2bf(a0);
    gwb[(size_t)Nn * Sn + (size_t)r * Sn + s] = f2bf(a1);
}

// ---------------- K2'': slices partials, pipelined (T14) -----------------------
__global__ __launch_bounds__(256) void k_mmS(
    const unsigned short* __restrict__ wAall, const float* __restrict__ xall,
    float* __restrict__ partial)
{
    __shared__ __align__(16) unsigned At32[2][4096];
    __shared__ __align__(16) unsigned Bt32[2][4096];
    int t = threadIdx.x;
    int lane = t & 63;
    int wid = t >> 6;
    int ws = wid & 1, wc = wid >> 1;
    int blk = blockIdx.x;
    int b = blk / (4 * S_KB);
    int rem = blk % (4 * S_KB);
    int cb = rem / S_KB;
    int kb = rem % S_KB;
    int n0 = kb * S_CHUNK;
    int c0 = cb * 128;
    const unsigned short* wA = wAall + (size_t)b * Nn * Sn;
    const float* Bsrc = xall + (size_t)b * Nn * Cn;

    f32x4 acc[4][4];
    const f32x4 fz = {0.f, 0.f, 0.f, 0.f};
    #pragma unroll
    for (int i = 0; i < 4; i++) {
        #pragma unroll
        for (int j = 0; j < 4; j++) acc[i][j] = fz;
    }

    int l15 = lane & 15, lg = lane >> 4;
    int c = t & 15;
    int p0 = t >> 4;

    s16x8 pa[2][2];
    float4 pb[2][4];
    const s16x8 z8 = {0,0,0,0,0,0,0,0};

    auto LOADS = [&](int kt) {
        #pragma unroll
        for (int h = 0; h < 2; h++) {
            int nl = 2 * (p0 + h * 16);
            int ng = n0 + kt + nl;
            pa[h][0] = z8; pa[h][1] = z8;
            pb[h][0] = make_float4(0.f,0.f,0.f,0.f); pb[h][1] = pb[h][0];
            pb[h][2] = pb[h][0]; pb[h][3] = pb[h][0];
            if (ng < Nn) {
                pa[h][0] = *(const s16x8*)(wA + (size_t)ng * Sn + 8 * c);
                pb[h][0] = *(const float4*)(Bsrc + (size_t)ng * Cn + c0 + 8 * c);
                pb[h][1] = *(const float4*)(Bsrc + (size_t)ng * Cn + c0 + 8 * c + 4);
            }
            if (ng + 1 < Nn) {
                pa[h][1] = *(const s16x8*)(wA + (size_t)(ng + 1) * Sn + 8 * c);
                pb[h][2] = *(const float4*)(Bsrc + (size_t)(ng + 1) * Cn + c0 + 8 * c);
                pb[h][3] = *(const float4*)(Bsrc + (size_t)(ng + 1) * Cn + c0 + 8 * c + 4);
            }
        }
    };
    auto STORE = [&](int buf) {
        #pragma unroll
        for (int h = 0; h < 2; h++) {
            int nl = 2 * (p0 + h * 16);
            #pragma unroll
            for (int i = 0; i < 8; i++) {
                unsigned val = ((unsigned)(unsigned short)pa[h][0][i]) |
                               (((unsigned)(unsigned short)pa[h][1][i]) << 16);
                At32[buf][lds_off(8 * c + i, nl) >> 2] = val;
            }
            float b0[8] = {pb[h][0].x, pb[h][0].y, pb[h][0].z, pb[h][0].w,
                           pb[h][1].x, pb[h][1].y, pb[h][1].z, pb[h][1].w};
            float b1[8] = {pb[h][2].x, pb[h][2].y, pb[h][2].z, pb[h][2].w,
                           pb[h][3].x, pb[h][3].y, pb[h][3].z, pb[h][3].w};
            #pragma unroll
            for (int i = 0; i < 8; i++) {
                unsigned val = (unsigned)f2bf(b0[i]) | (((unsigned)f2bf(b1[i])) << 16);
                Bt32[buf][lds_off(8 * c + i, nl) >> 2] = val;
            }
        }
    };

    LOADS(0);
    int cur = 0;
    for (int it = 0; it < 5; it++) {     // S_CHUNK/64
        STORE(cur);
        if (it < 4) LOADS((it + 1) * 64);
        __syncthreads();
        #pragma unroll
        for (int m = 0; m < 2; m++) {
            s16x8 af[4], bfr[4];
            #pragma unroll
            for (int i = 0; i < 4; i++) {
                int row = ws * 64 + i * 16 + l15;
                af[i] = *(const s16x8*)((const char*)At32[cur] + lds_off(row, m * 32 + lg * 8));
            }
            #pragma unroll
            for (int j = 0; j < 4; j++) {
                int row = wc * 64 + j * 16 + l15;
                bfr[j] = *(const s16x8*)((const char*)Bt32[cur] + lds_off(row, m * 32 + lg * 8));
            }
            #pragma unroll
            for (int i = 0; i < 4; i++) {
                #pragma unroll
                for (int j = 0; j < 4; j++)
                    acc[i][j] = __builtin_amdgcn_mfma_f32_16x16x32_bf16(
                        af[i], bfr[j], acc[i][j], 0, 0, 0);
            }
        }
        __syncthreads();
        cur ^= 1;
    }

    float* pp = partial + (size_t)blk * 16384;
    #pragma unroll
    for (int i = 0; i < 4; i++) {
        int srow = ws * 64 + i * 16 + lg * 4;
        #pragma unroll
        for (int j = 0; j < 4; j++) {
            int ccol = wc * 64 + j * 16 + l15;
            #pragma unroll
            for (int r = 0; r < 4; r++)
                pp[(size_t)(srow + r) * 128 + ccol] = acc[i][j][r];
        }
    }
}

// ---------------- K4': gb partials, both operands bf16 -------------------------
__global__ __launch_bounds__(256) void k_mmG(
    const unsigned short* __restrict__ wAall, const unsigned short* __restrict__ gwall,
    float* __restrict__ partial)
{
    __shared__ __align__(16) unsigned At32[4096];
    __shared__ __align__(16) unsigned Bt32[4096];
    int t = threadIdx.x;
    int lane = t & 63;
    int wid = t >> 6;
    int ws = wid & 1, wc = wid >> 1;
    int blk = blockIdx.x;
    int b = blk / G_KB;
    int kb = blk % G_KB;
    int n0 = kb * G_CHUNK;
    const unsigned short* wA = wAall + (size_t)b * Nn * Sn;
    const unsigned short* Bsrc = gwall + (size_t)b * Nn * Sn;

    f32x4 acc[4][4];
    const f32x4 fz = {0.f, 0.f, 0.f, 0.f};
    #pragma unroll
    for (int i = 0; i < 4; i++) {
        #pragma unroll
        for (int j = 0; j < 4; j++) acc[i][j] = fz;
    }

    int l15 = lane & 15, lg = lane >> 4;

    for (int kt = 0; kt < G_CHUNK; kt += 64) {
        stage_pairtile(wA, Sn, 0, n0 + kt, Nn, At32, t);
        stage_pairtile(Bsrc, Sn, 0, n0 + kt, Nn, Bt32, t);
        __syncthreads();
        #pragma unroll
        for (int m = 0; m < 2; m++) {
            s16x8 af[4], bfr[4];
            #pragma unroll
            for (int i = 0; i < 4; i++) {
                int row = ws * 64 + i * 16 + l15;
                af[i] = *(const s16x8*)((const char*)At32 + lds_off(row, m * 32 + lg * 8));
            }
            #pragma unroll
            for (int j = 0; j < 4; j++) {
                int row = wc * 64 + j * 16 + l15;
                bfr[j] = *(const s16x8*)((const char*)Bt32 + lds_off(row, m * 32 + lg * 8));
            }
            #pragma unroll
            for (int i = 0; i < 4; i++) {
                #pragma unroll
                for (int j = 0; j < 4; j++)
                    acc[i][j] = __builtin_amdgcn_mfma_f32_16x16x32_bf16(
                        af[i], bfr[j], acc[i][j], 0, 0, 0);
            }
        }
        __syncthreads();
    }

    float* pp = partial + (size_t)blk * 16384;
    #pragma unroll
    for (int i = 0; i < 4; i++) {
        int srow = ws * 64 + i * 16 + lg * 4;
        #pragma unroll
        for (int j = 0; j < 4; j++) {
            int ccol = wc * 64 + j * 16 + l15;
            #pragma unroll
            for (int r = 0; r < 4; r++)
                pp[(size_t)(srow + r) * 128 + ccol] = acc[i][j][r];
        }
    }
}

// ---------------- reduce partials -> sl16 (with /wsum) -------------------------
__global__ __launch_bounds__(256) void k_reduceS(
    const float* __restrict__ partial, const float* __restrict__ wsum,
    unsigned short* __restrict__ sl16)
{
    int g = blockIdx.x * 256 + threadIdx.x;
    int c = g & 127;
    int s = (g >> 7) & 127;
    int cb = (g >> 14) & 3;
    int b = g >> 16;
    const float* pp = partial + (size_t)(b * 4 + cb) * S_KB * 16384 + (size_t)s * 128 + c;
    float sum = 0.f;
    #pragma unroll 7
    for (int kb = 0; kb < S_KB; kb++) sum += pp[(size_t)kb * 16384];
    sl16[((size_t)b * Sn + s) * Cn + cb * 128 + c] =
        f2bf(sum / fmaxf(wsum[b * Sn + s], EPSf));
}

// ---------------- reduce partials -> gb_raw ------------------------------------
__global__ __launch_bounds__(256) void k_reduceG(
    const float* __restrict__ partial, float* __restrict__ gb_raw)
{
    int g = blockIdx.x * 256 + threadIdx.x;
    int t2 = g & 127;
    int s = (g >> 7) & 127;
    int b = g >> 14;
    const float* pp = partial + (size_t)b * G_KB * 16384 + (size_t)s * 128 + t2;
    float sum = 0.f;
    #pragma unroll 8
    for (int kb = 0; kb < G_KB; kb++) sum += pp[(size_t)kb * 16384];
    gb_raw[(size_t)b * 16384 + (size_t)s * 128 + t2] = sum;
}

// ---------------- K4b: symmetrize, row-normalize, log --------------------------
__global__ __launch_bounds__(128) void k_gb_fin(
    const float* __restrict__ gb_raw, float* __restrict__ gb)
{
    int bid = blockIdx.x;
    int b = bid >> 7, i = bid & 127;
    int j = threadIdx.x;
    const float* gr = gb_raw + (size_t)b * Sn * Sn;
    float sym = 0.5f * (gr[i * Sn + j] + gr[j * Sn + i]);
    float sum = sym;
    #pragma unroll
    for (int d = 1; d < 64; d <<= 1) sum += __shfl_xor(sum, d);
    __shared__ float wred[2];
    if ((j & 63) == 0) wred[j >> 6] = sum;
    __syncthreads();
    sum = wred[0] + wred[1];
    float r = fmaxf(sum, EPSf);
    gb[(size_t)b * Sn * Sn + (size_t)i * Sn + j] = logf(fmaxf(sym / r, EPSf));
}

// ---------------- K5': q/k/v = sl16 @ WT[z] + bias, MFMA, fused ----------------
__global__ __launch_bounds__(256) void k_qkv(
    const unsigned short* __restrict__ sl16, const unsigned short* __restrict__ WT,
    const float* __restrict__ bq, const float* __restrict__ bk,
    const float* __restrict__ bv,
    float* __restrict__ q, float* __restrict__ kb, float* __restrict__ vb)
{
    __shared__ __align__(16) unsigned At32[4096];
    __shared__ __align__(16) unsigned Bt32[4096];
    int t = threadIdx.x;
    int lane = t & 63;
    int wid = t >> 6;
    int ws = wid & 1, wc = wid >> 1;
    int l15 = lane & 15, lg = lane >> 4;
    int rb = blockIdx.x, cb = blockIdx.y, sel = blockIdx.z;
    const unsigned short* Bmat = WT + (size_t)sel * Cn * Cn;
    const float* bias = (sel == 0) ? bq : (sel == 1) ? bk : bv;
    float* outp = (sel == 0) ? q : (sel == 1) ? kb : vb;

    f32x4 acc[4][4];
    const f32x4 fz = {0.f, 0.f, 0.f, 0.f};
    #pragma unroll
    for (int i = 0; i < 4; i++) {
        #pragma unroll
        for (int j = 0; j < 4; j++) acc[i][j] = fz;
    }

    for (int ks = 0; ks < 8; ks++) {
        stage_bf16tile(sl16 + (size_t)rb * 128 * Cn + ks * 64, Cn, 128, At32, t);
        stage_bf16tile(Bmat + (size_t)cb * 128 * Cn + ks * 64, Cn, 128, Bt32, t);
        __syncthreads();
        #pragma unroll
        for (int m = 0; m < 2; m++) {
            s16x8 af[4], bfr[4];
            #pragma unroll
            for (int i = 0; i < 4; i++)
                af[i] = *(const s16x8*)((const char*)At32 +
                        lds_off(ws * 64 + i * 16 + l15, m * 32 + lg * 8));
            #pragma unroll
            for (int j = 0; j < 4; j++)
                bfr[j] = *(const s16x8*)((const char*)Bt32 +
                        lds_off(wc * 64 + j * 16 + l15, m * 32 + lg * 8));
            #pragma unroll
            for (int i = 0; i < 4; i++) {
                #pragma unroll
                for (int j = 0; j < 4; j++)
                    acc[i][j] = __builtin_amdgcn_mfma_f32_16x16x32_bf16(
                        af[i], bfr[j], acc[i][j], 0, 0, 0);
            }
        }
        __syncthreads();
    }

    float bvv[4];
    #pragma unroll
    for (int j = 0; j < 4; j++) bvv[j] = bias[cb * 128 + wc * 64 + j * 16 + l15];
    #pragma unroll
    for (int i = 0; i < 4; i++) {
        #pragma unroll
        for (int r = 0; r < 4; r++) {
            int m = rb * 128 + ws * 64 + i * 16 + lg * 4 + r;
            #pragma unroll
            for (int j = 0; j < 4; j++)
                outp[(size_t)m * Cn + cb * 128 + wc * 64 + j * 16 + l15] =
                    acc[i][j][r] + bvv[j];
        }
    }
}

// ---------------- K6: attention per (b,h,i) -> bf16 out ------------------------
__global__ __launch_bounds__(128) void k_attn(
    const float* __restrict__ q, const float* __restrict__ k,
    const float* __restrict__ v, const float* __restrict__ gb,
    const float* __restrict__ beta_raw, unsigned short* __restrict__ attn16)
{
    __shared__ float kv[128][65];
    __shared__ float qv[64];
    __shared__ float p[128];
    __shared__ float wred[2][2];

    int t = threadIdx.x;
    int bid = blockIdx.x;
    int b = bid / (Hn * Sn);
    int h = (bid / Sn) % Hn;
    int i = bid % Sn;
    size_t base = (size_t)b * Sn * Cn + (size_t)h * Dn;

    if (t < 64) qv[t] = q[base + (size_t)i * Cn + t];
    for (int l = 0; l < 64; l++) {
        int idx = t + l * 128;
        int j = idx >> 6, d = idx & 63;
        kv[j][d] = k[base + (size_t)j * Cn + d];
    }
    __syncthreads();

    float dot = 0.f;
    #pragma unroll
    for (int d = 0; d < 64; d++) dot += qv[d] * kv[t][d];

    float beta = log1pf(__expf(beta_raw[0]));
    float logit = dot * 0.125f + beta * gb[(size_t)b * Sn * Sn + (size_t)i * Sn + t];

    float m = logit;
    #pragma unroll
    for (int d = 1; d < 64; d <<= 1) m = fmaxf(m, __shfl_xor(m, d));
    if ((t & 63) == 0) wred[0][t >> 6] = m;
    __syncthreads();
    m = fmaxf(wred[0][0], wred[0][1]);
    float e = __expf(logit - m);
    float sm = e;
    #pragma unroll
    for (int d = 1; d < 64; d <<= 1) sm += __shfl_xor(sm, d);
    if ((t & 63) == 0) wred[1][t >> 6] = sm;
    __syncthreads();
    sm = wred[1][0] + wred[1][1];
    p[t] = e / sm;
    __syncthreads();

    for (int l = 0; l < 64; l++) {
        int idx = t + l * 128;
        int j = idx >> 6, d = idx & 63;
        kv[j][d] = v[base + (size_t)j * Cn + d];
    }
    __syncthreads();

    if (t < 64) {
        float o = 0.f;
        #pragma unroll 8
        for (int j = 0; j < 128; j++) o += p[j] * kv[j][t];
        attn16[base + (size_t)i * Cn + t] = f2bf(o);
    }
}

// ---------------- K7': SoT[b][c][s] = (attn16 @ WoT + bo)^T bf16 ---------------
__global__ __launch_bounds__(256) void k_wo(
    const unsigned short* __restrict__ attn16, const unsigned short* __restrict__ WoT,
    const float* __restrict__ bo, unsigned short* __restrict__ SoT)
{
    __shared__ __align__(16) unsigned At32[4096];
    __shared__ __align__(16) unsigned Bt32[4096];
    int t = threadIdx.x;
    int lane = t & 63;
    int wid = t >> 6;
    int ws = wid & 1, wc = wid >> 1;
    int l15 = lane & 15, lg = lane >> 4;
    int b = blockIdx.x, cb = blockIdx.y;

    f32x4 acc[4][4];
    const f32x4 fz = {0.f, 0.f, 0.f, 0.f};
    #pragma unroll
    for (int i = 0; i < 4; i++) {
        #pragma unroll
        for (int j = 0; j < 4; j++) acc[i][j] = fz;
    }

    for (int ks = 0; ks < 8; ks++) {
        stage_bf16tile(attn16 + (size_t)b * 128 * Cn + ks * 64, Cn, 128, At32, t);
        stage_bf16tile(WoT + (size_t)cb * 128 * Cn + ks * 64, Cn, 128, Bt32, t);
        __syncthreads();
        #pragma unroll
        for (int m = 0; m < 2; m++) {
            s16x8 af[4], bfr[4];
            #pragma unroll
            for (int i = 0; i < 4; i++)
                af[i] = *(const s16x8*)((const char*)At32 +
                        lds_off(ws * 64 + i * 16 + l15, m * 32 + lg * 8));
            #pragma unroll
            for (int j = 0; j < 4; j++)
                bfr[j] = *(const s16x8*)((const char*)Bt32 +
                        lds_off(wc * 64 + j * 16 + l15, m * 32 + lg * 8));
            #pragma unroll
            for (int i = 0; i < 4; i++) {
                #pragma unroll
                for (int j = 0; j < 4; j++)
                    acc[i][j] = __builtin_amdgcn_mfma_f32_16x16x32_bf16(
                        af[i], bfr[j], acc[i][j], 0, 0, 0);
            }
        }
        __syncthreads();
    }

    float bvv[4];
    #pragma unroll
    for (int j = 0; j < 4; j++) bvv[j] = bo[cb * 128 + wc * 64 + j * 16 + l15];
    unsigned short* sb = SoT + (size_t)b * Cn * Sn;
    #pragma unroll
    for (int i = 0; i < 4; i++) {
        #pragma unroll
        for (int j = 0; j < 4; j++) {
            int c = cb * 128 + wc * 64 + j * 16 + l15;
            #pragma unroll
            for (int r = 0; r < 4; r++) {
                int s = ws * 64 + i * 16 + lg * 4 + r;
                sb[(size_t)c * Sn + s] = f2bf(acc[i][j][r] + bvv[j]);
            }
        }
    }
}

// ---------------- K8': out[n][c] = sum_s w[n,s]*so[s,c] via MFMA ---------------
__global__ __launch_bounds__(256) void k_out2(
    const unsigned short* __restrict__ wAll, const unsigned short* __restrict__ SoT,
    float* __restrict__ out)
{
    __shared__ __align__(16) unsigned At32[4096];
    __shared__ __align__(16) unsigned Bt32[4096];
    int t = threadIdx.x;
    int lane = t & 63;
    int wid = t >> 6;
    int ws = wid & 1, wc = wid >> 1;
    int l15 = lane & 15, lg = lane >> 4;
    int blk = blockIdx.x;
    int b = blk / (NB128 * 4);
    int rem = blk % (NB128 * 4);
    int rb = rem >> 2;
    int cb = rem & 3;
    int n0 = rb * 128, c0 = cb * 128;
    int nvalid = Nn - n0; if (nvalid > 128) nvalid = 128;
    const unsigned short* wb = wAll + (size_t)b * Nn * Sn;
    const unsigned short* sb = SoT + (size_t)b * Cn * Sn;

    f32x4 acc[4][4];
    const f32x4 fz = {0.f, 0.f, 0.f, 0.f};
    #pragma unroll
    for (int i = 0; i < 4; i++) {
        #pragma unroll
        for (int j = 0; j < 4; j++) acc[i][j] = fz;
    }

    #pragma unroll
    for (int ksi = 0; ksi < 2; ksi++) {
        stage_bf16tile(wb + (size_t)n0 * Sn + ksi * 64, Sn, nvalid, At32, t);
        stage_bf16tile(sb + (size_t)c0 * Sn + ksi * 64, Sn, 128, Bt32, t);
        __syncthreads();
        #pragma unroll
        for (int m = 0; m < 2; m++) {
            s16x8 af[4], bfr[4];
            #pragma unroll
            for (int i = 0; i < 4; i++)
                af[i] = *(const s16x8*)((const char*)At32 +
                        lds_off(ws * 64 + i * 16 + l15, m * 32 + lg * 8));
            #pragma unroll
            for (int j = 0; j < 4; j++)
                bfr[j] = *(const s16x8*)((const char*)Bt32 +
                        lds_off(wc * 64 + j * 16 + l15, m * 32 + lg * 8));
            #pragma unroll
            for (int i = 0; i < 4; i++) {
                #pragma unroll
                for (int j = 0; j < 4; j++)
                    acc[i][j] = __builtin_amdgcn_mfma_f32_16x16x32_bf16(
                        af[i], bfr[j], acc[i][j], 0, 0, 0);
            }
        }
        __syncthreads();
    }

    #pragma unroll
    for (int i = 0; i < 4; i++) {
        #pragma unroll
        for (int r = 0; r < 4; r++) {
            int n = n0 + ws * 64 + i * 16 + lg * 4 + r;
            if (n < Nn) {
                #pragma unroll
                for (int j = 0; j < 4; j++)
                    out[((size_t)b * Nn + n) * Cn + c0 + wc * 64 + j * 16 + l15] =
                        acc[i][j][r];
            }
        }
    }
}

extern "C" void kernel_launch(void* const* d_in, const int* in_sizes, int n_in,
                              void* d_out, int out_size, void* d_ws, size_t ws_size,
                              hipStream_t stream)
{
    const float* x  = (const float*)d_in[0];
    const int* adj  = (const int*)d_in[1];
    const float* av = (const float*)d_in[2];
    const float* Ws = (const float*)d_in[3];
    const float* bs = (const float*)d_in[4];
    const float* Wq = (const float*)d_in[5];
    const float* bq = (const float*)d_in[6];
    const float* Wk = (const float*)d_in[7];
    const float* bk = (const float*)d_in[8];
    const float* Wv = (const float*)d_in[9];
    const float* bv = (const float*)d_in[10];
    const float* Wo = (const float*)d_in[11];
    const float* bo = (const float*)d_in[12];
    const float* br = (const float*)d_in[13];
    float* out = (float*)d_out;
    (void)in_sizes; (void)n_in; (void)out_size; (void)ws_size;

    char* ws = (char*)d_ws;
    size_t off = 0;
    unsigned short* wb16  = (unsigned short*)(ws + off); off += (size_t)Bn * Nn * Sn * 2; // 10.24 MB
    unsigned short* gwb16 = (unsigned short*)(ws + off); off += (size_t)Bn * Nn * Sn * 2; // 10.24 MB
    unsigned short* sl16  = (unsigned short*)(ws + off); off += (size_t)Bn * Sn * Cn * 2; // 256 KB
    float* wsum       = (float*)(ws + off); off += 1024;
    float* gb_raw     = (float*)(ws + off); off += (size_t)Bn * Sn * Sn * 4;
    float* gb         = (float*)(ws + off); off += (size_t)Bn * Sn * Sn * 4;
    float* q          = (float*)(ws + off); off += (size_t)Bn * Sn * Cn * 4;
    float* kbuf       = (float*)(ws + off); off += (size_t)Bn * Sn * Cn * 4;
    float* vbuf       = (float*)(ws + off); off += (size_t)Bn * Sn * Cn * 4;
    unsigned short* attn16 = (unsigned short*)(ws + off); off += (size_t)Bn * Sn * Cn * 2;
    unsigned short* WsT = (unsigned short*)(ws + off); off += (size_t)Sn * Cn * 2;
    unsigned short* WT  = (unsigned short*)(ws + off); off += (size_t)4 * Cn * Cn * 2;   // 2 MB
    unsigned short* SoT = (unsigned short*)(ws + off); off += (size_t)Bn * Cn * Sn * 2;
    // Union region U: CSR buffers live [k_deg .. k_gather], then partialS
    // [k_mmS .. k_reduceS] (33.0 MB), then partialG [k_mmG .. k_reduceG] (20.6 MB).
    char* U = ws + off;
    int*  deg    = (int*)(U);
    int*  cursor = (int*)(U + 80128);
    int*  offs   = (int*)(U + 160256);
    int2* epack  = (int2*)(U + 240640);     // 2.56 MB
    float* partialS = (float*)U;            // 504 * 64 KB = 33.0 MB
    float* partialG = (float*)U;            // 314 * 64 KB = 20.6 MB

    hipMemsetAsync(wsum, 0, 1024, stream);
    hipMemsetAsync(U, 0, 160256, stream);   // deg + cursor

    k_prepW<<<dim3(16, 16, 5), 256, 0, stream>>>(Ws, Wq, Wk, Wv, Wo, WsT, WT);
    k_assign2<<<Bn * NB64, 256, 0, stream>>>(x, WsT, bs, wb16, wsum);

    // CSR build + gather (bf16 gw)
    k_deg<<<(En + 255) / 256, 256, 0, stream>>>(adj, deg);
    k_scan<<<1, 1024, 0, stream>>>(deg, offs);
    k_fill<<<(En + 255) / 256, 256, 0, stream>>>(adj, av, offs, cursor, epack);
    k_gather<<<Nn, 128, 0, stream>>>(wb16, epack, offs, gwb16);

    // slices(bf16) = wT @ x / wsum  (pipelined MFMA partials + reduce)
    k_mmS<<<Bn * 4 * S_KB, 256, 0, stream>>>(wb16, x, partialS);
    k_reduceS<<<(Bn * Sn * Cn) / 256, 256, 0, stream>>>(partialS, wsum, sl16);

    // gb_raw = wT @ gw (MFMA partials + reduce)
    k_mmG<<<Bn * G_KB, 256, 0, stream>>>(wb16, gwb16, partialG);
    k_reduceG<<<(Bn * Sn * Sn) / 256, 256, 0, stream>>>(partialG, gb_raw);
    k_gb_fin<<<Bn * Sn, 128, 0, stream>>>(gb_raw, gb);

    // q/k/v via fused MFMA GEMM, then attention, then Wo (writes SoT directly)
    k_qkv<<<dim3(2, 4, 3), 256, 0, stream>>>(sl16, WT, bq, bk, bv, q, kbuf, vbuf);
    k_attn<<<Bn * Hn * Sn, 128, 0, stream>>>(q, kbuf, vbuf, gb, br, attn16);
    k_wo<<<dim3(2, 4), 256, 0, stream>>>(attn16, WT + (size_t)3 * Cn * Cn, bo, SoT);

    k_out2<<<Bn * NB128 * 4, 256, 0, stream>>>(wb16, SoT, out);
}

// Round 10
// 248.366 us; speedup vs baseline: 4.3724x; 1.0217x over previous
//
#include <hip/hip_runtime.h>
#include <math.h>

#define Bn 2
#define Nn 20000
#define Cn 512
#define Sn 128
#define Hn 8
#define Dn 64
#define En 320000
#define EPSf 1e-6f
#define NB64 313   // ceil(20000/64)
#define NB128 157  // ceil(20000/128)

#define S_CHUNK 320
#define S_KB 63        // 63*320 = 20160 >= 20000
#define G_CHUNK 128
#define G_KB 157       // 157*128 = 20096 >= 20000

typedef __attribute__((ext_vector_type(4))) float f32x4;
typedef __attribute__((ext_vector_type(8))) short s16x8;

__device__ __forceinline__ unsigned short f2bf(float f) {
    unsigned u = __float_as_uint(f);
    return (unsigned short)((u + 0x7fffu + ((u >> 16) & 1u)) >> 16);
}
__device__ __forceinline__ float bf2f(unsigned short h) {
    return __uint_as_float(((unsigned)h) << 16);
}

// Swizzled LDS byte offset for a [rows][64 k] bf16 tile (rows<=128).
// Frag reads (16B, k mult of 8): 2-way bank aliasing (free per m136).
__device__ __forceinline__ unsigned lds_off(int row, int n) {
    unsigned ch = ((((unsigned)n >> 3) ^ ((unsigned)row & 7u) ^ (((unsigned)row >> 3) & 7u)) & 7u);
    return (unsigned)row * 128u + ch * 16u + ((unsigned)n & 7u) * 2u;
}

// ---- stage [128 rows][64 k] bf16 tile from bf16 row-major source (row=out dim)
__device__ __forceinline__ void stage_bf16tile(
    const unsigned short* __restrict__ src, int stride, int nvalid, unsigned* dst, int t)
{
    #pragma unroll
    for (int l = 0; l < 2; l++) {
        int task = t + l * 256;
        int row = task >> 2, seg = task & 3;
        s16x8 a = {0,0,0,0,0,0,0,0}, b = {0,0,0,0,0,0,0,0};
        if (row < nvalid) {
            a = *(const s16x8*)(src + (size_t)row * stride + seg * 16);
            b = *(const s16x8*)(src + (size_t)row * stride + seg * 16 + 8);
        }
        *(s16x8*)((char*)dst + lds_off(row, seg * 16)) = a;
        *(s16x8*)((char*)dst + lds_off(row, seg * 16 + 8)) = b;
    }
}

// ---- stage transpose-pack: [out:128][k(n):64] tile from [n][out] bf16 source --
__device__ __forceinline__ void stage_pairtile(
    const unsigned short* __restrict__ src, int stride, int c0,
    int nbase, int nlimit, unsigned* dst, int t)
{
    int c = t & 15;
    int p0 = t >> 4;
    #pragma unroll
    for (int half = 0; half < 2; half++) {
        int pp = p0 + half * 16;
        int nl = 2 * pp;
        int ng = nbase + nl;
        s16x8 a0 = {0,0,0,0,0,0,0,0}, a1 = {0,0,0,0,0,0,0,0};
        if (ng < nlimit)     a0 = *(const s16x8*)(src + (size_t)ng * stride + c0 + 8 * c);
        if (ng + 1 < nlimit) a1 = *(const s16x8*)(src + (size_t)(ng + 1) * stride + c0 + 8 * c);
        #pragma unroll
        for (int i = 0; i < 8; i++) {
            unsigned val = ((unsigned)(unsigned short)a0[i]) |
                           (((unsigned)(unsigned short)a1[i]) << 16);
            dst[lds_off(8 * c + i, nl) >> 2] = val;
        }
    }
}

// ---------------- prep: weight transposes + workspace zeroing ------------------
// z=0,y<4: WsT <- Ws^T; z=0,y>=4: zero deg/cursor/wsum (replaces 47us rocclr
// fillBufferAligned in the captured graph!); z=1..4: WT[z-1] <- W^T.
__global__ __launch_bounds__(256) void k_prepW(
    const float* __restrict__ Ws, const float* __restrict__ Wq,
    const float* __restrict__ Wk, const float* __restrict__ Wv,
    const float* __restrict__ Wo, unsigned short* __restrict__ WsT,
    unsigned short* __restrict__ WT, int* __restrict__ zeroU,
    float* __restrict__ wsum)
{
    __shared__ float tile[32][33];
    int t = threadIdx.x;
    int z = blockIdx.z;
    int k0 = blockIdx.x * 32;
    int c0 = blockIdx.y * 32;
    const float* W;
    unsigned short* dst;
    int ncols;
    if (z == 0) {
        if (c0 >= Sn) {
            // zeroing duty: blocks (y=4..15, x=0..15) -> 192 blocks x 256 thr
            int idx = (((int)blockIdx.y - 4) * 16 + (int)blockIdx.x) * 256 + t;
            if (idx < 40064) zeroU[idx] = 0;                 // deg + cursor
            else if (idx < 40064 + Bn * Sn) wsum[idx - 40064] = 0.f;
            return;
        }
        W = Ws; dst = WsT; ncols = Sn;
    } else {
        W = (z == 1) ? Wq : (z == 2) ? Wk : (z == 3) ? Wv : Wo;
        dst = WT + (size_t)(z - 1) * Cn * Cn; ncols = Cn;
    }
    #pragma unroll
    for (int l = 0; l < 4; l++) {
        int idx = t + l * 256;
        int r = idx >> 5, c = idx & 31;
        tile[r][c] = W[(size_t)(k0 + r) * ncols + c0 + c];
    }
    __syncthreads();
    #pragma unroll
    for (int l = 0; l < 4; l++) {
        int idx = t + l * 256;
        int r = idx >> 5, c = idx & 31;
        dst[(size_t)(c0 + r) * Cn + k0 + c] = f2bf(tile[c][r]);
    }
}

// ---------------- K1''': weights = softmax(x @ Ws + bs), pipelined -------------
__global__ __launch_bounds__(256) void k_assign2(
    const float* __restrict__ x, const unsigned short* __restrict__ WsT,
    const float* __restrict__ bs, unsigned short* __restrict__ weights,
    float* __restrict__ wsum)
{
    __shared__ __align__(16) unsigned At32[2][2048];   // 2 x 8 KB (64 rows)
    __shared__ __align__(16) unsigned Bt32[2][4096];   // 2 x 16 KB (128 s)
    __shared__ float wsum_loc[128];

    int t = threadIdx.x;
    int lane = t & 63;
    int wid = t >> 6;
    int l15 = lane & 15, lg = lane >> 4;
    int blk = blockIdx.x;
    int b = blk / NB64;
    int rb = blk % NB64;
    int n0 = rb * 64;
    int nvalid = Nn - n0; if (nvalid > 64) nvalid = 64;
    const float* xb = x + (size_t)b * Nn * Cn;

    if (t < 128) wsum_loc[t] = 0.f;

    int arow = t >> 2, aseg = t & 3;
    bool aok = (arow < nvalid);
    const float4* aptr = (const float4*)(xb + (size_t)(n0 + arow) * Cn) + aseg * 4;
    int brow = t >> 2, bseg = t & 3;
    const unsigned short* bp0 = WsT + (size_t)brow * Cn + bseg * 16;
    const unsigned short* bp1 = WsT + (size_t)(brow + 64) * Cn + bseg * 16;

    const f32x4 fz = {0.f, 0.f, 0.f, 0.f};
    f32x4 acc[8];
    #pragma unroll
    for (int j = 0; j < 8; j++) acc[j] = fz;

    float4 ra[4];
    #pragma unroll
    for (int i = 0; i < 4; i++) ra[i] = make_float4(0.f, 0.f, 0.f, 0.f);
    s16x8 rb0a, rb0b, rb1a, rb1b;

    if (aok) { ra[0] = aptr[0]; ra[1] = aptr[1]; ra[2] = aptr[2]; ra[3] = aptr[3]; }
    rb0a = *(const s16x8*)(bp0);     rb0b = *(const s16x8*)(bp0 + 8);
    rb1a = *(const s16x8*)(bp1);     rb1b = *(const s16x8*)(bp1 + 8);

    int cur = 0;
    for (int ks = 0; ks < 8; ks++) {
        {
            float v[16] = {ra[0].x, ra[0].y, ra[0].z, ra[0].w,
                           ra[1].x, ra[1].y, ra[1].z, ra[1].w,
                           ra[2].x, ra[2].y, ra[2].z, ra[2].w,
                           ra[3].x, ra[3].y, ra[3].z, ra[3].w};
            #pragma unroll
            for (int h = 0; h < 2; h++) {
                uint4 u;
                u.x = (unsigned)f2bf(v[h*8+0]) | (((unsigned)f2bf(v[h*8+1])) << 16);
                u.y = (unsigned)f2bf(v[h*8+2]) | (((unsigned)f2bf(v[h*8+3])) << 16);
                u.z = (unsigned)f2bf(v[h*8+4]) | (((unsigned)f2bf(v[h*8+5])) << 16);
                u.w = (unsigned)f2bf(v[h*8+6]) | (((unsigned)f2bf(v[h*8+7])) << 16);
                *(uint4*)((char*)At32[cur] + lds_off(arow, aseg * 16 + h * 8)) = u;
            }
            *(s16x8*)((char*)Bt32[cur] + lds_off(brow, bseg * 16)) = rb0a;
            *(s16x8*)((char*)Bt32[cur] + lds_off(brow, bseg * 16 + 8)) = rb0b;
            *(s16x8*)((char*)Bt32[cur] + lds_off(brow + 64, bseg * 16)) = rb1a;
            *(s16x8*)((char*)Bt32[cur] + lds_off(brow + 64, bseg * 16 + 8)) = rb1b;
        }
        if (ks < 7) {
            int kn = ks + 1;
            if (aok) {
                ra[0] = aptr[kn*16]; ra[1] = aptr[kn*16+1];
                ra[2] = aptr[kn*16+2]; ra[3] = aptr[kn*16+3];
            }
            rb0a = *(const s16x8*)(bp0 + kn*64); rb0b = *(const s16x8*)(bp0 + kn*64 + 8);
            rb1a = *(const s16x8*)(bp1 + kn*64); rb1b = *(const s16x8*)(bp1 + kn*64 + 8);
        }
        __syncthreads();
        #pragma unroll
        for (int m = 0; m < 2; m++) {
            s16x8 af = *(const s16x8*)((const char*)At32[cur] +
                       lds_off(wid * 16 + l15, m * 32 + lg * 8));
            #pragma unroll
            for (int j = 0; j < 8; j++) {
                s16x8 bf = *(const s16x8*)((const char*)Bt32[cur] +
                           lds_off(j * 16 + l15, m * 32 + lg * 8));
                acc[j] = __builtin_amdgcn_mfma_f32_16x16x32_bf16(af, bf, acc[j], 0, 0, 0);
            }
        }
        __syncthreads();
        cur ^= 1;
    }

    float bsv[8];
    #pragma unroll
    for (int j = 0; j < 8; j++) bsv[j] = bs[j * 16 + l15];

    unsigned short* wb = weights + (size_t)b * Nn * Sn;
    unsigned short* wt = (unsigned short*)&At32[0][0];   // 16 KB = 64 x 128 bf16
    float wacc[8] = {0.f,0.f,0.f,0.f,0.f,0.f,0.f,0.f};
    #pragma unroll
    for (int r = 0; r < 4; r++) {
        float lv[8];
        #pragma unroll
        for (int j = 0; j < 8; j++) lv[j] = acc[j][r] + bsv[j];
        float m = lv[0];
        #pragma unroll
        for (int j = 1; j < 8; j++) m = fmaxf(m, lv[j]);
        m = fmaxf(m, __shfl_xor(m, 1));
        m = fmaxf(m, __shfl_xor(m, 2));
        m = fmaxf(m, __shfl_xor(m, 4));
        m = fmaxf(m, __shfl_xor(m, 8));
        float e[8], sm = 0.f;
        #pragma unroll
        for (int j = 0; j < 8; j++) { e[j] = __expf(lv[j] - m); sm += e[j]; }
        sm += __shfl_xor(sm, 1);
        sm += __shfl_xor(sm, 2);
        sm += __shfl_xor(sm, 4);
        sm += __shfl_xor(sm, 8);
        float inv = 1.f / sm;
        int rloc = wid * 16 + lg * 4 + r;
        bool valid = (n0 + rloc < Nn);
        #pragma unroll
        for (int j = 0; j < 8; j++) {
            float w = e[j] * inv;
            wt[rloc * 128 + j * 16 + l15] = f2bf(w);
            if (valid) wacc[j] += w;
        }
    }
    #pragma unroll
    for (int j = 0; j < 8; j++) {
        wacc[j] += __shfl_xor(wacc[j], 16);
        wacc[j] += __shfl_xor(wacc[j], 32);
    }
    if (lg == 0) {
        #pragma unroll
        for (int j = 0; j < 8; j++) atomicAdd(&wsum_loc[j * 16 + l15], wacc[j]);
    }
    __syncthreads();
    // coalesced writeout: 32 bf16 (4 x 16B) per thread
    {
        int orow = t >> 2, oseg = t & 3;
        if (orow < nvalid) {
            uint4* dst = (uint4*)(wb + (size_t)(n0 + orow) * Sn + oseg * 32);
            const uint4* src = (const uint4*)(wt + (size_t)orow * 128 + oseg * 32);
            dst[0] = src[0]; dst[1] = src[1]; dst[2] = src[2]; dst[3] = src[3];
        }
    }
    if (t < 128) atomicAdd(&wsum[b * Sn + t], wsum_loc[t]);
}

// ---------------- CSR build: degree histogram ----------------------------------
__global__ __launch_bounds__(256) void k_deg(
    const int* __restrict__ adj, int* __restrict__ deg)
{
    int e = blockIdx.x * 256 + threadIdx.x;
    if (e < En) atomicAdd(&deg[adj[e]], 1);
}

// ---------------- CSR build: single-block wave-shuffle prefix scan -------------
__global__ __launch_bounds__(1024) void k_scan(
    const int* __restrict__ deg, int* __restrict__ offs)
{
    __shared__ int wsums[16];
    __shared__ int excl[16];
    __shared__ int runsS;
    __shared__ int totS;
    int t = threadIdx.x;
    int lane = t & 63;
    int w = t >> 6;
    if (t == 0) { offs[0] = 0; runsS = 0; }
    __syncthreads();
    for (int base = 0; base < Nn; base += 1024) {
        int v = (base + t < Nn) ? deg[base + t] : 0;
        int sv = v;
        #pragma unroll
        for (int d = 1; d < 64; d <<= 1) {
            int u = __shfl_up(sv, d);
            if (lane >= d) sv += u;
        }
        if (lane == 63) wsums[w] = sv;
        __syncthreads();
        if (t < 16) {
            int xv = wsums[t];
            int sw = xv;
            #pragma unroll
            for (int d = 1; d < 16; d <<= 1) {
                int u = __shfl_up(sw, d);
                if (t >= d) sw += u;
            }
            excl[t] = sw - xv;
            if (t == 15) totS = sw;
        }
        __syncthreads();
        if (base + t < Nn) offs[base + t + 1] = runsS + excl[w] + sv;
        __syncthreads();
        if (t == 0) runsS += totS;
        __syncthreads();
    }
}

// ---------------- CSR build: fill packed (col, val) edge records ---------------
__global__ __launch_bounds__(256) void k_fill(
    const int* __restrict__ adj, const float* __restrict__ vals,
    const int* __restrict__ offs, int* __restrict__ cursor,
    int2* __restrict__ epack)
{
    int e = blockIdx.x * 256 + threadIdx.x;
    if (e < En) {
        int r = adj[e];
        int p = atomicAdd(&cursor[r], 1);
        epack[offs[r] + p] = make_int2(adj[En + e], __float_as_int(vals[e]));
    }
}

// ---------------- K3': gw[b,r,:] = sum_{edges} v * w[b,col,:] -> bf16 ----------
__global__ __launch_bounds__(128) void k_gather(
    const unsigned short* __restrict__ weights, const int2* __restrict__ epack,
    const int* __restrict__ offs, unsigned short* __restrict__ gwb)
{
    int r = blockIdx.x;
    int s = threadIdx.x;
    int o0 = offs[r], o1 = offs[r + 1];
    const unsigned short* w0 = weights;
    const unsigned short* w1 = weights + (size_t)Nn * Sn;
    float a0 = 0.f, a1 = 0.f;
    int j = o0;
    for (; j + 4 <= o1; j += 4) {
        int2 e0 = epack[j], e1 = epack[j + 1], e2 = epack[j + 2], e3 = epack[j + 3];
        float v0 = __int_as_float(e0.y), v1 = __int_as_float(e1.y);
        float v2 = __int_as_float(e2.y), v3 = __int_as_float(e3.y);
        float p00 = bf2f(w0[(size_t)e0.x * Sn + s]);
        float p01 = bf2f(w1[(size_t)e0.x * Sn + s]);
        float p10 = bf2f(w0[(size_t)e1.x * Sn + s]);
        float p11 = bf2f(w1[(size_t)e1.x * Sn + s]);
        float p20 = bf2f(w0[(size_t)e2.x * Sn + s]);
        float p21 = bf2f(w1[(size_t)e2.x * Sn + s]);
        float p30 = bf2f(w0[(size_t)e3.x * Sn + s]);
        float p31 = bf2f(w1[(size_t)e3.x * Sn + s]);
        a0 += v0 * p00 + v1 * p10 + v2 * p20 + v3 * p30;
        a1 += v0 * p01 + v1 * p11 + v2 * p21 + v3 * p31;
    }
    for (; j < o1; j++) {
        int2 e = epack[j];
        float v = __int_as_float(e.y);
        a0 += v * bf2f(w0[(size_t)e.x * Sn + s]);
        a1 += v * bf2f(w1[(size_t)e.x * Sn + s]);
    }
    gwb[(size_t)r * Sn + s] = f2bf(a0);
    gwb[(size_t)Nn * Sn + (size_t)r * Sn + s] = f2bf(a1);
}

// ---------------- K2'': slices partials, pipelined (T14) -----------------------
__global__ __launch_bounds__(256) void k_mmS(
    const unsigned short* __restrict__ wAall, const float* __restrict__ xall,
    float* __restrict__ partial)
{
    __shared__ __align__(16) unsigned At32[2][4096];
    __shared__ __align__(16) unsigned Bt32[2][4096];
    int t = threadIdx.x;
    int lane = t & 63;
    int wid = t >> 6;
    int ws = wid & 1, wc = wid >> 1;
    int blk = blockIdx.x;
    int b = blk / (4 * S_KB);
    int rem = blk % (4 * S_KB);
    int cb = rem / S_KB;
    int kb = rem % S_KB;
    int n0 = kb * S_CHUNK;
    int c0 = cb * 128;
    const unsigned short* wA = wAall + (size_t)b * Nn * Sn;
    const float* Bsrc = xall + (size_t)b * Nn * Cn;

    f32x4 acc[4][4];
    const f32x4 fz = {0.f, 0.f, 0.f, 0.f};
    #pragma unroll
    for (int i = 0; i < 4; i++) {
        #pragma unroll
        for (int j = 0; j < 4; j++) acc[i][j] = fz;
    }

    int l15 = lane & 15, lg = lane >> 4;
    int c = t & 15;
    int p0 = t >> 4;

    s16x8 pa[2][2];
    float4 pb[2][4];
    const s16x8 z8 = {0,0,0,0,0,0,0,0};

    auto LOADS = [&](int kt) {
        #pragma unroll
        for (int h = 0; h < 2; h++) {
            int nl = 2 * (p0 + h * 16);
            int ng = n0 + kt + nl;
            pa[h][0] = z8; pa[h][1] = z8;
            pb[h][0] = make_float4(0.f,0.f,0.f,0.f); pb[h][1] = pb[h][0];
            pb[h][2] = pb[h][0]; pb[h][3] = pb[h][0];
            if (ng < Nn) {
                pa[h][0] = *(const s16x8*)(wA + (size_t)ng * Sn + 8 * c);
                pb[h][0] = *(const float4*)(Bsrc + (size_t)ng * Cn + c0 + 8 * c);
                pb[h][1] = *(const float4*)(Bsrc + (size_t)ng * Cn + c0 + 8 * c + 4);
            }
            if (ng + 1 < Nn) {
                pa[h][1] = *(const s16x8*)(wA + (size_t)(ng + 1) * Sn + 8 * c);
                pb[h][2] = *(const float4*)(Bsrc + (size_t)(ng + 1) * Cn + c0 + 8 * c);
                pb[h][3] = *(const float4*)(Bsrc + (size_t)(ng + 1) * Cn + c0 + 8 * c + 4);
            }
        }
    };
    auto STORE = [&](int buf) {
        #pragma unroll
        for (int h = 0; h < 2; h++) {
            int nl = 2 * (p0 + h * 16);
            #pragma unroll
            for (int i = 0; i < 8; i++) {
                unsigned val = ((unsigned)(unsigned short)pa[h][0][i]) |
                               (((unsigned)(unsigned short)pa[h][1][i]) << 16);
                At32[buf][lds_off(8 * c + i, nl) >> 2] = val;
            }
            float b0[8] = {pb[h][0].x, pb[h][0].y, pb[h][0].z, pb[h][0].w,
                           pb[h][1].x, pb[h][1].y, pb[h][1].z, pb[h][1].w};
            float b1[8] = {pb[h][2].x, pb[h][2].y, pb[h][2].z, pb[h][2].w,
                           pb[h][3].x, pb[h][3].y, pb[h][3].z, pb[h][3].w};
            #pragma unroll
            for (int i = 0; i < 8; i++) {
                unsigned val = (unsigned)f2bf(b0[i]) | (((unsigned)f2bf(b1[i])) << 16);
                Bt32[buf][lds_off(8 * c + i, nl) >> 2] = val;
            }
        }
    };

    LOADS(0);
    int cur = 0;
    for (int it = 0; it < 5; it++) {     // S_CHUNK/64
        STORE(cur);
        if (it < 4) LOADS((it + 1) * 64);
        __syncthreads();
        #pragma unroll
        for (int m = 0; m < 2; m++) {
            s16x8 af[4], bfr[4];
            #pragma unroll
            for (int i = 0; i < 4; i++) {
                int row = ws * 64 + i * 16 + l15;
                af[i] = *(const s16x8*)((const char*)At32[cur] + lds_off(row, m * 32 + lg * 8));
            }
            #pragma unroll
            for (int j = 0; j < 4; j++) {
                int row = wc * 64 + j * 16 + l15;
                bfr[j] = *(const s16x8*)((const char*)Bt32[cur] + lds_off(row, m * 32 + lg * 8));
            }
            #pragma unroll
            for (int i = 0; i < 4; i++) {
                #pragma unroll
                for (int j = 0; j < 4; j++)
                    acc[i][j] = __builtin_amdgcn_mfma_f32_16x16x32_bf16(
                        af[i], bfr[j], acc[i][j], 0, 0, 0);
            }
        }
        __syncthreads();
        cur ^= 1;
    }

    float* pp = partial + (size_t)blk * 16384;
    #pragma unroll
    for (int i = 0; i < 4; i++) {
        int srow = ws * 64 + i * 16 + lg * 4;
        #pragma unroll
        for (int j = 0; j < 4; j++) {
            int ccol = wc * 64 + j * 16 + l15;
            #pragma unroll
            for (int r = 0; r < 4; r++)
                pp[(size_t)(srow + r) * 128 + ccol] = acc[i][j][r];
        }
    }
}

// ---------------- K4': gb partials, both operands bf16 -------------------------
__global__ __launch_bounds__(256) void k_mmG(
    const unsigned short* __restrict__ wAall, const unsigned short* __restrict__ gwall,
    float* __restrict__ partial)
{
    __shared__ __align__(16) unsigned At32[4096];
    __shared__ __align__(16) unsigned Bt32[4096];
    int t = threadIdx.x;
    int lane = t & 63;
    int wid = t >> 6;
    int ws = wid & 1, wc = wid >> 1;
    int blk = blockIdx.x;
    int b = blk / G_KB;
    int kb = blk % G_KB;
    int n0 = kb * G_CHUNK;
    const unsigned short* wA = wAall + (size_t)b * Nn * Sn;
    const unsigned short* Bsrc = gwall + (size_t)b * Nn * Sn;

    f32x4 acc[4][4];
    const f32x4 fz = {0.f, 0.f, 0.f, 0.f};
    #pragma unroll
    for (int i = 0; i < 4; i++) {
        #pragma unroll
        for (int j = 0; j < 4; j++) acc[i][j] = fz;
    }

    int l15 = lane & 15, lg = lane >> 4;

    for (int kt = 0; kt < G_CHUNK; kt += 64) {
        stage_pairtile(wA, Sn, 0, n0 + kt, Nn, At32, t);
        stage_pairtile(Bsrc, Sn, 0, n0 + kt, Nn, Bt32, t);
        __syncthreads();
        #pragma unroll
        for (int m = 0; m < 2; m++) {
            s16x8 af[4], bfr[4];
            #pragma unroll
            for (int i = 0; i < 4; i++) {
                int row = ws * 64 + i * 16 + l15;
                af[i] = *(const s16x8*)((const char*)At32 + lds_off(row, m * 32 + lg * 8));
            }
            #pragma unroll
            for (int j = 0; j < 4; j++) {
                int row = wc * 64 + j * 16 + l15;
                bfr[j] = *(const s16x8*)((const char*)Bt32 + lds_off(row, m * 32 + lg * 8));
            }
            #pragma unroll
            for (int i = 0; i < 4; i++) {
                #pragma unroll
                for (int j = 0; j < 4; j++)
                    acc[i][j] = __builtin_amdgcn_mfma_f32_16x16x32_bf16(
                        af[i], bfr[j], acc[i][j], 0, 0, 0);
            }
        }
        __syncthreads();
    }

    float* pp = partial + (size_t)blk * 16384;
    #pragma unroll
    for (int i = 0; i < 4; i++) {
        int srow = ws * 64 + i * 16 + lg * 4;
        #pragma unroll
        for (int j = 0; j < 4; j++) {
            int ccol = wc * 64 + j * 16 + l15;
            #pragma unroll
            for (int r = 0; r < 4; r++)
                pp[(size_t)(srow + r) * 128 + ccol] = acc[i][j][r];
        }
    }
}

// ---------------- reduce partials -> sl16 (with /wsum) -------------------------
__global__ __launch_bounds__(256) void k_reduceS(
    const float* __restrict__ partial, const float* __restrict__ wsum,
    unsigned short* __restrict__ sl16)
{
    int g = blockIdx.x * 256 + threadIdx.x;
    int c = g & 127;
    int s = (g >> 7) & 127;
    int cb = (g >> 14) & 3;
    int b = g >> 16;
    const float* pp = partial + (size_t)(b * 4 + cb) * S_KB * 16384 + (size_t)s * 128 + c;
    float sum = 0.f;
    #pragma unroll 7
    for (int kb = 0; kb < S_KB; kb++) sum += pp[(size_t)kb * 16384];
    sl16[((size_t)b * Sn + s) * Cn + cb * 128 + c] =
        f2bf(sum / fmaxf(wsum[b * Sn + s], EPSf));
}

// ---------------- reduce partials -> gb_raw ------------------------------------
__global__ __launch_bounds__(256) void k_reduceG(
    const float* __restrict__ partial, float* __restrict__ gb_raw)
{
    int g = blockIdx.x * 256 + threadIdx.x;
    int t2 = g & 127;
    int s = (g >> 7) & 127;
    int b = g >> 14;
    const float* pp = partial + (size_t)b * G_KB * 16384 + (size_t)s * 128 + t2;
    float sum = 0.f;
    #pragma unroll 8
    for (int kb = 0; kb < G_KB; kb++) sum += pp[(size_t)kb * 16384];
    gb_raw[(size_t)b * 16384 + (size_t)s * 128 + t2] = sum;
}

// ---------------- K4b: symmetrize, row-normalize, log --------------------------
__global__ __launch_bounds__(128) void k_gb_fin(
    const float* __restrict__ gb_raw, float* __restrict__ gb)
{
    int bid = blockIdx.x;
    int b = bid >> 7, i = bid & 127;
    int j = threadIdx.x;
    const float* gr = gb_raw + (size_t)b * Sn * Sn;
    float sym = 0.5f * (gr[i * Sn + j] + gr[j * Sn + i]);
    float sum = sym;
    #pragma unroll
    for (int d = 1; d < 64; d <<= 1) sum += __shfl_xor(sum, d);
    __shared__ float wred[2];
    if ((j & 63) == 0) wred[j >> 6] = sum;
    __syncthreads();
    sum = wred[0] + wred[1];
    float r = fmaxf(sum, EPSf);
    gb[(size_t)b * Sn * Sn + (size_t)i * Sn + j] = logf(fmaxf(sym / r, EPSf));
}

// ---------------- K5': q/k/v = sl16 @ WT[z] + bias, MFMA, fused ----------------
__global__ __launch_bounds__(256) void k_qkv(
    const unsigned short* __restrict__ sl16, const unsigned short* __restrict__ WT,
    const float* __restrict__ bq, const float* __restrict__ bk,
    const float* __restrict__ bv,
    float* __restrict__ q, float* __restrict__ kb, float* __restrict__ vb)
{
    __shared__ __align__(16) unsigned At32[4096];
    __shared__ __align__(16) unsigned Bt32[4096];
    int t = threadIdx.x;
    int lane = t & 63;
    int wid = t >> 6;
    int ws = wid & 1, wc = wid >> 1;
    int l15 = lane & 15, lg = lane >> 4;
    int rb = blockIdx.x, cb = blockIdx.y, sel = blockIdx.z;
    const unsigned short* Bmat = WT + (size_t)sel * Cn * Cn;
    const float* bias = (sel == 0) ? bq : (sel == 1) ? bk : bv;
    float* outp = (sel == 0) ? q : (sel == 1) ? kb : vb;

    f32x4 acc[4][4];
    const f32x4 fz = {0.f, 0.f, 0.f, 0.f};
    #pragma unroll
    for (int i = 0; i < 4; i++) {
        #pragma unroll
        for (int j = 0; j < 4; j++) acc[i][j] = fz;
    }

    for (int ks = 0; ks < 8; ks++) {
        stage_bf16tile(sl16 + (size_t)rb * 128 * Cn + ks * 64, Cn, 128, At32, t);
        stage_bf16tile(Bmat + (size_t)cb * 128 * Cn + ks * 64, Cn, 128, Bt32, t);
        __syncthreads();
        #pragma unroll
        for (int m = 0; m < 2; m++) {
            s16x8 af[4], bfr[4];
            #pragma unroll
            for (int i = 0; i < 4; i++)
                af[i] = *(const s16x8*)((const char*)At32 +
                        lds_off(ws * 64 + i * 16 + l15, m * 32 + lg * 8));
            #pragma unroll
            for (int j = 0; j < 4; j++)
                bfr[j] = *(const s16x8*)((const char*)Bt32 +
                        lds_off(wc * 64 + j * 16 + l15, m * 32 + lg * 8));
            #pragma unroll
            for (int i = 0; i < 4; i++) {
                #pragma unroll
                for (int j = 0; j < 4; j++)
                    acc[i][j] = __builtin_amdgcn_mfma_f32_16x16x32_bf16(
                        af[i], bfr[j], acc[i][j], 0, 0, 0);
            }
        }
        __syncthreads();
    }

    float bvv[4];
    #pragma unroll
    for (int j = 0; j < 4; j++) bvv[j] = bias[cb * 128 + wc * 64 + j * 16 + l15];
    #pragma unroll
    for (int i = 0; i < 4; i++) {
        #pragma unroll
        for (int r = 0; r < 4; r++) {
            int m = rb * 128 + ws * 64 + i * 16 + lg * 4 + r;
            #pragma unroll
            for (int j = 0; j < 4; j++)
                outp[(size_t)m * Cn + cb * 128 + wc * 64 + j * 16 + l15] =
                    acc[i][j][r] + bvv[j];
        }
    }
}

// ---------------- K6: attention per (b,h,i) -> bf16 out ------------------------
__global__ __launch_bounds__(128) void k_attn(
    const float* __restrict__ q, const float* __restrict__ k,
    const float* __restrict__ v, const float* __restrict__ gb,
    const float* __restrict__ beta_raw, unsigned short* __restrict__ attn16)
{
    __shared__ float kv[128][65];
    __shared__ float qv[64];
    __shared__ float p[128];
    __shared__ float wred[2][2];

    int t = threadIdx.x;
    int bid = blockIdx.x;
    int b = bid / (Hn * Sn);
    int h = (bid / Sn) % Hn;
    int i = bid % Sn;
    size_t base = (size_t)b * Sn * Cn + (size_t)h * Dn;

    if (t < 64) qv[t] = q[base + (size_t)i * Cn + t];
    for (int l = 0; l < 64; l++) {
        int idx = t + l * 128;
        int j = idx >> 6, d = idx & 63;
        kv[j][d] = k[base + (size_t)j * Cn + d];
    }
    __syncthreads();

    float dot = 0.f;
    #pragma unroll
    for (int d = 0; d < 64; d++) dot += qv[d] * kv[t][d];

    float beta = log1pf(__expf(beta_raw[0]));
    float logit = dot * 0.125f + beta * gb[(size_t)b * Sn * Sn + (size_t)i * Sn + t];

    float m = logit;
    #pragma unroll
    for (int d = 1; d < 64; d <<= 1) m = fmaxf(m, __shfl_xor(m, d));
    if ((t & 63) == 0) wred[0][t >> 6] = m;
    __syncthreads();
    m = fmaxf(wred[0][0], wred[0][1]);
    float e = __expf(logit - m);
    float sm = e;
    #pragma unroll
    for (int d = 1; d < 64; d <<= 1) sm += __shfl_xor(sm, d);
    if ((t & 63) == 0) wred[1][t >> 6] = sm;
    __syncthreads();
    sm = wred[1][0] + wred[1][1];
    p[t] = e / sm;
    __syncthreads();

    for (int l = 0; l < 64; l++) {
        int idx = t + l * 128;
        int j = idx >> 6, d = idx & 63;
        kv[j][d] = v[base + (size_t)j * Cn + d];
    }
    __syncthreads();

    if (t < 64) {
        float o = 0.f;
        #pragma unroll 8
        for (int j = 0; j < 128; j++) o += p[j] * kv[j][t];
        attn16[base + (size_t)i * Cn + t] = f2bf(o);
    }
}

// ---------------- K7': SoT[b][c][s] = (attn16 @ WoT + bo)^T bf16 ---------------
__global__ __launch_bounds__(256) void k_wo(
    const unsigned short* __restrict__ attn16, const unsigned short* __restrict__ WoT,
    const float* __restrict__ bo, unsigned short* __restrict__ SoT)
{
    __shared__ __align__(16) unsigned At32[4096];
    __shared__ __align__(16) unsigned Bt32[4096];
    int t = threadIdx.x;
    int lane = t & 63;
    int wid = t >> 6;
    int ws = wid & 1, wc = wid >> 1;
    int l15 = lane & 15, lg = lane >> 4;
    int b = blockIdx.x, cb = blockIdx.y;

    f32x4 acc[4][4];
    const f32x4 fz = {0.f, 0.f, 0.f, 0.f};
    #pragma unroll
    for (int i = 0; i < 4; i++) {
        #pragma unroll
        for (int j = 0; j < 4; j++) acc[i][j] = fz;
    }

    for (int ks = 0; ks < 8; ks++) {
        stage_bf16tile(attn16 + (size_t)b * 128 * Cn + ks * 64, Cn, 128, At32, t);
        stage_bf16tile(WoT + (size_t)cb * 128 * Cn + ks * 64, Cn, 128, Bt32, t);
        __syncthreads();
        #pragma unroll
        for (int m = 0; m < 2; m++) {
            s16x8 af[4], bfr[4];
            #pragma unroll
            for (int i = 0; i < 4; i++)
                af[i] = *(const s16x8*)((const char*)At32 +
                        lds_off(ws * 64 + i * 16 + l15, m * 32 + lg * 8));
            #pragma unroll
            for (int j = 0; j < 4; j++)
                bfr[j] = *(const s16x8*)((const char*)Bt32 +
                        lds_off(wc * 64 + j * 16 + l15, m * 32 + lg * 8));
            #pragma unroll
            for (int i = 0; i < 4; i++) {
                #pragma unroll
                for (int j = 0; j < 4; j++)
                    acc[i][j] = __builtin_amdgcn_mfma_f32_16x16x32_bf16(
                        af[i], bfr[j], acc[i][j], 0, 0, 0);
            }
        }
        __syncthreads();
    }

    float bvv[4];
    #pragma unroll
    for (int j = 0; j < 4; j++) bvv[j] = bo[cb * 128 + wc * 64 + j * 16 + l15];
    unsigned short* sb = SoT + (size_t)b * Cn * Sn;
    #pragma unroll
    for (int i = 0; i < 4; i++) {
        #pragma unroll
        for (int j = 0; j < 4; j++) {
            int c = cb * 128 + wc * 64 + j * 16 + l15;
            #pragma unroll
            for (int r = 0; r < 4; r++) {
                int s = ws * 64 + i * 16 + lg * 4 + r;
                sb[(size_t)c * Sn + s] = f2bf(acc[i][j][r] + bvv[j]);
            }
        }
    }
}

// ---------------- K8': out[n][c] = sum_s w[n,s]*so[s,c] via MFMA ---------------
__global__ __launch_bounds__(256) void k_out2(
    const unsigned short* __restrict__ wAll, const unsigned short* __restrict__ SoT,
    float* __restrict__ out)
{
    __shared__ __align__(16) unsigned At32[4096];
    __shared__ __align__(16) unsigned Bt32[4096];
    int t = threadIdx.x;
    int lane = t & 63;
    int wid = t >> 6;
    int ws = wid & 1, wc = wid >> 1;
    int l15 = lane & 15, lg = lane >> 4;
    int blk = blockIdx.x;
    int b = blk / (NB128 * 4);
    int rem = blk % (NB128 * 4);
    int rb = rem >> 2;
    int cb = rem & 3;
    int n0 = rb * 128, c0 = cb * 128;
    int nvalid = Nn - n0; if (nvalid > 128) nvalid = 128;
    const unsigned short* wb = wAll + (size_t)b * Nn * Sn;
    const unsigned short* sb = SoT + (size_t)b * Cn * Sn;

    f32x4 acc[4][4];
    const f32x4 fz = {0.f, 0.f, 0.f, 0.f};
    #pragma unroll
    for (int i = 0; i < 4; i++) {
        #pragma unroll
        for (int j = 0; j < 4; j++) acc[i][j] = fz;
    }

    #pragma unroll
    for (int ksi = 0; ksi < 2; ksi++) {
        stage_bf16tile(wb + (size_t)n0 * Sn + ksi * 64, Sn, nvalid, At32, t);
        stage_bf16tile(sb + (size_t)c0 * Sn + ksi * 64, Sn, 128, Bt32, t);
        __syncthreads();
        #pragma unroll
        for (int m = 0; m < 2; m++) {
            s16x8 af[4], bfr[4];
            #pragma unroll
            for (int i = 0; i < 4; i++)
                af[i] = *(const s16x8*)((const char*)At32 +
                        lds_off(ws * 64 + i * 16 + l15, m * 32 + lg * 8));
            #pragma unroll
            for (int j = 0; j < 4; j++)
                bfr[j] = *(const s16x8*)((const char*)Bt32 +
                        lds_off(wc * 64 + j * 16 + l15, m * 32 + lg * 8));
            #pragma unroll
            for (int i = 0; i < 4; i++) {
                #pragma unroll
                for (int j = 0; j < 4; j++)
                    acc[i][j] = __builtin_amdgcn_mfma_f32_16x16x32_bf16(
                        af[i], bfr[j], acc[i][j], 0, 0, 0);
            }
        }
        __syncthreads();
    }

    #pragma unroll
    for (int i = 0; i < 4; i++) {
        #pragma unroll
        for (int r = 0; r < 4; r++) {
            int n = n0 + ws * 64 + i * 16 + lg * 4 + r;
            if (n < Nn) {
                #pragma unroll
                for (int j = 0; j < 4; j++)
                    out[((size_t)b * Nn + n) * Cn + c0 + wc * 64 + j * 16 + l15] =
                        acc[i][j][r];
            }
        }
    }
}

extern "C" void kernel_launch(void* const* d_in, const int* in_sizes, int n_in,
                              void* d_out, int out_size, void* d_ws, size_t ws_size,
                              hipStream_t stream)
{
    const float* x  = (const float*)d_in[0];
    const int* adj  = (const int*)d_in[1];
    const float* av = (const float*)d_in[2];
    const float* Ws = (const float*)d_in[3];
    const float* bs = (const float*)d_in[4];
    const float* Wq = (const float*)d_in[5];
    const float* bq = (const float*)d_in[6];
    const float* Wk = (const float*)d_in[7];
    const float* bk = (const float*)d_in[8];
    const float* Wv = (const float*)d_in[9];
    const float* bv = (const float*)d_in[10];
    const float* Wo = (const float*)d_in[11];
    const float* bo = (const float*)d_in[12];
    const float* br = (const float*)d_in[13];
    float* out = (float*)d_out;
    (void)in_sizes; (void)n_in; (void)out_size; (void)ws_size;

    char* ws = (char*)d_ws;
    size_t off = 0;
    unsigned short* wb16  = (unsigned short*)(ws + off); off += (size_t)Bn * Nn * Sn * 2; // 10.24 MB
    unsigned short* gwb16 = (unsigned short*)(ws + off); off += (size_t)Bn * Nn * Sn * 2; // 10.24 MB
    unsigned short* sl16  = (unsigned short*)(ws + off); off += (size_t)Bn * Sn * Cn * 2; // 256 KB
    float* wsum       = (float*)(ws + off); off += 1024;
    float* gb_raw     = (float*)(ws + off); off += (size_t)Bn * Sn * Sn * 4;
    float* gb         = (float*)(ws + off); off += (size_t)Bn * Sn * Sn * 4;
    float* q          = (float*)(ws + off); off += (size_t)Bn * Sn * Cn * 4;
    float* kbuf       = (float*)(ws + off); off += (size_t)Bn * Sn * Cn * 4;
    float* vbuf       = (float*)(ws + off); off += (size_t)Bn * Sn * Cn * 4;
    unsigned short* attn16 = (unsigned short*)(ws + off); off += (size_t)Bn * Sn * Cn * 2;
    unsigned short* WsT = (unsigned short*)(ws + off); off += (size_t)Sn * Cn * 2;
    unsigned short* WT  = (unsigned short*)(ws + off); off += (size_t)4 * Cn * Cn * 2;   // 2 MB
    unsigned short* SoT = (unsigned short*)(ws + off); off += (size_t)Bn * Cn * Sn * 2;
    // Union region U: CSR buffers live [k_deg .. k_gather], then partialS
    // [k_mmS .. k_reduceS] (33.0 MB), then partialG [k_mmG .. k_reduceG] (20.6 MB).
    char* U = ws + off;
    int*  deg    = (int*)(U);
    int*  cursor = (int*)(U + 80128);
    int*  offs   = (int*)(U + 160256);
    int2* epack  = (int2*)(U + 240640);     // 2.56 MB
    float* partialS = (float*)U;            // 504 * 64 KB = 33.0 MB
    float* partialG = (float*)U;            // 314 * 64 KB = 20.6 MB

    // NOTE: no hipMemsetAsync here — rocclr fillBufferAligned for the 160 KB
    // region took ~47 us/replay in the captured graph (R9 profile). k_prepW's
    // idle blocks zero deg/cursor/wsum instead.
    k_prepW<<<dim3(16, 16, 5), 256, 0, stream>>>(Ws, Wq, Wk, Wv, Wo, WsT, WT,
                                                 (int*)U, wsum);
    k_assign2<<<Bn * NB64, 256, 0, stream>>>(x, WsT, bs, wb16, wsum);

    // CSR build + gather (bf16 gw)
    k_deg<<<(En + 255) / 256, 256, 0, stream>>>(adj, deg);
    k_scan<<<1, 1024, 0, stream>>>(deg, offs);
    k_fill<<<(En + 255) / 256, 256, 0, stream>>>(adj, av, offs, cursor, epack);
    k_gather<<<Nn, 128, 0, stream>>>(wb16, epack, offs, gwb16);

    // slices(bf16) = wT @ x / wsum  (pipelined MFMA partials + reduce)
    k_mmS<<<Bn * 4 * S_KB, 256, 0, stream>>>(wb16, x, partialS);
    k_reduceS<<<(Bn * Sn * Cn) / 256, 256, 0, stream>>>(partialS, wsum, sl16);

    // gb_raw = wT @ gw (MFMA partials + reduce)
    k_mmG<<<Bn * G_KB, 256, 0, stream>>>(wb16, gwb16, partialG);
    k_reduceG<<<(Bn * Sn * Sn) / 256, 256, 0, stream>>>(partialG, gb_raw);
    k_gb_fin<<<Bn * Sn, 128, 0, stream>>>(gb_raw, gb);

    // q/k/v via fused MFMA GEMM, then attention, then Wo (writes SoT directly)
    k_qkv<<<dim3(2, 4, 3), 256, 0, stream>>>(sl16, WT, bq, bk, bv, q, kbuf, vbuf);
    k_attn<<<Bn * Hn * Sn, 128, 0, stream>>>(q, kbuf, vbuf, gb, br, attn16);
    k_wo<<<dim3(2, 4), 256, 0, stream>>>(attn16, WT + (size_t)3 * Cn * Cn, bo, SoT);

    k_out2<<<Bn * NB128 * 4, 256, 0, stream>>>(wb16, SoT, out);
}

// Round 11
// 228.609 us; speedup vs baseline: 4.7503x; 1.0864x over previous
//
#include <hip/hip_runtime.h>
#include <math.h>

#define Bn 2
#define Nn 20000
#define Cn 512
#define Sn 128
#define Hn 8
#define Dn 64
#define En 320000
#define EPSf 1e-6f
#define NB64 313   // ceil(20000/64)
#define NB128 157  // ceil(20000/128)
#define NSCAN 20   // ceil(20000/1024)

#define S_CHUNK 320
#define S_KB 63        // 63*320 = 20160 >= 20000
#define G_CHUNK 128
#define G_KB 157       // 157*128 = 20096 >= 20000

typedef __attribute__((ext_vector_type(4))) float f32x4;
typedef __attribute__((ext_vector_type(8))) short s16x8;

__device__ __forceinline__ unsigned short f2bf(float f) {
    unsigned u = __float_as_uint(f);
    return (unsigned short)((u + 0x7fffu + ((u >> 16) & 1u)) >> 16);
}
__device__ __forceinline__ float bf2f(unsigned short h) {
    return __uint_as_float(((unsigned)h) << 16);
}

// Swizzled LDS byte offset for a [rows][64 k] bf16 tile (rows<=128).
__device__ __forceinline__ unsigned lds_off(int row, int n) {
    unsigned ch = ((((unsigned)n >> 3) ^ ((unsigned)row & 7u) ^ (((unsigned)row >> 3) & 7u)) & 7u);
    return (unsigned)row * 128u + ch * 16u + ((unsigned)n & 7u) * 2u;
}

// ---- stage [128 rows][64 k] bf16 tile from bf16 row-major source --------------
__device__ __forceinline__ void stage_bf16tile(
    const unsigned short* __restrict__ src, int stride, int nvalid, unsigned* dst, int t)
{
    #pragma unroll
    for (int l = 0; l < 2; l++) {
        int task = t + l * 256;
        int row = task >> 2, seg = task & 3;
        s16x8 a = {0,0,0,0,0,0,0,0}, b = {0,0,0,0,0,0,0,0};
        if (row < nvalid) {
            a = *(const s16x8*)(src + (size_t)row * stride + seg * 16);
            b = *(const s16x8*)(src + (size_t)row * stride + seg * 16 + 8);
        }
        *(s16x8*)((char*)dst + lds_off(row, seg * 16)) = a;
        *(s16x8*)((char*)dst + lds_off(row, seg * 16 + 8)) = b;
    }
}

// ---------------- prep: weight transposes + workspace zeroing ------------------
__global__ __launch_bounds__(256) void k_prepW(
    const float* __restrict__ Ws, const float* __restrict__ Wq,
    const float* __restrict__ Wk, const float* __restrict__ Wv,
    const float* __restrict__ Wo, unsigned short* __restrict__ WsT,
    unsigned short* __restrict__ WT, int* __restrict__ zeroU,
    float* __restrict__ wsum)
{
    __shared__ float tile[32][33];
    int t = threadIdx.x;
    int z = blockIdx.z;
    int k0 = blockIdx.x * 32;
    int c0 = blockIdx.y * 32;
    const float* W;
    unsigned short* dst;
    int ncols;
    if (z == 0) {
        if (c0 >= Sn) {
            int idx = (((int)blockIdx.y - 4) * 16 + (int)blockIdx.x) * 256 + t;
            if (idx < 40064) zeroU[idx] = 0;                 // deg + cursor
            else if (idx < 40064 + Bn * Sn) wsum[idx - 40064] = 0.f;
            return;
        }
        W = Ws; dst = WsT; ncols = Sn;
    } else {
        W = (z == 1) ? Wq : (z == 2) ? Wk : (z == 3) ? Wv : Wo;
        dst = WT + (size_t)(z - 1) * Cn * Cn; ncols = Cn;
    }
    #pragma unroll
    for (int l = 0; l < 4; l++) {
        int idx = t + l * 256;
        int r = idx >> 5, c = idx & 31;
        tile[r][c] = W[(size_t)(k0 + r) * ncols + c0 + c];
    }
    __syncthreads();
    #pragma unroll
    for (int l = 0; l < 4; l++) {
        int idx = t + l * 256;
        int r = idx >> 5, c = idx & 31;
        dst[(size_t)(c0 + r) * Cn + k0 + c] = f2bf(tile[c][r]);
    }
}

// ---------------- K1''': weights = softmax(x @ Ws + bs), pipelined -------------
__global__ __launch_bounds__(256) void k_assign2(
    const float* __restrict__ x, const unsigned short* __restrict__ WsT,
    const float* __restrict__ bs, unsigned short* __restrict__ weights,
    float* __restrict__ wsum)
{
    __shared__ __align__(16) unsigned At32[2][2048];
    __shared__ __align__(16) unsigned Bt32[2][4096];
    __shared__ float wsum_loc[128];

    int t = threadIdx.x;
    int lane = t & 63;
    int wid = t >> 6;
    int l15 = lane & 15, lg = lane >> 4;
    int blk = blockIdx.x;
    int b = blk / NB64;
    int rb = blk % NB64;
    int n0 = rb * 64;
    int nvalid = Nn - n0; if (nvalid > 64) nvalid = 64;
    const float* xb = x + (size_t)b * Nn * Cn;

    if (t < 128) wsum_loc[t] = 0.f;

    int arow = t >> 2, aseg = t & 3;
    bool aok = (arow < nvalid);
    const float4* aptr = (const float4*)(xb + (size_t)(n0 + arow) * Cn) + aseg * 4;
    int brow = t >> 2, bseg = t & 3;
    const unsigned short* bp0 = WsT + (size_t)brow * Cn + bseg * 16;
    const unsigned short* bp1 = WsT + (size_t)(brow + 64) * Cn + bseg * 16;

    const f32x4 fz = {0.f, 0.f, 0.f, 0.f};
    f32x4 acc[8];
    #pragma unroll
    for (int j = 0; j < 8; j++) acc[j] = fz;

    float4 ra[4];
    #pragma unroll
    for (int i = 0; i < 4; i++) ra[i] = make_float4(0.f, 0.f, 0.f, 0.f);
    s16x8 rb0a, rb0b, rb1a, rb1b;

    if (aok) { ra[0] = aptr[0]; ra[1] = aptr[1]; ra[2] = aptr[2]; ra[3] = aptr[3]; }
    rb0a = *(const s16x8*)(bp0);     rb0b = *(const s16x8*)(bp0 + 8);
    rb1a = *(const s16x8*)(bp1);     rb1b = *(const s16x8*)(bp1 + 8);

    int cur = 0;
    for (int ks = 0; ks < 8; ks++) {
        {
            float v[16] = {ra[0].x, ra[0].y, ra[0].z, ra[0].w,
                           ra[1].x, ra[1].y, ra[1].z, ra[1].w,
                           ra[2].x, ra[2].y, ra[2].z, ra[2].w,
                           ra[3].x, ra[3].y, ra[3].z, ra[3].w};
            #pragma unroll
            for (int h = 0; h < 2; h++) {
                uint4 u;
                u.x = (unsigned)f2bf(v[h*8+0]) | (((unsigned)f2bf(v[h*8+1])) << 16);
                u.y = (unsigned)f2bf(v[h*8+2]) | (((unsigned)f2bf(v[h*8+3])) << 16);
                u.z = (unsigned)f2bf(v[h*8+4]) | (((unsigned)f2bf(v[h*8+5])) << 16);
                u.w = (unsigned)f2bf(v[h*8+6]) | (((unsigned)f2bf(v[h*8+7])) << 16);
                *(uint4*)((char*)At32[cur] + lds_off(arow, aseg * 16 + h * 8)) = u;
            }
            *(s16x8*)((char*)Bt32[cur] + lds_off(brow, bseg * 16)) = rb0a;
            *(s16x8*)((char*)Bt32[cur] + lds_off(brow, bseg * 16 + 8)) = rb0b;
            *(s16x8*)((char*)Bt32[cur] + lds_off(brow + 64, bseg * 16)) = rb1a;
            *(s16x8*)((char*)Bt32[cur] + lds_off(brow + 64, bseg * 16 + 8)) = rb1b;
        }
        if (ks < 7) {
            int kn = ks + 1;
            if (aok) {
                ra[0] = aptr[kn*16]; ra[1] = aptr[kn*16+1];
                ra[2] = aptr[kn*16+2]; ra[3] = aptr[kn*16+3];
            }
            rb0a = *(const s16x8*)(bp0 + kn*64); rb0b = *(const s16x8*)(bp0 + kn*64 + 8);
            rb1a = *(const s16x8*)(bp1 + kn*64); rb1b = *(const s16x8*)(bp1 + kn*64 + 8);
        }
        __syncthreads();
        #pragma unroll
        for (int m = 0; m < 2; m++) {
            s16x8 af = *(const s16x8*)((const char*)At32[cur] +
                       lds_off(wid * 16 + l15, m * 32 + lg * 8));
            #pragma unroll
            for (int j = 0; j < 8; j++) {
                s16x8 bf = *(const s16x8*)((const char*)Bt32[cur] +
                           lds_off(j * 16 + l15, m * 32 + lg * 8));
                acc[j] = __builtin_amdgcn_mfma_f32_16x16x32_bf16(af, bf, acc[j], 0, 0, 0);
            }
        }
        __syncthreads();
        cur ^= 1;
    }

    float bsv[8];
    #pragma unroll
    for (int j = 0; j < 8; j++) bsv[j] = bs[j * 16 + l15];

    unsigned short* wb = weights + (size_t)b * Nn * Sn;
    unsigned short* wt = (unsigned short*)&At32[0][0];
    float wacc[8] = {0.f,0.f,0.f,0.f,0.f,0.f,0.f,0.f};
    #pragma unroll
    for (int r = 0; r < 4; r++) {
        float lv[8];
        #pragma unroll
        for (int j = 0; j < 8; j++) lv[j] = acc[j][r] + bsv[j];
        float m = lv[0];
        #pragma unroll
        for (int j = 1; j < 8; j++) m = fmaxf(m, lv[j]);
        m = fmaxf(m, __shfl_xor(m, 1));
        m = fmaxf(m, __shfl_xor(m, 2));
        m = fmaxf(m, __shfl_xor(m, 4));
        m = fmaxf(m, __shfl_xor(m, 8));
        float e[8], sm = 0.f;
        #pragma unroll
        for (int j = 0; j < 8; j++) { e[j] = __expf(lv[j] - m); sm += e[j]; }
        sm += __shfl_xor(sm, 1);
        sm += __shfl_xor(sm, 2);
        sm += __shfl_xor(sm, 4);
        sm += __shfl_xor(sm, 8);
        float inv = 1.f / sm;
        int rloc = wid * 16 + lg * 4 + r;
        bool valid = (n0 + rloc < Nn);
        #pragma unroll
        for (int j = 0; j < 8; j++) {
            float w = e[j] * inv;
            wt[rloc * 128 + j * 16 + l15] = f2bf(w);
            if (valid) wacc[j] += w;
        }
    }
    #pragma unroll
    for (int j = 0; j < 8; j++) {
        wacc[j] += __shfl_xor(wacc[j], 16);
        wacc[j] += __shfl_xor(wacc[j], 32);
    }
    if (lg == 0) {
        #pragma unroll
        for (int j = 0; j < 8; j++) atomicAdd(&wsum_loc[j * 16 + l15], wacc[j]);
    }
    __syncthreads();
    {
        int orow = t >> 2, oseg = t & 3;
        if (orow < nvalid) {
            uint4* dst = (uint4*)(wb + (size_t)(n0 + orow) * Sn + oseg * 32);
            const uint4* src = (const uint4*)(wt + (size_t)orow * 128 + oseg * 32);
            dst[0] = src[0]; dst[1] = src[1]; dst[2] = src[2]; dst[3] = src[3];
        }
    }
    if (t < 128) atomicAdd(&wsum[b * Sn + t], wsum_loc[t]);
}

// ---------------- CSR build: degree histogram ----------------------------------
__global__ __launch_bounds__(256) void k_deg(
    const int* __restrict__ adj, int* __restrict__ deg)
{
    int e = blockIdx.x * 256 + threadIdx.x;
    if (e < En) atomicAdd(&deg[adj[e]], 1);
}

// ---------------- CSR build: two-level scan (A: per-block inclusive) -----------
__global__ __launch_bounds__(1024) void k_scanA(
    const int* __restrict__ deg, int* __restrict__ offs, int* __restrict__ bsum)
{
    __shared__ int wsums[16];
    __shared__ int excl[16];
    int t = threadIdx.x;
    int lane = t & 63;
    int w = t >> 6;
    int base = blockIdx.x * 1024;
    int v = (base + t < Nn) ? deg[base + t] : 0;
    int sv = v;
    #pragma unroll
    for (int d = 1; d < 64; d <<= 1) {
        int u = __shfl_up(sv, d);
        if (lane >= d) sv += u;
    }
    if (lane == 63) wsums[w] = sv;
    __syncthreads();
    if (t < 16) {
        int xv = wsums[t];
        int sw = xv;
        #pragma unroll
        for (int d = 1; d < 16; d <<= 1) {
            int u = __shfl_up(sw, d);
            if (t >= d) sw += u;
        }
        excl[t] = sw - xv;
        if (t == 15) bsum[blockIdx.x] = sw;
    }
    __syncthreads();
    if (base + t < Nn) offs[base + t + 1] = excl[w] + sv;
    if (blockIdx.x == 0 && t == 0) offs[0] = 0;
}

// ---------------- CSR build: two-level scan (B: add block prefixes) ------------
__global__ __launch_bounds__(1024) void k_scanB(
    int* __restrict__ offs, const int* __restrict__ bsum)
{
    __shared__ int pS;
    int t = threadIdx.x;
    int blk = blockIdx.x;
    if (t == 0) {
        int p = 0;
        for (int j = 0; j < blk; j++) p += bsum[j];
        pS = p;
    }
    __syncthreads();
    int base = blk * 1024;
    if (blk > 0 && base + t < Nn) offs[base + t + 1] += pS;
}

// ---------------- CSR build: fill packed (col, val) edge records ---------------
__global__ __launch_bounds__(256) void k_fill(
    const int* __restrict__ adj, const float* __restrict__ vals,
    const int* __restrict__ offs, int* __restrict__ cursor,
    int2* __restrict__ epack)
{
    int e = blockIdx.x * 256 + threadIdx.x;
    if (e < En) {
        int r = adj[e];
        int p = atomicAdd(&cursor[r], 1);
        epack[offs[r] + p] = make_int2(adj[En + e], __float_as_int(vals[e]));
    }
}

// ---------------- K3'': gw rows via 8-parallel edges + s16x8 loads -------------
// thread = (edge-group eg=t>>4, s-chunk sc=t&15); rows reduce in LDS.
__global__ __launch_bounds__(128) void k_gather(
    const unsigned short* __restrict__ weights, const int2* __restrict__ epack,
    const int* __restrict__ offs, unsigned short* __restrict__ gwb)
{
    __shared__ float red[2][8][132];   // pad 132 -> ~2-way write banks
    int r = blockIdx.x;
    int t = threadIdx.x;
    int eg = t >> 4;
    int sc = t & 15;
    int o0 = offs[r], o1 = offs[r + 1];
    const unsigned short* w0 = weights;
    const unsigned short* w1 = weights + (size_t)Nn * Sn;
    float a0[8], a1[8];
    #pragma unroll
    for (int i = 0; i < 8; i++) { a0[i] = 0.f; a1[i] = 0.f; }
    for (int j = o0 + eg; j < o1; j += 8) {
        int2 e = epack[j];
        float v = __int_as_float(e.y);
        s16x8 x0 = *(const s16x8*)(w0 + (size_t)e.x * Sn + sc * 8);
        s16x8 x1 = *(const s16x8*)(w1 + (size_t)e.x * Sn + sc * 8);
        #pragma unroll
        for (int i = 0; i < 8; i++) {
            a0[i] += v * bf2f((unsigned short)x0[i]);
            a1[i] += v * bf2f((unsigned short)x1[i]);
        }
    }
    #pragma unroll
    for (int i = 0; i < 8; i++) {
        red[0][eg][sc * 8 + i] = a0[i];
        red[1][eg][sc * 8 + i] = a1[i];
    }
    __syncthreads();
    float s0 = 0.f, s1 = 0.f;
    #pragma unroll
    for (int gix = 0; gix < 8; gix++) { s0 += red[0][gix][t]; s1 += red[1][gix][t]; }
    gwb[(size_t)r * Sn + t] = f2bf(s0);
    gwb[(size_t)Nn * Sn + (size_t)r * Sn + t] = f2bf(s1);
}

// ---------------- K2'': slices partials, pipelined (T14) -----------------------
__global__ __launch_bounds__(256) void k_mmS(
    const unsigned short* __restrict__ wAall, const float* __restrict__ xall,
    float* __restrict__ partial)
{
    __shared__ __align__(16) unsigned At32[2][4096];
    __shared__ __align__(16) unsigned Bt32[2][4096];
    int t = threadIdx.x;
    int lane = t & 63;
    int wid = t >> 6;
    int ws = wid & 1, wc = wid >> 1;
    int blk = blockIdx.x;
    int b = blk / (4 * S_KB);
    int rem = blk % (4 * S_KB);
    int cb = rem / S_KB;
    int kb = rem % S_KB;
    int n0 = kb * S_CHUNK;
    int c0 = cb * 128;
    const unsigned short* wA = wAall + (size_t)b * Nn * Sn;
    const float* Bsrc = xall + (size_t)b * Nn * Cn;

    f32x4 acc[4][4];
    const f32x4 fz = {0.f, 0.f, 0.f, 0.f};
    #pragma unroll
    for (int i = 0; i < 4; i++) {
        #pragma unroll
        for (int j = 0; j < 4; j++) acc[i][j] = fz;
    }

    int l15 = lane & 15, lg = lane >> 4;
    int c = t & 15;
    int p0 = t >> 4;

    s16x8 pa[2][2];
    float4 pb[2][4];
    const s16x8 z8 = {0,0,0,0,0,0,0,0};

    auto LOADS = [&](int kt) {
        #pragma unroll
        for (int h = 0; h < 2; h++) {
            int nl = 2 * (p0 + h * 16);
            int ng = n0 + kt + nl;
            pa[h][0] = z8; pa[h][1] = z8;
            pb[h][0] = make_float4(0.f,0.f,0.f,0.f); pb[h][1] = pb[h][0];
            pb[h][2] = pb[h][0]; pb[h][3] = pb[h][0];
            if (ng < Nn) {
                pa[h][0] = *(const s16x8*)(wA + (size_t)ng * Sn + 8 * c);
                pb[h][0] = *(const float4*)(Bsrc + (size_t)ng * Cn + c0 + 8 * c);
                pb[h][1] = *(const float4*)(Bsrc + (size_t)ng * Cn + c0 + 8 * c + 4);
            }
            if (ng + 1 < Nn) {
                pa[h][1] = *(const s16x8*)(wA + (size_t)(ng + 1) * Sn + 8 * c);
                pb[h][2] = *(const float4*)(Bsrc + (size_t)(ng + 1) * Cn + c0 + 8 * c);
                pb[h][3] = *(const float4*)(Bsrc + (size_t)(ng + 1) * Cn + c0 + 8 * c + 4);
            }
        }
    };
    auto STORE = [&](int buf) {
        #pragma unroll
        for (int h = 0; h < 2; h++) {
            int nl = 2 * (p0 + h * 16);
            #pragma unroll
            for (int i = 0; i < 8; i++) {
                unsigned val = ((unsigned)(unsigned short)pa[h][0][i]) |
                               (((unsigned)(unsigned short)pa[h][1][i]) << 16);
                At32[buf][lds_off(8 * c + i, nl) >> 2] = val;
            }
            float b0[8] = {pb[h][0].x, pb[h][0].y, pb[h][0].z, pb[h][0].w,
                           pb[h][1].x, pb[h][1].y, pb[h][1].z, pb[h][1].w};
            float b1[8] = {pb[h][2].x, pb[h][2].y, pb[h][2].z, pb[h][2].w,
                           pb[h][3].x, pb[h][3].y, pb[h][3].z, pb[h][3].w};
            #pragma unroll
            for (int i = 0; i < 8; i++) {
                unsigned val = (unsigned)f2bf(b0[i]) | (((unsigned)f2bf(b1[i])) << 16);
                Bt32[buf][lds_off(8 * c + i, nl) >> 2] = val;
            }
        }
    };

    LOADS(0);
    int cur = 0;
    for (int it = 0; it < 5; it++) {
        STORE(cur);
        if (it < 4) LOADS((it + 1) * 64);
        __syncthreads();
        #pragma unroll
        for (int m = 0; m < 2; m++) {
            s16x8 af[4], bfr[4];
            #pragma unroll
            for (int i = 0; i < 4; i++) {
                int row = ws * 64 + i * 16 + l15;
                af[i] = *(const s16x8*)((const char*)At32[cur] + lds_off(row, m * 32 + lg * 8));
            }
            #pragma unroll
            for (int j = 0; j < 4; j++) {
                int row = wc * 64 + j * 16 + l15;
                bfr[j] = *(const s16x8*)((const char*)Bt32[cur] + lds_off(row, m * 32 + lg * 8));
            }
            #pragma unroll
            for (int i = 0; i < 4; i++) {
                #pragma unroll
                for (int j = 0; j < 4; j++)
                    acc[i][j] = __builtin_amdgcn_mfma_f32_16x16x32_bf16(
                        af[i], bfr[j], acc[i][j], 0, 0, 0);
            }
        }
        __syncthreads();
        cur ^= 1;
    }

    float* pp = partial + (size_t)blk * 16384;
    #pragma unroll
    for (int i = 0; i < 4; i++) {
        int srow = ws * 64 + i * 16 + lg * 4;
        #pragma unroll
        for (int j = 0; j < 4; j++) {
            int ccol = wc * 64 + j * 16 + l15;
            #pragma unroll
            for (int r = 0; r < 4; r++)
                pp[(size_t)(srow + r) * 128 + ccol] = acc[i][j][r];
        }
    }
}

// ---------------- K4'': gb partials, pipelined, both operands bf16 -------------
__global__ __launch_bounds__(256) void k_mmG(
    const unsigned short* __restrict__ wAall, const unsigned short* __restrict__ gwall,
    float* __restrict__ partial)
{
    __shared__ __align__(16) unsigned At32[2][4096];
    __shared__ __align__(16) unsigned Bt32[2][4096];
    int t = threadIdx.x;
    int lane = t & 63;
    int wid = t >> 6;
    int ws = wid & 1, wc = wid >> 1;
    int blk = blockIdx.x;
    int b = blk / G_KB;
    int kb = blk % G_KB;
    int n0 = kb * G_CHUNK;
    const unsigned short* wA = wAall + (size_t)b * Nn * Sn;
    const unsigned short* Bsrc = gwall + (size_t)b * Nn * Sn;

    f32x4 acc[4][4];
    const f32x4 fz = {0.f, 0.f, 0.f, 0.f};
    #pragma unroll
    for (int i = 0; i < 4; i++) {
        #pragma unroll
        for (int j = 0; j < 4; j++) acc[i][j] = fz;
    }

    int l15 = lane & 15, lg = lane >> 4;
    int c = t & 15;
    int p0 = t >> 4;

    s16x8 pa[2][2], pg[2][2];
    const s16x8 z8 = {0,0,0,0,0,0,0,0};

    auto LOADS = [&](int kt) {
        #pragma unroll
        for (int h = 0; h < 2; h++) {
            int nl = 2 * (p0 + h * 16);
            int ng = n0 + kt + nl;
            pa[h][0] = z8; pa[h][1] = z8; pg[h][0] = z8; pg[h][1] = z8;
            if (ng < Nn) {
                pa[h][0] = *(const s16x8*)(wA + (size_t)ng * Sn + 8 * c);
                pg[h][0] = *(const s16x8*)(Bsrc + (size_t)ng * Sn + 8 * c);
            }
            if (ng + 1 < Nn) {
                pa[h][1] = *(const s16x8*)(wA + (size_t)(ng + 1) * Sn + 8 * c);
                pg[h][1] = *(const s16x8*)(Bsrc + (size_t)(ng + 1) * Sn + 8 * c);
            }
        }
    };
    auto STORE = [&](int buf) {
        #pragma unroll
        for (int h = 0; h < 2; h++) {
            int nl = 2 * (p0 + h * 16);
            #pragma unroll
            for (int i = 0; i < 8; i++) {
                unsigned va = ((unsigned)(unsigned short)pa[h][0][i]) |
                              (((unsigned)(unsigned short)pa[h][1][i]) << 16);
                At32[buf][lds_off(8 * c + i, nl) >> 2] = va;
                unsigned vg = ((unsigned)(unsigned short)pg[h][0][i]) |
                              (((unsigned)(unsigned short)pg[h][1][i]) << 16);
                Bt32[buf][lds_off(8 * c + i, nl) >> 2] = vg;
            }
        }
    };

    LOADS(0);
    int cur = 0;
    for (int it = 0; it < 2; it++) {     // G_CHUNK/64
        STORE(cur);
        if (it < 1) LOADS(64);
        __syncthreads();
        #pragma unroll
        for (int m = 0; m < 2; m++) {
            s16x8 af[4], bfr[4];
            #pragma unroll
            for (int i = 0; i < 4; i++) {
                int row = ws * 64 + i * 16 + l15;
                af[i] = *(const s16x8*)((const char*)At32[cur] + lds_off(row, m * 32 + lg * 8));
            }
            #pragma unroll
            for (int j = 0; j < 4; j++) {
                int row = wc * 64 + j * 16 + l15;
                bfr[j] = *(const s16x8*)((const char*)Bt32[cur] + lds_off(row, m * 32 + lg * 8));
            }
            #pragma unroll
            for (int i = 0; i < 4; i++) {
                #pragma unroll
                for (int j = 0; j < 4; j++)
                    acc[i][j] = __builtin_amdgcn_mfma_f32_16x16x32_bf16(
                        af[i], bfr[j], acc[i][j], 0, 0, 0);
            }
        }
        __syncthreads();
        cur ^= 1;
    }

    float* pp = partial + (size_t)blk * 16384;
    #pragma unroll
    for (int i = 0; i < 4; i++) {
        int srow = ws * 64 + i * 16 + lg * 4;
        #pragma unroll
        for (int j = 0; j < 4; j++) {
            int ccol = wc * 64 + j * 16 + l15;
            #pragma unroll
            for (int r = 0; r < 4; r++)
                pp[(size_t)(srow + r) * 128 + ccol] = acc[i][j][r];
        }
    }
}

// ---------------- fused reduce: partialS -> sl16, partialG -> gb_raw -----------
__global__ __launch_bounds__(256) void k_reduceSG(
    const float* __restrict__ pS, const float* __restrict__ pG,
    const float* __restrict__ wsum, unsigned short* __restrict__ sl16,
    float* __restrict__ gb_raw)
{
    int g = blockIdx.x * 256 + threadIdx.x;
    if (g < Bn * Sn * Cn) {
        int c = g & 127;
        int s = (g >> 7) & 127;
        int cb = (g >> 14) & 3;
        int b = g >> 16;
        const float* pp = pS + (size_t)(b * 4 + cb) * S_KB * 16384 + (size_t)s * 128 + c;
        float sum = 0.f;
        #pragma unroll 7
        for (int kb = 0; kb < S_KB; kb++) sum += pp[(size_t)kb * 16384];
        sl16[((size_t)b * Sn + s) * Cn + cb * 128 + c] =
            f2bf(sum / fmaxf(wsum[b * Sn + s], EPSf));
    } else {
        int g2 = g - Bn * Sn * Cn;
        int t2 = g2 & 127;
        int s = (g2 >> 7) & 127;
        int b = g2 >> 14;
        const float* pp = pG + (size_t)b * G_KB * 16384 + (size_t)s * 128 + t2;
        float sum = 0.f;
        #pragma unroll 8
        for (int kb = 0; kb < G_KB; kb++) sum += pp[(size_t)kb * 16384];
        gb_raw[(size_t)b * 16384 + (size_t)s * 128 + t2] = sum;
    }
}

// ---------------- K4b: symmetrize, row-normalize, log --------------------------
__global__ __launch_bounds__(128) void k_gb_fin(
    const float* __restrict__ gb_raw, float* __restrict__ gb)
{
    int bid = blockIdx.x;
    int b = bid >> 7, i = bid & 127;
    int j = threadIdx.x;
    const float* gr = gb_raw + (size_t)b * Sn * Sn;
    float sym = 0.5f * (gr[i * Sn + j] + gr[j * Sn + i]);
    float sum = sym;
    #pragma unroll
    for (int d = 1; d < 64; d <<= 1) sum += __shfl_xor(sum, d);
    __shared__ float wred[2];
    if ((j & 63) == 0) wred[j >> 6] = sum;
    __syncthreads();
    sum = wred[0] + wred[1];
    float r = fmaxf(sum, EPSf);
    gb[(size_t)b * Sn * Sn + (size_t)i * Sn + j] = logf(fmaxf(sym / r, EPSf));
}

// ---------------- K5': q/k/v = sl16 @ WT[z] + bias, MFMA, fused ----------------
__global__ __launch_bounds__(256) void k_qkv(
    const unsigned short* __restrict__ sl16, const unsigned short* __restrict__ WT,
    const float* __restrict__ bq, const float* __restrict__ bk,
    const float* __restrict__ bv,
    float* __restrict__ q, float* __restrict__ kb, float* __restrict__ vb)
{
    __shared__ __align__(16) unsigned At32[4096];
    __shared__ __align__(16) unsigned Bt32[4096];
    int t = threadIdx.x;
    int lane = t & 63;
    int wid = t >> 6;
    int ws = wid & 1, wc = wid >> 1;
    int l15 = lane & 15, lg = lane >> 4;
    int rb = blockIdx.x, cb = blockIdx.y, sel = blockIdx.z;
    const unsigned short* Bmat = WT + (size_t)sel * Cn * Cn;
    const float* bias = (sel == 0) ? bq : (sel == 1) ? bk : bv;
    float* outp = (sel == 0) ? q : (sel == 1) ? kb : vb;

    f32x4 acc[4][4];
    const f32x4 fz = {0.f, 0.f, 0.f, 0.f};
    #pragma unroll
    for (int i = 0; i < 4; i++) {
        #pragma unroll
        for (int j = 0; j < 4; j++) acc[i][j] = fz;
    }

    for (int ks = 0; ks < 8; ks++) {
        stage_bf16tile(sl16 + (size_t)rb * 128 * Cn + ks * 64, Cn, 128, At32, t);
        stage_bf16tile(Bmat + (size_t)cb * 128 * Cn + ks * 64, Cn, 128, Bt32, t);
        __syncthreads();
        #pragma unroll
        for (int m = 0; m < 2; m++) {
            s16x8 af[4], bfr[4];
            #pragma unroll
            for (int i = 0; i < 4; i++)
                af[i] = *(const s16x8*)((const char*)At32 +
                        lds_off(ws * 64 + i * 16 + l15, m * 32 + lg * 8));
            #pragma unroll
            for (int j = 0; j < 4; j++)
                bfr[j] = *(const s16x8*)((const char*)Bt32 +
                        lds_off(wc * 64 + j * 16 + l15, m * 32 + lg * 8));
            #pragma unroll
            for (int i = 0; i < 4; i++) {
                #pragma unroll
                for (int j = 0; j < 4; j++)
                    acc[i][j] = __builtin_amdgcn_mfma_f32_16x16x32_bf16(
                        af[i], bfr[j], acc[i][j], 0, 0, 0);
            }
        }
        __syncthreads();
    }

    float bvv[4];
    #pragma unroll
    for (int j = 0; j < 4; j++) bvv[j] = bias[cb * 128 + wc * 64 + j * 16 + l15];
    #pragma unroll
    for (int i = 0; i < 4; i++) {
        #pragma unroll
        for (int r = 0; r < 4; r++) {
            int m = rb * 128 + ws * 64 + i * 16 + lg * 4 + r;
            #pragma unroll
            for (int j = 0; j < 4; j++)
                outp[(size_t)m * Cn + cb * 128 + wc * 64 + j * 16 + l15] =
                    acc[i][j][r] + bvv[j];
        }
    }
}

// ---------------- K6: attention per (b,h,i) -> bf16 out ------------------------
__global__ __launch_bounds__(128) void k_attn(
    const float* __restrict__ q, const float* __restrict__ k,
    const float* __restrict__ v, const float* __restrict__ gb,
    const float* __restrict__ beta_raw, unsigned short* __restrict__ attn16)
{
    __shared__ float kv[128][65];
    __shared__ float qv[64];
    __shared__ float p[128];
    __shared__ float wred[2][2];

    int t = threadIdx.x;
    int bid = blockIdx.x;
    int b = bid / (Hn * Sn);
    int h = (bid / Sn) % Hn;
    int i = bid % Sn;
    size_t base = (size_t)b * Sn * Cn + (size_t)h * Dn;

    if (t < 64) qv[t] = q[base + (size_t)i * Cn + t];
    for (int l = 0; l < 64; l++) {
        int idx = t + l * 128;
        int j = idx >> 6, d = idx & 63;
        kv[j][d] = k[base + (size_t)j * Cn + d];
    }
    __syncthreads();

    float dot = 0.f;
    #pragma unroll
    for (int d = 0; d < 64; d++) dot += qv[d] * kv[t][d];

    float beta = log1pf(__expf(beta_raw[0]));
    float logit = dot * 0.125f + beta * gb[(size_t)b * Sn * Sn + (size_t)i * Sn + t];

    float m = logit;
    #pragma unroll
    for (int d = 1; d < 64; d <<= 1) m = fmaxf(m, __shfl_xor(m, d));
    if ((t & 63) == 0) wred[0][t >> 6] = m;
    __syncthreads();
    m = fmaxf(wred[0][0], wred[0][1]);
    float e = __expf(logit - m);
    float sm = e;
    #pragma unroll
    for (int d = 1; d < 64; d <<= 1) sm += __shfl_xor(sm, d);
    if ((t & 63) == 0) wred[1][t >> 6] = sm;
    __syncthreads();
    sm = wred[1][0] + wred[1][1];
    p[t] = e / sm;
    __syncthreads();

    for (int l = 0; l < 64; l++) {
        int idx = t + l * 128;
        int j = idx >> 6, d = idx & 63;
        kv[j][d] = v[base + (size_t)j * Cn + d];
    }
    __syncthreads();

    if (t < 64) {
        float o = 0.f;
        #pragma unroll 8
        for (int j = 0; j < 128; j++) o += p[j] * kv[j][t];
        attn16[base + (size_t)i * Cn + t] = f2bf(o);
    }
}

// ---------------- K7': SoT[b][c][s] = (attn16 @ WoT + bo)^T bf16 ---------------
__global__ __launch_bounds__(256) void k_wo(
    const unsigned short* __restrict__ attn16, const unsigned short* __restrict__ WoT,
    const float* __restrict__ bo, unsigned short* __restrict__ SoT)
{
    __shared__ __align__(16) unsigned At32[4096];
    __shared__ __align__(16) unsigned Bt32[4096];
    int t = threadIdx.x;
    int lane = t & 63;
    int wid = t >> 6;
    int ws = wid & 1, wc = wid >> 1;
    int l15 = lane & 15, lg = lane >> 4;
    int b = blockIdx.x, cb = blockIdx.y;

    f32x4 acc[4][4];
    const f32x4 fz = {0.f, 0.f, 0.f, 0.f};
    #pragma unroll
    for (int i = 0; i < 4; i++) {
        #pragma unroll
        for (int j = 0; j < 4; j++) acc[i][j] = fz;
    }

    for (int ks = 0; ks < 8; ks++) {
        stage_bf16tile(attn16 + (size_t)b * 128 * Cn + ks * 64, Cn, 128, At32, t);
        stage_bf16tile(WoT + (size_t)cb * 128 * Cn + ks * 64, Cn, 128, Bt32, t);
        __syncthreads();
        #pragma unroll
        for (int m = 0; m < 2; m++) {
            s16x8 af[4], bfr[4];
            #pragma unroll
            for (int i = 0; i < 4; i++)
                af[i] = *(const s16x8*)((const char*)At32 +
                        lds_off(ws * 64 + i * 16 + l15, m * 32 + lg * 8));
            #pragma unroll
            for (int j = 0; j < 4; j++)
                bfr[j] = *(const s16x8*)((const char*)Bt32 +
                        lds_off(wc * 64 + j * 16 + l15, m * 32 + lg * 8));
            #pragma unroll
            for (int i = 0; i < 4; i++) {
                #pragma unroll
                for (int j = 0; j < 4; j++)
                    acc[i][j] = __builtin_amdgcn_mfma_f32_16x16x32_bf16(
                        af[i], bfr[j], acc[i][j], 0, 0, 0);
            }
        }
        __syncthreads();
    }

    float bvv[4];
    #pragma unroll
    for (int j = 0; j < 4; j++) bvv[j] = bo[cb * 128 + wc * 64 + j * 16 + l15];
    unsigned short* sb = SoT + (size_t)b * Cn * Sn;
    #pragma unroll
    for (int i = 0; i < 4; i++) {
        #pragma unroll
        for (int j = 0; j < 4; j++) {
            int c = cb * 128 + wc * 64 + j * 16 + l15;
            #pragma unroll
            for (int r = 0; r < 4; r++) {
                int s = ws * 64 + i * 16 + lg * 4 + r;
                sb[(size_t)c * Sn + s] = f2bf(acc[i][j][r] + bvv[j]);
            }
        }
    }
}

// ---------------- K8': out[n][c] = sum_s w[n,s]*so[s,c] via MFMA ---------------
__global__ __launch_bounds__(256) void k_out2(
    const unsigned short* __restrict__ wAll, const unsigned short* __restrict__ SoT,
    float* __restrict__ out)
{
    __shared__ __align__(16) unsigned At32[4096];
    __shared__ __align__(16) unsigned Bt32[4096];
    int t = threadIdx.x;
    int lane = t & 63;
    int wid = t >> 6;
    int ws = wid & 1, wc = wid >> 1;
    int l15 = lane & 15, lg = lane >> 4;
    int blk = blockIdx.x;
    int b = blk / (NB128 * 4);
    int rem = blk % (NB128 * 4);
    int rb = rem >> 2;
    int cb = rem & 3;
    int n0 = rb * 128, c0 = cb * 128;
    int nvalid = Nn - n0; if (nvalid > 128) nvalid = 128;
    const unsigned short* wb = wAll + (size_t)b * Nn * Sn;
    const unsigned short* sb = SoT + (size_t)b * Cn * Sn;

    f32x4 acc[4][4];
    const f32x4 fz = {0.f, 0.f, 0.f, 0.f};
    #pragma unroll
    for (int i = 0; i < 4; i++) {
        #pragma unroll
        for (int j = 0; j < 4; j++) acc[i][j] = fz;
    }

    #pragma unroll
    for (int ksi = 0; ksi < 2; ksi++) {
        stage_bf16tile(wb + (size_t)n0 * Sn + ksi * 64, Sn, nvalid, At32, t);
        stage_bf16tile(sb + (size_t)c0 * Sn + ksi * 64, Sn, 128, Bt32, t);
        __syncthreads();
        #pragma unroll
        for (int m = 0; m < 2; m++) {
            s16x8 af[4], bfr[4];
            #pragma unroll
            for (int i = 0; i < 4; i++)
                af[i] = *(const s16x8*)((const char*)At32 +
                        lds_off(ws * 64 + i * 16 + l15, m * 32 + lg * 8));
            #pragma unroll
            for (int j = 0; j < 4; j++)
                bfr[j] = *(const s16x8*)((const char*)Bt32 +
                        lds_off(wc * 64 + j * 16 + l15, m * 32 + lg * 8));
            #pragma unroll
            for (int i = 0; i < 4; i++) {
                #pragma unroll
                for (int j = 0; j < 4; j++)
                    acc[i][j] = __builtin_amdgcn_mfma_f32_16x16x32_bf16(
                        af[i], bfr[j], acc[i][j], 0, 0, 0);
            }
        }
        __syncthreads();
    }

    #pragma unroll
    for (int i = 0; i < 4; i++) {
        #pragma unroll
        for (int r = 0; r < 4; r++) {
            int n = n0 + ws * 64 + i * 16 + lg * 4 + r;
            if (n < Nn) {
                #pragma unroll
                for (int j = 0; j < 4; j++)
                    out[((size_t)b * Nn + n) * Cn + c0 + wc * 64 + j * 16 + l15] =
                        acc[i][j][r];
            }
        }
    }
}

extern "C" void kernel_launch(void* const* d_in, const int* in_sizes, int n_in,
                              void* d_out, int out_size, void* d_ws, size_t ws_size,
                              hipStream_t stream)
{
    const float* x  = (const float*)d_in[0];
    const int* adj  = (const int*)d_in[1];
    const float* av = (const float*)d_in[2];
    const float* Ws = (const float*)d_in[3];
    const float* bs = (const float*)d_in[4];
    const float* Wq = (const float*)d_in[5];
    const float* bq = (const float*)d_in[6];
    const float* Wk = (const float*)d_in[7];
    const float* bk = (const float*)d_in[8];
    const float* Wv = (const float*)d_in[9];
    const float* bv = (const float*)d_in[10];
    const float* Wo = (const float*)d_in[11];
    const float* bo = (const float*)d_in[12];
    const float* br = (const float*)d_in[13];
    float* out = (float*)d_out;
    (void)in_sizes; (void)n_in; (void)out_size; (void)ws_size;

    char* ws = (char*)d_ws;
    size_t off = 0;
    unsigned short* wb16  = (unsigned short*)(ws + off); off += (size_t)Bn * Nn * Sn * 2;
    unsigned short* gwb16 = (unsigned short*)(ws + off); off += (size_t)Bn * Nn * Sn * 2;
    unsigned short* sl16  = (unsigned short*)(ws + off); off += (size_t)Bn * Sn * Cn * 2;
    float* wsum       = (float*)(ws + off); off += 1024;
    float* gb_raw     = (float*)(ws + off); off += (size_t)Bn * Sn * Sn * 4;
    float* gb         = (float*)(ws + off); off += (size_t)Bn * Sn * Sn * 4;
    float* q          = (float*)(ws + off); off += (size_t)Bn * Sn * Cn * 4;
    float* kbuf       = (float*)(ws + off); off += (size_t)Bn * Sn * Cn * 4;
    float* vbuf       = (float*)(ws + off); off += (size_t)Bn * Sn * Cn * 4;
    unsigned short* attn16 = (unsigned short*)(ws + off); off += (size_t)Bn * Sn * Cn * 2;
    unsigned short* WsT = (unsigned short*)(ws + off); off += (size_t)Sn * Cn * 2;
    unsigned short* WT  = (unsigned short*)(ws + off); off += (size_t)4 * Cn * Cn * 2;
    unsigned short* SoT = (unsigned short*)(ws + off); off += (size_t)Bn * Cn * Sn * 2;
    // Union region U:
    //  [0, 160256)           : deg + cursor (zeroed by k_prepW)
    //  [160256, 240640)      : offs
    //  [240640, 2800640)     : epack (dead after k_gather)
    //  [2800640, 2800720)    : bsum (dead after k_scanB)
    //  partialS = U[0, 33.0 MB)  (clobbers CSR region AFTER gather — safe)
    //  partialG = U[33.0 MB, 53.6 MB)
    char* U = ws + off;
    int*  deg    = (int*)(U);
    int*  cursor = (int*)(U + 80128);
    int*  offs   = (int*)(U + 160256);
    int2* epack  = (int2*)(U + 240640);
    int*  bsum   = (int*)(U + 2800640);
    float* partialS = (float*)U;                                   // 504*64KB
    float* partialG = (float*)(U + (size_t)504 * 65536);           // 314*64KB

    k_prepW<<<dim3(16, 16, 5), 256, 0, stream>>>(Ws, Wq, Wk, Wv, Wo, WsT, WT,
                                                 (int*)U, wsum);
    k_assign2<<<Bn * NB64, 256, 0, stream>>>(x, WsT, bs, wb16, wsum);

    // CSR build + gather (bf16 gw)
    k_deg<<<(En + 255) / 256, 256, 0, stream>>>(adj, deg);
    k_scanA<<<NSCAN, 1024, 0, stream>>>(deg, offs, bsum);
    k_scanB<<<NSCAN, 1024, 0, stream>>>(offs, bsum);
    k_fill<<<(En + 255) / 256, 256, 0, stream>>>(adj, av, offs, cursor, epack);
    k_gather<<<Nn, 128, 0, stream>>>(wb16, epack, offs, gwb16);

    // both big MFMA partial GEMMs back-to-back, then one fused reduce
    k_mmS<<<Bn * 4 * S_KB, 256, 0, stream>>>(wb16, x, partialS);
    k_mmG<<<Bn * G_KB, 256, 0, stream>>>(wb16, gwb16, partialG);
    k_reduceSG<<<(Bn * Sn * Cn + Bn * Sn * Sn) / 256, 256, 0, stream>>>(
        partialS, partialG, wsum, sl16, gb_raw);
    k_gb_fin<<<Bn * Sn, 128, 0, stream>>>(gb_raw, gb);

    // q/k/v via fused MFMA GEMM, then attention, then Wo (writes SoT directly)
    k_qkv<<<dim3(2, 4, 3), 256, 0, stream>>>(sl16, WT, bq, bk, bv, q, kbuf, vbuf);
    k_attn<<<Bn * Hn * Sn, 128, 0, stream>>>(q, kbuf, vbuf, gb, br, attn16);
    k_wo<<<dim3(2, 4), 256, 0, stream>>>(attn16, WT + (size_t)3 * Cn * Cn, bo, SoT);

    k_out2<<<Bn * NB128 * 4, 256, 0, stream>>>(wb16, SoT, out);
}